// Round 12
// baseline (559.146 us; speedup 1.0000x reference)
//
#include <hip/hip_runtime.h>

typedef unsigned short U16;
typedef __attribute__((ext_vector_type(4))) float f32x4;
typedef __attribute__((ext_vector_type(8))) short short8;
typedef __attribute__((ext_vector_type(8))) __bf16 bf16x8;

#define Bsz 8
#define Lsz 4096
#define HID 1024
#define DIMV 512
#define D_INNER 1024
#define NHEADS 32
#define HEADDIM 32
#define D_STATE 64
#define CONV_DIM 1152
#define D_PROJ 2208
#define D_PROJ_PAD 2304
#define MROWS 32768
#define CL2 256        // scan chunk per unit
#define NSUB 4         // sub-chunks of 64
#define NCH 16         // Lsz / CL2

__device__ __forceinline__ float bf2f(U16 u) {
  return __builtin_bit_cast(float, (unsigned)(((unsigned)u) << 16));
}
__device__ __forceinline__ U16 f2bf(float f) {
  unsigned u = __builtin_bit_cast(unsigned, f);
  return (U16)((u + 0x7FFFu + ((u >> 16) & 1u)) >> 16);
}
__device__ __forceinline__ void gload_lds16(const void* g, void* l) {
  __builtin_amdgcn_global_load_lds((const __attribute__((address_space(1))) unsigned int*)g,
                                   (__attribute__((address_space(3))) unsigned int*)l, 16, 0, 0);
}

// ---------- tiny txt GEMM ----------
__global__ __launch_bounds__(512) void txt_kernel(const float* __restrict__ text,
                                                  const float* __restrict__ Wt,
                                                  const float* __restrict__ bt,
                                                  float* __restrict__ txt) {
  int b = blockIdx.x, j = threadIdx.x;
  float s = bt[j];
  const float* tp = text + (size_t)b * 77 * 768;
  for (int k = 0; k < 768; ++k) s += tp[k] * Wt[(size_t)k * 512 + j];
  txt[b * 512 + j] = s;
}

// ---------- transpose + convert weights ----------
__global__ __launch_bounds__(256) void transpose_cvt_kernel(const float* __restrict__ in,
                                                            U16* __restrict__ out,
                                                            int K, int N, int Npad) {
  __shared__ U16 tile[32][33];
  int n0 = blockIdx.x * 32, k0 = blockIdx.y * 32;
  int tx = threadIdx.x, ty = threadIdx.y;
  #pragma unroll
  for (int i = 0; i < 4; ++i) {
    int k = k0 + ty + i * 8, n = n0 + tx;
    float v = (n < N) ? in[(size_t)k * N + n] : 0.f;
    tile[ty + i * 8][tx] = f2bf(v);
  }
  __syncthreads();
  #pragma unroll
  for (int i = 0; i < 4; ++i) {
    int n = n0 + ty + i * 8;
    out[(size_t)n * K + k0 + tx] = tile[tx][ty + i * 8];
  }
}

// ---------- bf16 MFMA GEMM ----------
template <int EPI, int AF32, int TRANS>
__global__ __launch_bounds__(256) void gemm_kernel(const void* __restrict__ Ap,
                                                   const U16* __restrict__ Bt,
                                                   U16* __restrict__ C,
                                                   const float* __restrict__ bias,
                                                   const float* __restrict__ txtv,
                                                   int M, int K, int Nreal, int NT) {
  __shared__ alignas(16) U16 smem[128 * 128];
  U16* As = smem;
  U16* Bs = smem + 128 * 64;
  const int tid = threadIdx.x;
  const int wid = tid >> 6, lane = tid & 63;
  const int lhi = lane >> 4, llo = lane & 15;
  const int xcd = blockIdx.x & 7, slot = blockIdx.x >> 3;
  const int m0 = (xcd + 8 * (slot / NT)) * 128;
  const int n0 = (slot % NT) * 128;
  const int wr = wid >> 1, wc = wid & 1;
  f32x4 acc[4][4] = {};

  for (int k0 = 0; k0 < K; k0 += 64) {
    __syncthreads();
    if constexpr (AF32) {
      const float* Af = (const float*)Ap;
      #pragma unroll
      for (int is = 0; is < 4; ++is) {
        int q = is * 256 + tid;
        int r = q >> 3, cl = q & 7;
        int cg = cl ^ (r & 7);
        const float* src = Af + (size_t)(m0 + r) * K + k0 + cg * 8;
        f32x4 v0 = *reinterpret_cast<const f32x4*>(src);
        f32x4 v1 = *reinterpret_cast<const f32x4*>(src + 4);
        short8 o;
        #pragma unroll
        for (int j = 0; j < 4; ++j) {
          o[j] = (short)f2bf(v0[j]);
          o[j + 4] = (short)f2bf(v1[j]);
        }
        *reinterpret_cast<short8*>(&As[q * 8]) = o;
      }
    } else {
      const U16* A = (const U16*)Ap;
      #pragma unroll
      for (int is = 0; is < 4; ++is) {
        int qbase = is * 256 + wid * 64;
        int q = qbase + lane;
        int r = q >> 3;
        int cc = (q & 7) ^ (r & 7);
        gload_lds16(A + (size_t)(m0 + r) * K + k0 + cc * 8, &As[qbase * 8]);
      }
    }
    #pragma unroll
    for (int is = 0; is < 4; ++is) {
      int qbase = is * 256 + wid * 64;
      int q = qbase + lane;
      int r = q >> 3;
      int cc = (q & 7) ^ (r & 7);
      gload_lds16(Bt + (size_t)(n0 + r) * K + k0 + cc * 8, &Bs[qbase * 8]);
    }
    __syncthreads();
    #pragma unroll
    for (int kk = 0; kk < 64; kk += 32) {
      bf16x8 av[4], bv[4];
      #pragma unroll
      for (int i = 0; i < 4; ++i) {
        int ra = wr * 64 + i * 16 + llo;
        short8 a = *reinterpret_cast<const short8*>(
            &As[ra * 64 + ((((kk >> 3) + lhi) ^ (ra & 7)) << 3)]);
        av[i] = __builtin_bit_cast(bf16x8, a);
        int rb = wc * 64 + i * 16 + llo;
        short8 b = *reinterpret_cast<const short8*>(
            &Bs[rb * 64 + ((((kk >> 3) + lhi) ^ (rb & 7)) << 3)]);
        bv[i] = __builtin_bit_cast(bf16x8, b);
      }
      #pragma unroll
      for (int i = 0; i < 4; ++i)
        #pragma unroll
        for (int j = 0; j < 4; ++j)
          acc[i][j] = __builtin_amdgcn_mfma_f32_16x16x32_bf16(av[i], bv[j], acc[i][j], 0, 0, 0);
    }
  }
  const int b = m0 >> 12;
  if constexpr (TRANS) {
    __syncthreads();
    U16* T = smem;
    #pragma unroll
    for (int i = 0; i < 4; ++i) {
      #pragma unroll
      for (int j = 0; j < 4; ++j) {
        int c_loc = wc * 64 + j * 16 + llo;
        int cg = n0 + c_loc;
        float badd = (cg < D_PROJ) ? bias[cg] : 0.f;
        int q = wr * 16 + i * 4 + lhi;
        int qs = q ^ ((c_loc & 15) << 1);
        U16 pk[4];
        #pragma unroll
        for (int r = 0; r < 4; ++r) {
          float v = acc[i][j][r] + badd;
          if (cg < 1024) v = v / (1.f + __expf(-v));
          pk[r] = f2bf(v);
        }
        uint2 p2;
        p2.x = (unsigned)pk[0] | ((unsigned)pk[1] << 16);
        p2.y = (unsigned)pk[2] | ((unsigned)pk[3] << 16);
        *reinterpret_cast<uint2*>(&T[c_loc * 128 + qs * 4]) = p2;
      }
    }
    __syncthreads();
    const int l0 = m0 & 4095;
    #pragma unroll
    for (int cs = 0; cs < 8; ++cs) {
      int c = cs * 16 + (tid >> 4);
      int gch = n0 + c;
      int kp = (tid & 15) * 2;
      int q0 = kp ^ ((c & 15) << 1);
      int q1 = (kp + 1) ^ ((c & 15) << 1);
      uint2 a = *reinterpret_cast<const uint2*>(&T[c * 128 + q0 * 4]);
      uint2 bq = *reinterpret_cast<const uint2*>(&T[c * 128 + q1 * 4]);
      if (gch < D_PROJ) {
        uint4 oo;
        oo.x = a.x; oo.y = a.y; oo.z = bq.x; oo.w = bq.y;
        *reinterpret_cast<uint4*>(C + ((size_t)b * D_PROJ_PAD + gch) * 4096 + l0 + kp * 4) = oo;
      }
    }
  } else {
    #pragma unroll
    for (int i = 0; i < 4; ++i) {
      int rbase = m0 + wr * 64 + i * 16 + lhi * 4;
      #pragma unroll
      for (int j = 0; j < 4; ++j) {
        int cg = n0 + wc * 64 + j * 16 + llo;
        if (cg < Nreal) {
          float badd = bias[cg] + (EPI ? txtv[b * 512 + cg] : 0.f);
          #pragma unroll
          for (int r = 0; r < 4; ++r)
            C[(size_t)(rbase + r) * Nreal + cg] = f2bf(acc[i][j][r] + badd);
        }
      }
    }
  }
}

// ---------- LayerNorm ----------
__global__ __launch_bounds__(128) void ln_kernel(const U16* __restrict__ tok,
                                                 U16* __restrict__ xo,
                                                 const float* __restrict__ w,
                                                 const float* __restrict__ bb) {
  int row = blockIdx.x, tid = threadIdx.x;
  const U16* rp = tok + (size_t)row * 512 + tid * 4;
  uint2 raw = *reinterpret_cast<const uint2*>(rp);
  float f0 = bf2f((U16)(raw.x & 0xffff)), f1 = bf2f((U16)(raw.x >> 16));
  float f2 = bf2f((U16)(raw.y & 0xffff)), f3 = bf2f((U16)(raw.y >> 16));
  float s = f0 + f1 + f2 + f3;
  float q = f0 * f0 + f1 * f1 + f2 * f2 + f3 * f3;
  for (int m = 1; m < 64; m <<= 1) { s += __shfl_xor(s, m); q += __shfl_xor(q, m); }
  __shared__ float ss[2], qq[2];
  if ((tid & 63) == 0) { ss[tid >> 6] = s; qq[tid >> 6] = q; }
  __syncthreads();
  s = ss[0] + ss[1]; q = qq[0] + qq[1];
  float mu = s * (1.f / 512.f);
  float var = q * (1.f / 512.f) - mu * mu;
  float rs = rsqrtf(var + 1e-5f);
  int j0 = tid * 4;
  unsigned c0 = f2bf((f0 - mu) * rs * w[j0] + bb[j0]);
  unsigned c1 = f2bf((f1 - mu) * rs * w[j0 + 1] + bb[j0 + 1]);
  unsigned c2 = f2bf((f2 - mu) * rs * w[j0 + 2] + bb[j0 + 2]);
  unsigned c3 = f2bf((f3 - mu) * rs * w[j0 + 3] + bb[j0 + 3]);
  uint2 o; o.x = c0 | (c1 << 16); o.y = c2 | (c3 << 16);
  *reinterpret_cast<uint2*>(xo + (size_t)row * 512 + j0) = o;
}

// ---------- tok partial column sums ----------
__global__ __launch_bounds__(256) void tokpart_kernel(const U16* __restrict__ tok,
                                                      float* __restrict__ part) {
  int b = blockIdx.x, j = blockIdx.y * 256 + threadIdx.x, z = blockIdx.z;
  float s = 0.f;
  int l0 = z * 256;
  for (int l = l0; l < l0 + 256; ++l)
    s += bf2f(tok[((size_t)b * Lsz + l) * 512 + j]);
  part[(z * 8 + b) * 512 + j] = s;
}

// ---------- decay precompute from zx_t ----------
__global__ __launch_bounds__(256) void decay_kernel(const U16* __restrict__ zxT,
                                                    const float* __restrict__ dt_bias,
                                                    const float* __restrict__ A_log,
                                                    float* __restrict__ decay4) {
  const int sc = blockIdx.x;
  const int w = threadIdx.x >> 6, l = threadIdx.x & 63;
  const int r0 = sc * 64;
  const int b = r0 >> 12, l0 = r0 & 4095;
  #pragma unroll
  for (int i = 0; i < 8; ++i) {
    int hh = w * 8 + i;
    float raw = bf2f(zxT[((size_t)b * D_PROJ_PAD + 2176 + hh) * 4096 + l0 + l]) + dt_bias[hh];
    float dt = (raw > 20.f) ? raw : log1pf(__expf(raw));
    float A = -__expf(A_log[hh]);
    float ldA2 = dt * A * 1.44269504088896f;
    float ldt2 = __log2f(dt);
    float la = ldA2;
    #pragma unroll
    for (int d = 1; d < 64; d <<= 1) {
      float o = __shfl_up(la, d);
      if (l >= d) la += o;
    }
    float laend = __shfl(la, 63);
    f32x4 v = {ldt2 - la, la, exp2f(la), exp2f(laend + ldt2 - la)};
    *reinterpret_cast<f32x4*>(decay4 + ((size_t)(b * 32 + hh) * 4096 + l0 + l) * 4) = v;
  }
}

// ---------- conv(K=4)+silu on transposed layout ----------
__global__ __launch_bounds__(256) void conv_t_kernel(
    const U16* __restrict__ zxT, const float* __restrict__ cw,
    const float* __restrict__ cb, U16* __restrict__ xh_t,
    U16* __restrict__ bm_t, U16* __restrict__ cm_t,
    U16* __restrict__ Bmo, U16* __restrict__ Cmo) {
  __shared__ U16 Tc[64 * 264];
  const int lc = blockIdx.x, cg = blockIdx.y, b = blockIdx.z;
  const int tid = threadIdx.x;
  const int cl = tid & 63, ls = tid >> 6;
  const int cc2 = cg * 64 + cl;
  const int l0 = lc * 256 + ls * 64;
  const U16* row = zxT + ((size_t)b * D_PROJ_PAD + 1024 + cc2) * 4096;

  U16 arr[72];
  {
    const U16* src = row + l0 - 8;
    #pragma unroll
    for (int k = 0; k < 9; ++k) {
      uint4 rv;
      if (l0 == 0 && k == 0) {
        rv.x = rv.y = rv.z = rv.w = 0u;
      } else {
        rv = *reinterpret_cast<const uint4*>(src + k * 8);
      }
      arr[k * 8 + 0] = (U16)(rv.x & 0xffff); arr[k * 8 + 1] = (U16)(rv.x >> 16);
      arr[k * 8 + 2] = (U16)(rv.y & 0xffff); arr[k * 8 + 3] = (U16)(rv.y >> 16);
      arr[k * 8 + 4] = (U16)(rv.z & 0xffff); arr[k * 8 + 5] = (U16)(rv.z >> 16);
      arr[k * 8 + 6] = (U16)(rv.w & 0xffff); arr[k * 8 + 7] = (U16)(rv.w >> 16);
    }
  }
  const float4 w4 = *reinterpret_cast<const float4*>(cw + cc2 * 4);
  const float cbv = cb[cc2];
  U16 o[64];
  #pragma unroll
  for (int j = 0; j < 64; ++j) {
    float acc = cbv + bf2f(arr[j + 5]) * w4.x + bf2f(arr[j + 6]) * w4.y +
                bf2f(arr[j + 7]) * w4.z + bf2f(arr[j + 8]) * w4.w;
    o[j] = f2bf(acc / (1.f + __expf(-acc)));
  }
  {
    U16* dst;
    if (cc2 < 1024)      dst = xh_t + ((size_t)b * 1024 + cc2) * 4096 + l0;
    else if (cc2 < 1088) dst = bm_t + ((size_t)(b * 64 + (cc2 - 1024))) * 4096 + l0;
    else                 dst = cm_t + ((size_t)(b * 64 + (cc2 - 1088))) * 4096 + l0;
    #pragma unroll
    for (int k = 0; k < 8; ++k) {
      uint4 ov;
      ov.x = (unsigned)o[k * 8 + 0] | ((unsigned)o[k * 8 + 1] << 16);
      ov.y = (unsigned)o[k * 8 + 2] | ((unsigned)o[k * 8 + 3] << 16);
      ov.z = (unsigned)o[k * 8 + 4] | ((unsigned)o[k * 8 + 5] << 16);
      ov.w = (unsigned)o[k * 8 + 6] | ((unsigned)o[k * 8 + 7] << 16);
      *reinterpret_cast<uint4*>(dst + k * 8) = ov;
    }
  }
  if (cg >= 16) {
    #pragma unroll
    for (int k = 0; k < 8; ++k) {
      uint4 ov;
      ov.x = (unsigned)o[k * 8 + 0] | ((unsigned)o[k * 8 + 1] << 16);
      ov.y = (unsigned)o[k * 8 + 2] | ((unsigned)o[k * 8 + 3] << 16);
      ov.z = (unsigned)o[k * 8 + 4] | ((unsigned)o[k * 8 + 5] << 16);
      ov.w = (unsigned)o[k * 8 + 6] | ((unsigned)o[k * 8 + 7] << 16);
      *reinterpret_cast<uint4*>(&Tc[cl * 264 + ls * 64 + k * 8]) = ov;
    }
    __syncthreads();
    U16* outp = (cg == 16) ? Bmo : Cmo;
    const int lt = tid;
    U16 rowv[64];
    #pragma unroll
    for (int n = 0; n < 64; ++n) rowv[n] = Tc[n * 264 + lt];
    U16* dst = outp + ((size_t)b * 4096 + lc * 256 + lt) * 64;
    #pragma unroll
    for (int k = 0; k < 8; ++k) {
      uint4 ov;
      ov.x = (unsigned)rowv[k * 8 + 0] | ((unsigned)rowv[k * 8 + 1] << 16);
      ov.y = (unsigned)rowv[k * 8 + 2] | ((unsigned)rowv[k * 8 + 3] << 16);
      ov.z = (unsigned)rowv[k * 8 + 4] | ((unsigned)rowv[k * 8 + 5] << 16);
      ov.w = (unsigned)rowv[k * 8 + 6] | ((unsigned)rowv[k * 8 + 7] << 16);
      *reinterpret_cast<uint4*>(dst + k * 8) = ov;
    }
  }
}

// ---------- SSD chunked scan via MFMA: mega-batched loads per sub-chunk ----------
// Staging + gz loads issued FIRST (latency drains under matmul1), matmul3
// fragment loads fully batched (one stall point).
__global__ __launch_bounds__(256, 2) void scan_chunk_kernel(
    const U16* __restrict__ xh_t, const U16* __restrict__ zxT,
    const U16* __restrict__ Bm, const U16* __restrict__ Cm,
    const U16* __restrict__ bm_t, const U16* __restrict__ cm_t,
    const float* __restrict__ decay4, const float* __restrict__ Dp,
    U16* __restrict__ hpart, U16* __restrict__ wacc,
    float* __restrict__ ylocal, float* __restrict__ aprod) {
  const int w = threadIdx.x >> 6, l = threadIdx.x & 63;
  const int bid = (blockIdx.x & 7) * 128 + (blockIdx.x >> 3);
  const int u = bid * 4 + w;
  const int hh = u & 31, ci = (u >> 5) & (NCH - 1), b = u >> 9;
  const int tl = l & 15, lg = l >> 4;

  __shared__ alignas(16) U16 MsmAll[4 * 64 * 72];
  __shared__ alignas(16) float decAll[4 * 256];
  U16* Msm = &MsmAll[w * 64 * 72];
  float* qsm = &decAll[w * 256];
  float* la2sm = qsm + 64;
  float* casm = qsm + 128;
  float* cfsm = qsm + 192;

  #pragma unroll
  for (int i = 0; i < 9; ++i)
    *reinterpret_cast<f32x4*>(reinterpret_cast<char*>(Msm) + (size_t)l * 144 + i * 16) =
        f32x4{0.f, 0.f, 0.f, 0.f};

  f32x4 hC[2][4] = {};
  f32x4 WB[2][4] = {};
  f32x4 corrp[2] = {};
  float ylac[2] = {0.f, 0.f}, dxac[2] = {0.f, 0.f};
  float capfx = 1.f;
  const size_t xrow = ((size_t)b * 1024 + hh * 32) * 4096;
  const size_t grow = ((size_t)b * D_PROJ_PAD + hh * 32) * 4096;
  const float* dbase = decay4 + ((size_t)(b * 32 + hh) * 4096) * 4;

  for (int sc = 0; sc < NSUB; ++sc) {
    const int lglob = ci * CL2 + sc * 64;
    const int r0g = b * 4096 + lglob;

    f32x4 dv = *reinterpret_cast<const f32x4*>(dbase + (size_t)(lglob + l) * 4);
    qsm[l] = dv[0];
    la2sm[l] = dv[1];
    casm[l] = dv[2];
    cfsm[l] = dv[3];
    const float cs = __shfl(dv[2], 63);

    // ---- issue ALL independent loads for this sub-chunk up front:
    //      staging raws (16) + gz (8). Latency drains under matmul1. ----
    short8 graw[2][2], xraw[2][2];
    uint2 gzp[4][2];
    #pragma unroll
    for (int pt = 0; pt < 2; ++pt)
      #pragma unroll
      for (int kt = 0; kt < 2; ++kt) {
        size_t po = (size_t)(pt * 16 + tl) * 4096 + lglob + kt * 32 + lg * 8;
        graw[pt][kt] = *reinterpret_cast<const short8*>(zxT + grow + po);
        xraw[pt][kt] = *reinterpret_cast<const short8*>(xh_t + xrow + po);
      }
    #pragma unroll
    for (int tt = 0; tt < 4; ++tt)
      #pragma unroll
      for (int pt = 0; pt < 2; ++pt)
        gzp[tt][pt] = *reinterpret_cast<const uint2*>(
            zxT + grow + (size_t)(pt * 16 + tl) * 4096 + lglob + tt * 16 + lg * 4);

    // ---- matmul1 half A: si in {0,1} (7 tiles) ----
    {
      f32x4 g[7] = {};
      #pragma unroll
      for (int k = 0; k < 2; ++k) {
        const size_t co = (size_t)k * 32 + lg * 8;
        bf16x8 af0 = *reinterpret_cast<const bf16x8*>(Bm + (size_t)(r0g + tl) * 64 + co);
        bf16x8 af1 = *reinterpret_cast<const bf16x8*>(Bm + (size_t)(r0g + 16 + tl) * 64 + co);
        bf16x8 cf0 = *reinterpret_cast<const bf16x8*>(Cm + (size_t)(r0g + tl) * 64 + co);
        bf16x8 cf1 = *reinterpret_cast<const bf16x8*>(Cm + (size_t)(r0g + 16 + tl) * 64 + co);
        bf16x8 cf2 = *reinterpret_cast<const bf16x8*>(Cm + (size_t)(r0g + 32 + tl) * 64 + co);
        bf16x8 cf3 = *reinterpret_cast<const bf16x8*>(Cm + (size_t)(r0g + 48 + tl) * 64 + co);
        __builtin_amdgcn_s_setprio(1);
        g[0] = __builtin_amdgcn_mfma_f32_16x16x32_bf16(af0, cf0, g[0], 0, 0, 0);
        g[1] = __builtin_amdgcn_mfma_f32_16x16x32_bf16(af0, cf1, g[1], 0, 0, 0);
        g[2] = __builtin_amdgcn_mfma_f32_16x16x32_bf16(af0, cf2, g[2], 0, 0, 0);
        g[3] = __builtin_amdgcn_mfma_f32_16x16x32_bf16(af0, cf3, g[3], 0, 0, 0);
        g[4] = __builtin_amdgcn_mfma_f32_16x16x32_bf16(af1, cf1, g[4], 0, 0, 0);
        g[5] = __builtin_amdgcn_mfma_f32_16x16x32_bf16(af1, cf2, g[5], 0, 0, 0);
        g[6] = __builtin_amdgcn_mfma_f32_16x16x32_bf16(af1, cf3, g[6], 0, 0, 0);
        __builtin_amdgcn_s_setprio(0);
      }
      f32x4 q0 = *reinterpret_cast<const f32x4*>(&qsm[lg * 4]);
      f32x4 q1 = *reinterpret_cast<const f32x4*>(&qsm[16 + lg * 4]);
      #pragma unroll
      for (int idx = 0; idx < 7; ++idx) {
        const int si = (idx < 4) ? 0 : 1;
        const int ti = (idx < 4) ? idx : (idx - 3);
        f32x4 q4 = si ? q1 : q0;
        float lat = la2sm[ti * 16 + tl];
        float v[4];
        #pragma unroll
        for (int r = 0; r < 4; ++r) {
          float val = g[idx][r] * exp2f(lat + q4[r]);
          if (si == ti) val = (lg * 4 + r <= tl) ? val : 0.f;
          v[r] = val;
        }
        uint2 pk;
        pk.x = (unsigned)f2bf(v[0]) | ((unsigned)f2bf(v[1]) << 16);
        pk.y = (unsigned)f2bf(v[2]) | ((unsigned)f2bf(v[3]) << 16);
        *reinterpret_cast<uint2*>(reinterpret_cast<char*>(Msm) +
                                  (size_t)(ti * 16 + tl) * 144 + (size_t)(si * 16 + lg * 4) * 2) = pk;
      }
    }
    // ---- matmul1 half B: si in {2,3} (3 tiles) ----
    {
      f32x4 g[3] = {};
      #pragma unroll
      for (int k = 0; k < 2; ++k) {
        const size_t co = (size_t)k * 32 + lg * 8;
        bf16x8 af2 = *reinterpret_cast<const bf16x8*>(Bm + (size_t)(r0g + 32 + tl) * 64 + co);
        bf16x8 af3 = *reinterpret_cast<const bf16x8*>(Bm + (size_t)(r0g + 48 + tl) * 64 + co);
        bf16x8 cf2 = *reinterpret_cast<const bf16x8*>(Cm + (size_t)(r0g + 32 + tl) * 64 + co);
        bf16x8 cf3 = *reinterpret_cast<const bf16x8*>(Cm + (size_t)(r0g + 48 + tl) * 64 + co);
        __builtin_amdgcn_s_setprio(1);
        g[0] = __builtin_amdgcn_mfma_f32_16x16x32_bf16(af2, cf2, g[0], 0, 0, 0);
        g[1] = __builtin_amdgcn_mfma_f32_16x16x32_bf16(af2, cf3, g[1], 0, 0, 0);
        g[2] = __builtin_amdgcn_mfma_f32_16x16x32_bf16(af3, cf3, g[2], 0, 0, 0);
        __builtin_amdgcn_s_setprio(0);
      }
      f32x4 q2 = *reinterpret_cast<const f32x4*>(&qsm[32 + lg * 4]);
      f32x4 q3 = *reinterpret_cast<const f32x4*>(&qsm[48 + lg * 4]);
      const int sis[3] = {2, 2, 3};
      const int tis[3] = {2, 3, 3};
      #pragma unroll
      for (int idx = 0; idx < 3; ++idx) {
        const int si = sis[idx], ti = tis[idx];
        f32x4 q4 = (si == 2) ? q2 : q3;
        float lat = la2sm[ti * 16 + tl];
        float v[4];
        #pragma unroll
        for (int r = 0; r < 4; ++r) {
          float val = g[idx][r] * exp2f(lat + q4[r]);
          if (si == ti) val = (lg * 4 + r <= tl) ? val : 0.f;
          v[r] = val;
        }
        uint2 pk;
        pk.x = (unsigned)f2bf(v[0]) | ((unsigned)f2bf(v[1]) << 16);
        pk.y = (unsigned)f2bf(v[2]) | ((unsigned)f2bf(v[3]) << 16);
        *reinterpret_cast<uint2*>(reinterpret_cast<char*>(Msm) +
                                  (size_t)(ti * 16 + tl) * 144 + (size_t)(si * 16 + lg * 4) * 2) = pk;
      }
    }

    // ---- scale staging (data already landed during matmul1); dxac here ----
    bf16x8 ga[2][2], xa[2][2];
    #pragma unroll
    for (int pt = 0; pt < 2; ++pt)
      #pragma unroll
      for (int kt = 0; kt < 2; ++kt) {
        const float* cap = &casm[kt * 32 + lg * 8];
        const float* cfp = &cfsm[kt * 32 + lg * 8];
        short8 gs, xs8;
        #pragma unroll
        for (int j = 0; j < 8; ++j) {
          float gf = bf2f((U16)graw[pt][kt][j]);
          float xf = bf2f((U16)xraw[pt][kt][j]);
          dxac[pt] = fmaf(gf, xf, dxac[pt]);
          gs[j] = (short)f2bf(gf * cap[j]);
          xs8[j] = (short)f2bf(xf * cfp[j]);
        }
        ga[pt][kt] = __builtin_bit_cast(bf16x8, gs);
        xa[pt][kt] = __builtin_bit_cast(bf16x8, xs8);
      }

    // ---- matmul2: Y = M X (X from xraw); ylac ----
    #pragma unroll
    for (int tt = 0; tt < 4; ++tt) {
      f32x4 y[2] = {f32x4{0.f, 0.f, 0.f, 0.f}, f32x4{0.f, 0.f, 0.f, 0.f}};
      __builtin_amdgcn_s_setprio(1);
      #pragma unroll
      for (int ks = 0; ks < 2; ++ks) {
        bf16x8 mf = *reinterpret_cast<const bf16x8*>(
            reinterpret_cast<char*>(Msm) + (size_t)(tt * 16 + tl) * 144 + (ks * 32 + lg * 8) * 2);
        #pragma unroll
        for (int pt = 0; pt < 2; ++pt)
          y[pt] = __builtin_amdgcn_mfma_f32_16x16x32_bf16(
              mf, __builtin_bit_cast(bf16x8, xraw[pt][ks]), y[pt], 0, 0, 0);
      }
      __builtin_amdgcn_s_setprio(0);
      #pragma unroll
      for (int pt = 0; pt < 2; ++pt) {
        uint2 gz2 = gzp[tt][pt];
        float gzv[4] = {bf2f((U16)(gz2.x & 0xffff)), bf2f((U16)(gz2.x >> 16)),
                        bf2f((U16)(gz2.y & 0xffff)), bf2f((U16)(gz2.y >> 16))};
        #pragma unroll
        for (int r = 0; r < 4; ++r)
          ylac[pt] = fmaf(gzv[r], y[pt][r], ylac[pt]);
      }
    }

    // ---- matmul3: ALL 16 fragment loads batched, then MFMA sweep ----
    {
      bf16x8 cb[4][2], bb[4][2];
      #pragma unroll
      for (int nt = 0; nt < 4; ++nt) {
        size_t cro = (size_t)(b * 64 + nt * 16 + tl) * 4096 + lglob;
        cb[nt][0] = *reinterpret_cast<const bf16x8*>(cm_t + cro + lg * 8);
        cb[nt][1] = *reinterpret_cast<const bf16x8*>(cm_t + cro + 32 + lg * 8);
        bb[nt][0] = *reinterpret_cast<const bf16x8*>(bm_t + cro + lg * 8);
        bb[nt][1] = *reinterpret_cast<const bf16x8*>(bm_t + cro + 32 + lg * 8);
      }
      __builtin_amdgcn_s_setprio(1);
      #pragma unroll
      for (int nt = 0; nt < 4; ++nt) {
        #pragma unroll
        for (int pt = 0; pt < 2; ++pt) {
          f32x4 z4 = {0.f, 0.f, 0.f, 0.f};
          f32x4 ws = __builtin_amdgcn_mfma_f32_16x16x32_bf16(ga[pt][0], cb[nt][0], z4, 0, 0, 0);
          ws = __builtin_amdgcn_mfma_f32_16x16x32_bf16(ga[pt][1], cb[nt][1], ws, 0, 0, 0);
          f32x4 hs = __builtin_amdgcn_mfma_f32_16x16x32_bf16(xa[pt][0], bb[nt][0], z4, 0, 0, 0);
          hs = __builtin_amdgcn_mfma_f32_16x16x32_bf16(xa[pt][1], bb[nt][1], hs, 0, 0, 0);
          corrp[pt] = corrp[pt] + hC[pt][nt] * ws;
          WB[pt][nt] = WB[pt][nt] + ws * capfx;
          hC[pt][nt] = hC[pt][nt] * cs + hs;
        }
      }
      __builtin_amdgcn_s_setprio(0);
    }
    capfx *= cs;
  }

  // ---- epilogue ----
  #pragma unroll
  for (int pt = 0; pt < 2; ++pt)
    #pragma unroll
    for (int nt = 0; nt < 4; ++nt) {
      size_t slot = (size_t)u * 2048 + (size_t)((pt * 4 + nt) * 64 + l) * 4;
      ushort4 hp, wp;
      hp.x = f2bf(hC[pt][nt][0]); hp.y = f2bf(hC[pt][nt][1]);
      hp.z = f2bf(hC[pt][nt][2]); hp.w = f2bf(hC[pt][nt][3]);
      wp.x = f2bf(WB[pt][nt][0]); wp.y = f2bf(WB[pt][nt][1]);
      wp.z = f2bf(WB[pt][nt][2]); wp.w = f2bf(WB[pt][nt][3]);
      *reinterpret_cast<ushort4*>(hpart + slot) = hp;
      *reinterpret_cast<ushort4*>(wacc + slot) = wp;
    }
  float corrv[2][4];
  #pragma unroll
  for (int pt = 0; pt < 2; ++pt)
    #pragma unroll
    for (int r = 0; r < 4; ++r) {
      float c = corrp[pt][r];
      c += __shfl_xor(c, 1); c += __shfl_xor(c, 2);
      c += __shfl_xor(c, 4); c += __shfl_xor(c, 8);
      corrv[pt][r] = c;
    }
  const float Dh = Dp[hh];
  float* ysm = qsm;
  #pragma unroll
  for (int pt = 0; pt < 2; ++pt) {
    float yv = ylac[pt] + Dh * dxac[pt];
    yv += __shfl_xor(yv, 16);
    yv += __shfl_xor(yv, 32);
    if (l < 16) ysm[pt * 16 + l] = yv;
  }
  if (tl == 0) {
    #pragma unroll
    for (int pt = 0; pt < 2; ++pt)
      #pragma unroll
      for (int r = 0; r < 4; ++r)
        ysm[pt * 16 + lg * 4 + r] += corrv[pt][r];
  }
  if (l < 32) ylocal[(size_t)u * 32 + l] = ysm[l];
  if (l == 0) aprod[u] = capfx;
}

// ---------- sequential combine across chunks (bf16 hpart/wacc) ----------
__global__ __launch_bounds__(256) void scan_combine_kernel(
    const U16* __restrict__ hpart, const U16* __restrict__ wacc,
    const float* __restrict__ ylocal, const float* __restrict__ aprod,
    float* __restrict__ yysum) {
  const int bh = blockIdx.x;
  const int b = bh >> 5, hh = bh & 31;
  const int w = threadIdx.x >> 6, l = threadIdx.x & 63;
  const int tl = l & 15, lg = l >> 4;
  __shared__ float csm[8][16];
  __shared__ float ylsm[32];
  const int pair0 = w * 2;
  f32x4 hr[2] = {};
  float cv[2][4] = {};
  for (int ci = 0; ci < NCH; ++ci) {
    int bx = (b * NCH + ci) * 32 + hh;
    size_t base = (size_t)bx * 2048 + (size_t)l * 4;
    float ap = aprod[bx];
    #pragma unroll
    for (int k = 0; k < 2; ++k) {
      size_t o = base + (size_t)(pair0 + k) * 256;
      ushort4 wraw = *reinterpret_cast<const ushort4*>(wacc + o);
      ushort4 praw = *reinterpret_cast<const ushort4*>(hpart + o);
      f32x4 wv = {bf2f(wraw.x), bf2f(wraw.y), bf2f(wraw.z), bf2f(wraw.w)};
      f32x4 pv = {bf2f(praw.x), bf2f(praw.y), bf2f(praw.z), bf2f(praw.w)};
      f32x4 a4 = hr[k] * wv;
      #pragma unroll
      for (int r = 0; r < 4; ++r) cv[k][r] += a4[r];
      hr[k] = hr[k] * ap + pv;
    }
  }
  #pragma unroll
  for (int k = 0; k < 2; ++k)
    #pragma unroll
    for (int r = 0; r < 4; ++r) {
      float c = cv[k][r];
      c += __shfl_xor(c, 1); c += __shfl_xor(c, 2);
      c += __shfl_xor(c, 4); c += __shfl_xor(c, 8);
      if (tl == 0) csm[pair0 + k][lg * 4 + r] = c;
    }
  if (threadIdx.x < 32) {
    float yl = 0.f;
    for (int ci = 0; ci < NCH; ++ci)
      yl += ylocal[(size_t)((b * NCH + ci) * 32 + hh) * 32 + threadIdx.x];
    ylsm[threadIdx.x] = yl;
  }
  __syncthreads();
  if (threadIdx.x < 32) {
    int p = threadIdx.x;
    int pt = p >> 4, pl = p & 15;
    float corr = csm[pt * 4 + 0][pl] + csm[pt * 4 + 1][pl] +
                 csm[pt * 4 + 2][pl] + csm[pt * 4 + 3][pl];
    yysum[(size_t)b * 1024 + hh * 32 + p] = ylsm[p] + corr;
  }
}

// ---------- folded epilogue ----------
__global__ __launch_bounds__(128) void final1_kernel(const float* __restrict__ tokpart,
                                                     const float* __restrict__ yysum,
                                                     const float* __restrict__ Wb,
                                                     const float* __restrict__ bb,
                                                     float* __restrict__ m2) {
  int b = blockIdx.x, j = blockIdx.y * 128 + threadIdx.x;
  float tm = 0.f;
  #pragma unroll
  for (int z = 0; z < 16; ++z) tm += tokpart[(z * 8 + b) * 512 + j];
  float s = 0.f;
  for (int d = 0; d < 1024; ++d) s += yysum[b * 1024 + d] * Wb[(size_t)d * 512 + j];
  m2[b * 512 + j] = (tm + s) * (1.f / (float)Lsz) + bb[j];
}

__global__ __launch_bounds__(256) void final2_kernel(const float* __restrict__ m2,
                                                     const float* __restrict__ Wo,
                                                     const float* __restrict__ bo,
                                                     float* __restrict__ out) {
  int b = blockIdx.x, o = blockIdx.y * 256 + threadIdx.x;
  float s = 0.f;
  for (int j = 0; j < 512; ++j) s += m2[b * 512 + j] * Wo[(size_t)j * 1024 + o];
  out[b * 1024 + o] = s + bo[o];
}

extern "C" void kernel_launch(void* const* d_in, const int* in_sizes, int n_in,
                              void* d_out, int out_size, void* d_ws, size_t ws_size,
                              hipStream_t stream) {
  const float* image = (const float*)d_in[0];
  const float* text = (const float*)d_in[1];
  const float* W_in = (const float*)d_in[2];
  const float* b_in = (const float*)d_in[3];
  const float* W_txt = (const float*)d_in[4];
  const float* b_txt = (const float*)d_in[5];
  const float* norm_w = (const float*)d_in[6];
  const float* norm_b = (const float*)d_in[7];
  const float* W_zx = (const float*)d_in[8];
  const float* b_zx = (const float*)d_in[9];
  const float* conv_w = (const float*)d_in[10];
  const float* conv_b = (const float*)d_in[11];
  const float* dt_bias = (const float*)d_in[12];
  const float* A_log = (const float*)d_in[13];
  const float* Dp = (const float*)d_in[14];
  const float* W_blk = (const float*)d_in[15];
  const float* b_blk = (const float*)d_in[16];
  const float* W_out = (const float*)d_in[17];
  const float* b_out = (const float*)d_in[18];
  float* out = (float*)d_out;

  char* ws = (char*)d_ws;
  size_t off = 0;
  auto take = [&](size_t bytes) {
    char* p = ws + off;
    off = (off + bytes + 255) & ~(size_t)255;
    return p;
  };
  U16* zxT = (U16*)take((size_t)Bsz * D_PROJ_PAD * 4096 * 2);
  U16* wt_in = (U16*)take((size_t)DIMV * HID * 2);
  U16* wt_zx = (U16*)take((size_t)D_PROJ_PAD * DIMV * 2);
  U16* tok_bf = (U16*)take((size_t)MROWS * DIMV * 2);
  U16* x_bf = (U16*)take((size_t)MROWS * DIMV * 2);
  U16* xh_t = (U16*)take((size_t)MROWS * D_INNER * 2);
  U16* bm_bf = (U16*)take((size_t)MROWS * 64 * 2);
  U16* cm_bf = (U16*)take((size_t)MROWS * 64 * 2);
  U16* bm_t = (U16*)take((size_t)MROWS * 64 * 2);
  U16* cm_t = (U16*)take((size_t)MROWS * 64 * 2);
  float* decay4 = (float*)take((size_t)256 * 4096 * 16);
  float* txtf = (float*)take(8 * 512 * 4);
  float* tokpart = (float*)take(16 * 8 * 512 * 4);
  float* yysum = (float*)take(8 * 1024 * 4);
  float* m2 = (float*)take(8 * 512 * 4);
  float* ylocal = (float*)take((size_t)4096 * 32 * 4);
  float* aprod = (float*)take((size_t)4096 * 4);
  U16* hpart = tok_bf;
  U16* wacc = x_bf;

  txt_kernel<<<8, 512, 0, stream>>>(text, W_txt, b_txt, txtf);
  transpose_cvt_kernel<<<dim3(DIMV / 32, HID / 32), dim3(32, 8), 0, stream>>>(W_in, wt_in, HID, DIMV, DIMV);
  transpose_cvt_kernel<<<dim3(D_PROJ_PAD / 32, DIMV / 32), dim3(32, 8), 0, stream>>>(W_zx, wt_zx, DIMV, D_PROJ, D_PROJ_PAD);

  gemm_kernel<1, 1, 0><<<1024, 256, 0, stream>>>(
      (const void*)image, wt_in, tok_bf, b_in, txtf, MROWS, HID, DIMV, 4);
  tokpart_kernel<<<dim3(8, 2, 16), 256, 0, stream>>>(tok_bf, tokpart);
  ln_kernel<<<MROWS, 128, 0, stream>>>(tok_bf, x_bf, norm_w, norm_b);

  gemm_kernel<0, 0, 1><<<4608, 256, 0, stream>>>(
      (const void*)x_bf, wt_zx, zxT, b_zx, nullptr, MROWS, DIMV, D_PROJ, 18);

  decay_kernel<<<512, 256, 0, stream>>>(zxT, dt_bias, A_log, decay4);
  conv_t_kernel<<<dim3(16, 18, 8), 256, 0, stream>>>(zxT, conv_w, conv_b,
                                                     xh_t, bm_t, cm_t, bm_bf, cm_bf);

  scan_chunk_kernel<<<1024, 256, 0, stream>>>(xh_t, zxT, bm_bf, cm_bf, bm_t, cm_t,
                                              decay4, Dp, hpart, wacc, ylocal, aprod);
  scan_combine_kernel<<<256, 256, 0, stream>>>(hpart, wacc, ylocal, aprod, yysum);

  final1_kernel<<<dim3(8, 4), 128, 0, stream>>>(tokpart, yysum, W_blk, b_blk, m2);
  final2_kernel<<<dim3(8, 4), 256, 0, stream>>>(m2, W_out, b_out, out);
}

// Round 13
// 537.372 us; speedup vs baseline: 1.0405x; 1.0405x over previous
//
#include <hip/hip_runtime.h>

typedef unsigned short U16;
typedef __attribute__((ext_vector_type(4))) float f32x4;
typedef __attribute__((ext_vector_type(8))) short short8;
typedef __attribute__((ext_vector_type(8))) __bf16 bf16x8;

#define Bsz 8
#define Lsz 4096
#define HID 1024
#define DIMV 512
#define D_INNER 1024
#define NHEADS 32
#define HEADDIM 32
#define D_STATE 64
#define CONV_DIM 1152
#define D_PROJ 2208
#define D_PROJ_PAD 2304
#define MROWS 32768
#define CL2 256        // scan chunk per unit
#define NSUB 4         // sub-chunks of 64
#define NCH 16         // Lsz / CL2

__device__ __forceinline__ float bf2f(U16 u) {
  return __builtin_bit_cast(float, (unsigned)(((unsigned)u) << 16));
}
__device__ __forceinline__ U16 f2bf(float f) {
  unsigned u = __builtin_bit_cast(unsigned, f);
  return (U16)((u + 0x7FFFu + ((u >> 16) & 1u)) >> 16);
}
__device__ __forceinline__ void gload_lds16(const void* g, void* l) {
  __builtin_amdgcn_global_load_lds((const __attribute__((address_space(1))) unsigned int*)g,
                                   (__attribute__((address_space(3))) unsigned int*)l, 16, 0, 0);
}

// ---------- tiny txt GEMM ----------
__global__ __launch_bounds__(512) void txt_kernel(const float* __restrict__ text,
                                                  const float* __restrict__ Wt,
                                                  const float* __restrict__ bt,
                                                  float* __restrict__ txt) {
  int b = blockIdx.x, j = threadIdx.x;
  float s = bt[j];
  const float* tp = text + (size_t)b * 77 * 768;
  for (int k = 0; k < 768; ++k) s += tp[k] * Wt[(size_t)k * 512 + j];
  txt[b * 512 + j] = s;
}

// ---------- transpose + convert weights ----------
__global__ __launch_bounds__(256) void transpose_cvt_kernel(const float* __restrict__ in,
                                                            U16* __restrict__ out,
                                                            int K, int N, int Npad) {
  __shared__ U16 tile[32][33];
  int n0 = blockIdx.x * 32, k0 = blockIdx.y * 32;
  int tx = threadIdx.x, ty = threadIdx.y;
  #pragma unroll
  for (int i = 0; i < 4; ++i) {
    int k = k0 + ty + i * 8, n = n0 + tx;
    float v = (n < N) ? in[(size_t)k * N + n] : 0.f;
    tile[ty + i * 8][tx] = f2bf(v);
  }
  __syncthreads();
  #pragma unroll
  for (int i = 0; i < 4; ++i) {
    int n = n0 + ty + i * 8;
    out[(size_t)n * K + k0 + tx] = tile[tx][ty + i * 8];
  }
}

// ---------- bf16 MFMA GEMM ----------
template <int EPI, int AF32, int TRANS>
__global__ __launch_bounds__(256) void gemm_kernel(const void* __restrict__ Ap,
                                                   const U16* __restrict__ Bt,
                                                   U16* __restrict__ C,
                                                   const float* __restrict__ bias,
                                                   const float* __restrict__ txtv,
                                                   int M, int K, int Nreal, int NT) {
  __shared__ alignas(16) U16 smem[128 * 128];
  U16* As = smem;
  U16* Bs = smem + 128 * 64;
  const int tid = threadIdx.x;
  const int wid = tid >> 6, lane = tid & 63;
  const int lhi = lane >> 4, llo = lane & 15;
  const int xcd = blockIdx.x & 7, slot = blockIdx.x >> 3;
  const int m0 = (xcd + 8 * (slot / NT)) * 128;
  const int n0 = (slot % NT) * 128;
  const int wr = wid >> 1, wc = wid & 1;
  f32x4 acc[4][4] = {};

  for (int k0 = 0; k0 < K; k0 += 64) {
    __syncthreads();
    if constexpr (AF32) {
      const float* Af = (const float*)Ap;
      #pragma unroll
      for (int is = 0; is < 4; ++is) {
        int q = is * 256 + tid;
        int r = q >> 3, cl = q & 7;
        int cg = cl ^ (r & 7);
        const float* src = Af + (size_t)(m0 + r) * K + k0 + cg * 8;
        f32x4 v0 = *reinterpret_cast<const f32x4*>(src);
        f32x4 v1 = *reinterpret_cast<const f32x4*>(src + 4);
        short8 o;
        #pragma unroll
        for (int j = 0; j < 4; ++j) {
          o[j] = (short)f2bf(v0[j]);
          o[j + 4] = (short)f2bf(v1[j]);
        }
        *reinterpret_cast<short8*>(&As[q * 8]) = o;
      }
    } else {
      const U16* A = (const U16*)Ap;
      #pragma unroll
      for (int is = 0; is < 4; ++is) {
        int qbase = is * 256 + wid * 64;
        int q = qbase + lane;
        int r = q >> 3;
        int cc = (q & 7) ^ (r & 7);
        gload_lds16(A + (size_t)(m0 + r) * K + k0 + cc * 8, &As[qbase * 8]);
      }
    }
    #pragma unroll
    for (int is = 0; is < 4; ++is) {
      int qbase = is * 256 + wid * 64;
      int q = qbase + lane;
      int r = q >> 3;
      int cc = (q & 7) ^ (r & 7);
      gload_lds16(Bt + (size_t)(n0 + r) * K + k0 + cc * 8, &Bs[qbase * 8]);
    }
    __syncthreads();
    #pragma unroll
    for (int kk = 0; kk < 64; kk += 32) {
      bf16x8 av[4], bv[4];
      #pragma unroll
      for (int i = 0; i < 4; ++i) {
        int ra = wr * 64 + i * 16 + llo;
        short8 a = *reinterpret_cast<const short8*>(
            &As[ra * 64 + ((((kk >> 3) + lhi) ^ (ra & 7)) << 3)]);
        av[i] = __builtin_bit_cast(bf16x8, a);
        int rb = wc * 64 + i * 16 + llo;
        short8 b = *reinterpret_cast<const short8*>(
            &Bs[rb * 64 + ((((kk >> 3) + lhi) ^ (rb & 7)) << 3)]);
        bv[i] = __builtin_bit_cast(bf16x8, b);
      }
      #pragma unroll
      for (int i = 0; i < 4; ++i)
        #pragma unroll
        for (int j = 0; j < 4; ++j)
          acc[i][j] = __builtin_amdgcn_mfma_f32_16x16x32_bf16(av[i], bv[j], acc[i][j], 0, 0, 0);
    }
  }
  const int b = m0 >> 12;
  if constexpr (TRANS) {
    __syncthreads();
    U16* T = smem;
    #pragma unroll
    for (int i = 0; i < 4; ++i) {
      #pragma unroll
      for (int j = 0; j < 4; ++j) {
        int c_loc = wc * 64 + j * 16 + llo;
        int cg = n0 + c_loc;
        float badd = (cg < D_PROJ) ? bias[cg] : 0.f;
        int q = wr * 16 + i * 4 + lhi;
        int qs = q ^ ((c_loc & 15) << 1);
        U16 pk[4];
        #pragma unroll
        for (int r = 0; r < 4; ++r) {
          float v = acc[i][j][r] + badd;
          if (cg < 1024) v = v / (1.f + __expf(-v));
          pk[r] = f2bf(v);
        }
        uint2 p2;
        p2.x = (unsigned)pk[0] | ((unsigned)pk[1] << 16);
        p2.y = (unsigned)pk[2] | ((unsigned)pk[3] << 16);
        *reinterpret_cast<uint2*>(&T[c_loc * 128 + qs * 4]) = p2;
      }
    }
    __syncthreads();
    const int l0 = m0 & 4095;
    #pragma unroll
    for (int cs = 0; cs < 8; ++cs) {
      int c = cs * 16 + (tid >> 4);
      int gch = n0 + c;
      int kp = (tid & 15) * 2;
      int q0 = kp ^ ((c & 15) << 1);
      int q1 = (kp + 1) ^ ((c & 15) << 1);
      uint2 a = *reinterpret_cast<const uint2*>(&T[c * 128 + q0 * 4]);
      uint2 bq = *reinterpret_cast<const uint2*>(&T[c * 128 + q1 * 4]);
      if (gch < D_PROJ) {
        uint4 oo;
        oo.x = a.x; oo.y = a.y; oo.z = bq.x; oo.w = bq.y;
        *reinterpret_cast<uint4*>(C + ((size_t)b * D_PROJ_PAD + gch) * 4096 + l0 + kp * 4) = oo;
      }
    }
  } else {
    #pragma unroll
    for (int i = 0; i < 4; ++i) {
      int rbase = m0 + wr * 64 + i * 16 + lhi * 4;
      #pragma unroll
      for (int j = 0; j < 4; ++j) {
        int cg = n0 + wc * 64 + j * 16 + llo;
        if (cg < Nreal) {
          float badd = bias[cg] + (EPI ? txtv[b * 512 + cg] : 0.f);
          #pragma unroll
          for (int r = 0; r < 4; ++r)
            C[(size_t)(rbase + r) * Nreal + cg] = f2bf(acc[i][j][r] + badd);
        }
      }
    }
  }
}

// ---------- LayerNorm ----------
__global__ __launch_bounds__(128) void ln_kernel(const U16* __restrict__ tok,
                                                 U16* __restrict__ xo,
                                                 const float* __restrict__ w,
                                                 const float* __restrict__ bb) {
  int row = blockIdx.x, tid = threadIdx.x;
  const U16* rp = tok + (size_t)row * 512 + tid * 4;
  uint2 raw = *reinterpret_cast<const uint2*>(rp);
  float f0 = bf2f((U16)(raw.x & 0xffff)), f1 = bf2f((U16)(raw.x >> 16));
  float f2 = bf2f((U16)(raw.y & 0xffff)), f3 = bf2f((U16)(raw.y >> 16));
  float s = f0 + f1 + f2 + f3;
  float q = f0 * f0 + f1 * f1 + f2 * f2 + f3 * f3;
  for (int m = 1; m < 64; m <<= 1) { s += __shfl_xor(s, m); q += __shfl_xor(q, m); }
  __shared__ float ss[2], qq[2];
  if ((tid & 63) == 0) { ss[tid >> 6] = s; qq[tid >> 6] = q; }
  __syncthreads();
  s = ss[0] + ss[1]; q = qq[0] + qq[1];
  float mu = s * (1.f / 512.f);
  float var = q * (1.f / 512.f) - mu * mu;
  float rs = rsqrtf(var + 1e-5f);
  int j0 = tid * 4;
  unsigned c0 = f2bf((f0 - mu) * rs * w[j0] + bb[j0]);
  unsigned c1 = f2bf((f1 - mu) * rs * w[j0 + 1] + bb[j0 + 1]);
  unsigned c2 = f2bf((f2 - mu) * rs * w[j0 + 2] + bb[j0 + 2]);
  unsigned c3 = f2bf((f3 - mu) * rs * w[j0 + 3] + bb[j0 + 3]);
  uint2 o; o.x = c0 | (c1 << 16); o.y = c2 | (c3 << 16);
  *reinterpret_cast<uint2*>(xo + (size_t)row * 512 + j0) = o;
}

// ---------- tok partial column sums ----------
__global__ __launch_bounds__(256) void tokpart_kernel(const U16* __restrict__ tok,
                                                      float* __restrict__ part) {
  int b = blockIdx.x, j = blockIdx.y * 256 + threadIdx.x, z = blockIdx.z;
  float s = 0.f;
  int l0 = z * 256;
  for (int l = l0; l < l0 + 256; ++l)
    s += bf2f(tok[((size_t)b * Lsz + l) * 512 + j]);
  part[(z * 8 + b) * 512 + j] = s;
}

// ---------- decay precompute from zx_t ----------
__global__ __launch_bounds__(256) void decay_kernel(const U16* __restrict__ zxT,
                                                    const float* __restrict__ dt_bias,
                                                    const float* __restrict__ A_log,
                                                    float* __restrict__ decay4) {
  const int sc = blockIdx.x;
  const int w = threadIdx.x >> 6, l = threadIdx.x & 63;
  const int r0 = sc * 64;
  const int b = r0 >> 12, l0 = r0 & 4095;
  #pragma unroll
  for (int i = 0; i < 8; ++i) {
    int hh = w * 8 + i;
    float raw = bf2f(zxT[((size_t)b * D_PROJ_PAD + 2176 + hh) * 4096 + l0 + l]) + dt_bias[hh];
    float dt = (raw > 20.f) ? raw : log1pf(__expf(raw));
    float A = -__expf(A_log[hh]);
    float ldA2 = dt * A * 1.44269504088896f;
    float ldt2 = __log2f(dt);
    float la = ldA2;
    #pragma unroll
    for (int d = 1; d < 64; d <<= 1) {
      float o = __shfl_up(la, d);
      if (l >= d) la += o;
    }
    float laend = __shfl(la, 63);
    f32x4 v = {ldt2 - la, la, exp2f(la), exp2f(laend + ldt2 - la)};
    *reinterpret_cast<f32x4*>(decay4 + ((size_t)(b * 32 + hh) * 4096 + l0 + l) * 4) = v;
  }
}

// ---------- conv(K=4)+silu on transposed layout ----------
__global__ __launch_bounds__(256) void conv_t_kernel(
    const U16* __restrict__ zxT, const float* __restrict__ cw,
    const float* __restrict__ cb, U16* __restrict__ xh_t,
    U16* __restrict__ bm_t, U16* __restrict__ cm_t,
    U16* __restrict__ Bmo, U16* __restrict__ Cmo) {
  __shared__ U16 Tc[64 * 264];
  const int lc = blockIdx.x, cg = blockIdx.y, b = blockIdx.z;
  const int tid = threadIdx.x;
  const int cl = tid & 63, ls = tid >> 6;
  const int cc2 = cg * 64 + cl;
  const int l0 = lc * 256 + ls * 64;
  const U16* row = zxT + ((size_t)b * D_PROJ_PAD + 1024 + cc2) * 4096;

  U16 arr[72];
  {
    const U16* src = row + l0 - 8;
    #pragma unroll
    for (int k = 0; k < 9; ++k) {
      uint4 rv;
      if (l0 == 0 && k == 0) {
        rv.x = rv.y = rv.z = rv.w = 0u;
      } else {
        rv = *reinterpret_cast<const uint4*>(src + k * 8);
      }
      arr[k * 8 + 0] = (U16)(rv.x & 0xffff); arr[k * 8 + 1] = (U16)(rv.x >> 16);
      arr[k * 8 + 2] = (U16)(rv.y & 0xffff); arr[k * 8 + 3] = (U16)(rv.y >> 16);
      arr[k * 8 + 4] = (U16)(rv.z & 0xffff); arr[k * 8 + 5] = (U16)(rv.z >> 16);
      arr[k * 8 + 6] = (U16)(rv.w & 0xffff); arr[k * 8 + 7] = (U16)(rv.w >> 16);
    }
  }
  const float4 w4 = *reinterpret_cast<const float4*>(cw + cc2 * 4);
  const float cbv = cb[cc2];
  U16 o[64];
  #pragma unroll
  for (int j = 0; j < 64; ++j) {
    float acc = cbv + bf2f(arr[j + 5]) * w4.x + bf2f(arr[j + 6]) * w4.y +
                bf2f(arr[j + 7]) * w4.z + bf2f(arr[j + 8]) * w4.w;
    o[j] = f2bf(acc / (1.f + __expf(-acc)));
  }
  {
    U16* dst;
    if (cc2 < 1024)      dst = xh_t + ((size_t)b * 1024 + cc2) * 4096 + l0;
    else if (cc2 < 1088) dst = bm_t + ((size_t)(b * 64 + (cc2 - 1024))) * 4096 + l0;
    else                 dst = cm_t + ((size_t)(b * 64 + (cc2 - 1088))) * 4096 + l0;
    #pragma unroll
    for (int k = 0; k < 8; ++k) {
      uint4 ov;
      ov.x = (unsigned)o[k * 8 + 0] | ((unsigned)o[k * 8 + 1] << 16);
      ov.y = (unsigned)o[k * 8 + 2] | ((unsigned)o[k * 8 + 3] << 16);
      ov.z = (unsigned)o[k * 8 + 4] | ((unsigned)o[k * 8 + 5] << 16);
      ov.w = (unsigned)o[k * 8 + 6] | ((unsigned)o[k * 8 + 7] << 16);
      *reinterpret_cast<uint4*>(dst + k * 8) = ov;
    }
  }
  if (cg >= 16) {
    #pragma unroll
    for (int k = 0; k < 8; ++k) {
      uint4 ov;
      ov.x = (unsigned)o[k * 8 + 0] | ((unsigned)o[k * 8 + 1] << 16);
      ov.y = (unsigned)o[k * 8 + 2] | ((unsigned)o[k * 8 + 3] << 16);
      ov.z = (unsigned)o[k * 8 + 4] | ((unsigned)o[k * 8 + 5] << 16);
      ov.w = (unsigned)o[k * 8 + 6] | ((unsigned)o[k * 8 + 7] << 16);
      *reinterpret_cast<uint4*>(&Tc[cl * 264 + ls * 64 + k * 8]) = ov;
    }
    __syncthreads();
    U16* outp = (cg == 16) ? Bmo : Cmo;
    const int lt = tid;
    U16 rowv[64];
    #pragma unroll
    for (int n = 0; n < 64; ++n) rowv[n] = Tc[n * 264 + lt];
    U16* dst = outp + ((size_t)b * 4096 + lc * 256 + lt) * 64;
    #pragma unroll
    for (int k = 0; k < 8; ++k) {
      uint4 ov;
      ov.x = (unsigned)rowv[k * 8 + 0] | ((unsigned)rowv[k * 8 + 1] << 16);
      ov.y = (unsigned)rowv[k * 8 + 2] | ((unsigned)rowv[k * 8 + 3] << 16);
      ov.z = (unsigned)rowv[k * 8 + 4] | ((unsigned)rowv[k * 8 + 5] << 16);
      ov.w = (unsigned)rowv[k * 8 + 6] | ((unsigned)rowv[k * 8 + 7] << 16);
      *reinterpret_cast<uint4*>(dst + k * 8) = ov;
    }
  }
}

// ---------- SSD chunked scan via MFMA (round-11 body + early staging issue) ----------
// graw/xraw (16 loads) issued BEFORE matmul1 so their HBM latency drains under
// matmul1's MFMA+mask work. gzp stays in matmul2; matmul3 per-nt streamed
// (round-11 register profile everywhere else; peak ~223 regs < 256 cap).
__global__ __launch_bounds__(256, 2) void scan_chunk_kernel(
    const U16* __restrict__ xh_t, const U16* __restrict__ zxT,
    const U16* __restrict__ Bm, const U16* __restrict__ Cm,
    const U16* __restrict__ bm_t, const U16* __restrict__ cm_t,
    const float* __restrict__ decay4, const float* __restrict__ Dp,
    U16* __restrict__ hpart, U16* __restrict__ wacc,
    float* __restrict__ ylocal, float* __restrict__ aprod) {
  const int w = threadIdx.x >> 6, l = threadIdx.x & 63;
  const int bid = (blockIdx.x & 7) * 128 + (blockIdx.x >> 3);
  const int u = bid * 4 + w;
  const int hh = u & 31, ci = (u >> 5) & (NCH - 1), b = u >> 9;
  const int tl = l & 15, lg = l >> 4;

  __shared__ alignas(16) U16 MsmAll[4 * 64 * 72];
  __shared__ alignas(16) float decAll[4 * 256];
  U16* Msm = &MsmAll[w * 64 * 72];
  float* qsm = &decAll[w * 256];
  float* la2sm = qsm + 64;
  float* casm = qsm + 128;
  float* cfsm = qsm + 192;

  #pragma unroll
  for (int i = 0; i < 9; ++i)
    *reinterpret_cast<f32x4*>(reinterpret_cast<char*>(Msm) + (size_t)l * 144 + i * 16) =
        f32x4{0.f, 0.f, 0.f, 0.f};

  f32x4 hC[2][4] = {};
  f32x4 WB[2][4] = {};
  f32x4 corrp[2] = {};
  float ylac[2] = {0.f, 0.f}, dxac[2] = {0.f, 0.f};
  float capfx = 1.f;
  const size_t xrow = ((size_t)b * 1024 + hh * 32) * 4096;
  const size_t grow = ((size_t)b * D_PROJ_PAD + hh * 32) * 4096;
  const float* dbase = decay4 + ((size_t)(b * 32 + hh) * 4096) * 4;

  for (int sc = 0; sc < NSUB; ++sc) {
    const int lglob = ci * CL2 + sc * 64;
    const int r0g = b * 4096 + lglob;

    f32x4 dv = *reinterpret_cast<const f32x4*>(dbase + (size_t)(lglob + l) * 4);
    qsm[l] = dv[0];
    la2sm[l] = dv[1];
    casm[l] = dv[2];
    cfsm[l] = dv[3];
    const float cs = __shfl(dv[2], 63);

    // ---- EARLY ISSUE: staging raw loads (latency drains under matmul1) ----
    short8 graw[2][2], xraw[2][2];
    #pragma unroll
    for (int pt = 0; pt < 2; ++pt)
      #pragma unroll
      for (int kt = 0; kt < 2; ++kt) {
        size_t po = (size_t)(pt * 16 + tl) * 4096 + lglob + kt * 32 + lg * 8;
        graw[pt][kt] = *reinterpret_cast<const short8*>(zxT + grow + po);
        xraw[pt][kt] = *reinterpret_cast<const short8*>(xh_t + xrow + po);
      }

    // ---- matmul1 half A: si in {0,1} (7 tiles), batched fragment loads ----
    {
      f32x4 g[7] = {};
      #pragma unroll
      for (int k = 0; k < 2; ++k) {
        const size_t co = (size_t)k * 32 + lg * 8;
        bf16x8 af0 = *reinterpret_cast<const bf16x8*>(Bm + (size_t)(r0g + tl) * 64 + co);
        bf16x8 af1 = *reinterpret_cast<const bf16x8*>(Bm + (size_t)(r0g + 16 + tl) * 64 + co);
        bf16x8 cf0 = *reinterpret_cast<const bf16x8*>(Cm + (size_t)(r0g + tl) * 64 + co);
        bf16x8 cf1 = *reinterpret_cast<const bf16x8*>(Cm + (size_t)(r0g + 16 + tl) * 64 + co);
        bf16x8 cf2 = *reinterpret_cast<const bf16x8*>(Cm + (size_t)(r0g + 32 + tl) * 64 + co);
        bf16x8 cf3 = *reinterpret_cast<const bf16x8*>(Cm + (size_t)(r0g + 48 + tl) * 64 + co);
        __builtin_amdgcn_s_setprio(1);
        g[0] = __builtin_amdgcn_mfma_f32_16x16x32_bf16(af0, cf0, g[0], 0, 0, 0);
        g[1] = __builtin_amdgcn_mfma_f32_16x16x32_bf16(af0, cf1, g[1], 0, 0, 0);
        g[2] = __builtin_amdgcn_mfma_f32_16x16x32_bf16(af0, cf2, g[2], 0, 0, 0);
        g[3] = __builtin_amdgcn_mfma_f32_16x16x32_bf16(af0, cf3, g[3], 0, 0, 0);
        g[4] = __builtin_amdgcn_mfma_f32_16x16x32_bf16(af1, cf1, g[4], 0, 0, 0);
        g[5] = __builtin_amdgcn_mfma_f32_16x16x32_bf16(af1, cf2, g[5], 0, 0, 0);
        g[6] = __builtin_amdgcn_mfma_f32_16x16x32_bf16(af1, cf3, g[6], 0, 0, 0);
        __builtin_amdgcn_s_setprio(0);
      }
      f32x4 q0 = *reinterpret_cast<const f32x4*>(&qsm[lg * 4]);
      f32x4 q1 = *reinterpret_cast<const f32x4*>(&qsm[16 + lg * 4]);
      #pragma unroll
      for (int idx = 0; idx < 7; ++idx) {
        const int si = (idx < 4) ? 0 : 1;
        const int ti = (idx < 4) ? idx : (idx - 3);
        f32x4 q4 = si ? q1 : q0;
        float lat = la2sm[ti * 16 + tl];
        float v[4];
        #pragma unroll
        for (int r = 0; r < 4; ++r) {
          float val = g[idx][r] * exp2f(lat + q4[r]);
          if (si == ti) val = (lg * 4 + r <= tl) ? val : 0.f;
          v[r] = val;
        }
        uint2 pk;
        pk.x = (unsigned)f2bf(v[0]) | ((unsigned)f2bf(v[1]) << 16);
        pk.y = (unsigned)f2bf(v[2]) | ((unsigned)f2bf(v[3]) << 16);
        *reinterpret_cast<uint2*>(reinterpret_cast<char*>(Msm) +
                                  (size_t)(ti * 16 + tl) * 144 + (size_t)(si * 16 + lg * 4) * 2) = pk;
      }
    }
    // ---- matmul1 half B: si in {2,3} (3 tiles) ----
    {
      f32x4 g[3] = {};
      #pragma unroll
      for (int k = 0; k < 2; ++k) {
        const size_t co = (size_t)k * 32 + lg * 8;
        bf16x8 af2 = *reinterpret_cast<const bf16x8*>(Bm + (size_t)(r0g + 32 + tl) * 64 + co);
        bf16x8 af3 = *reinterpret_cast<const bf16x8*>(Bm + (size_t)(r0g + 48 + tl) * 64 + co);
        bf16x8 cf2 = *reinterpret_cast<const bf16x8*>(Cm + (size_t)(r0g + 32 + tl) * 64 + co);
        bf16x8 cf3 = *reinterpret_cast<const bf16x8*>(Cm + (size_t)(r0g + 48 + tl) * 64 + co);
        __builtin_amdgcn_s_setprio(1);
        g[0] = __builtin_amdgcn_mfma_f32_16x16x32_bf16(af2, cf2, g[0], 0, 0, 0);
        g[1] = __builtin_amdgcn_mfma_f32_16x16x32_bf16(af2, cf3, g[1], 0, 0, 0);
        g[2] = __builtin_amdgcn_mfma_f32_16x16x32_bf16(af3, cf3, g[2], 0, 0, 0);
        __builtin_amdgcn_s_setprio(0);
      }
      f32x4 q2 = *reinterpret_cast<const f32x4*>(&qsm[32 + lg * 4]);
      f32x4 q3 = *reinterpret_cast<const f32x4*>(&qsm[48 + lg * 4]);
      const int sis[3] = {2, 2, 3};
      const int tis[3] = {2, 3, 3};
      #pragma unroll
      for (int idx = 0; idx < 3; ++idx) {
        const int si = sis[idx], ti = tis[idx];
        f32x4 q4 = (si == 2) ? q2 : q3;
        float lat = la2sm[ti * 16 + tl];
        float v[4];
        #pragma unroll
        for (int r = 0; r < 4; ++r) {
          float val = g[idx][r] * exp2f(lat + q4[r]);
          if (si == ti) val = (lg * 4 + r <= tl) ? val : 0.f;
          v[r] = val;
        }
        uint2 pk;
        pk.x = (unsigned)f2bf(v[0]) | ((unsigned)f2bf(v[1]) << 16);
        pk.y = (unsigned)f2bf(v[2]) | ((unsigned)f2bf(v[3]) << 16);
        *reinterpret_cast<uint2*>(reinterpret_cast<char*>(Msm) +
                                  (size_t)(ti * 16 + tl) * 144 + (size_t)(si * 16 + lg * 4) * 2) = pk;
      }
    }

    // ---- scale staging (raws already landed); dxac here ----
    bf16x8 ga[2][2], xa[2][2];
    #pragma unroll
    for (int pt = 0; pt < 2; ++pt)
      #pragma unroll
      for (int kt = 0; kt < 2; ++kt) {
        const float* cap = &casm[kt * 32 + lg * 8];
        const float* cfp = &cfsm[kt * 32 + lg * 8];
        short8 gs, xs8;
        #pragma unroll
        for (int j = 0; j < 8; ++j) {
          float gf = bf2f((U16)graw[pt][kt][j]);
          float xf = bf2f((U16)xraw[pt][kt][j]);
          dxac[pt] = fmaf(gf, xf, dxac[pt]);
          gs[j] = (short)f2bf(gf * cap[j]);
          xs8[j] = (short)f2bf(xf * cfp[j]);
        }
        ga[pt][kt] = __builtin_bit_cast(bf16x8, gs);
        xa[pt][kt] = __builtin_bit_cast(bf16x8, xs8);
      }

    // ---- matmul2: Y = M X (X from xraw); gz preloaded batch; ylac ----
    {
      uint2 gzp[4][2];
      #pragma unroll
      for (int tt = 0; tt < 4; ++tt)
        #pragma unroll
        for (int pt = 0; pt < 2; ++pt)
          gzp[tt][pt] = *reinterpret_cast<const uint2*>(
              zxT + grow + (size_t)(pt * 16 + tl) * 4096 + lglob + tt * 16 + lg * 4);
      #pragma unroll
      for (int tt = 0; tt < 4; ++tt) {
        f32x4 y[2] = {f32x4{0.f, 0.f, 0.f, 0.f}, f32x4{0.f, 0.f, 0.f, 0.f}};
        __builtin_amdgcn_s_setprio(1);
        #pragma unroll
        for (int ks = 0; ks < 2; ++ks) {
          bf16x8 mf = *reinterpret_cast<const bf16x8*>(
              reinterpret_cast<char*>(Msm) + (size_t)(tt * 16 + tl) * 144 + (ks * 32 + lg * 8) * 2);
          #pragma unroll
          for (int pt = 0; pt < 2; ++pt)
            y[pt] = __builtin_amdgcn_mfma_f32_16x16x32_bf16(
                mf, __builtin_bit_cast(bf16x8, xraw[pt][ks]), y[pt], 0, 0, 0);
        }
        __builtin_amdgcn_s_setprio(0);
        #pragma unroll
        for (int pt = 0; pt < 2; ++pt) {
          uint2 gz2 = gzp[tt][pt];
          float gzv[4] = {bf2f((U16)(gz2.x & 0xffff)), bf2f((U16)(gz2.x >> 16)),
                          bf2f((U16)(gz2.y & 0xffff)), bf2f((U16)(gz2.y >> 16))};
          #pragma unroll
          for (int r = 0; r < 4; ++r)
            ylac[pt] = fmaf(gzv[r], y[pt][r], ylac[pt]);
        }
      }
    }

    // ---- matmul3 streamed per nt (batched fragment loads per nt) ----
    #pragma unroll
    for (int nt = 0; nt < 4; ++nt) {
      size_t cro = (size_t)(b * 64 + nt * 16 + tl) * 4096 + lglob;
      bf16x8 cb0 = *reinterpret_cast<const bf16x8*>(cm_t + cro + lg * 8);
      bf16x8 cb1 = *reinterpret_cast<const bf16x8*>(cm_t + cro + 32 + lg * 8);
      bf16x8 bb0 = *reinterpret_cast<const bf16x8*>(bm_t + cro + lg * 8);
      bf16x8 bb1 = *reinterpret_cast<const bf16x8*>(bm_t + cro + 32 + lg * 8);
      __builtin_amdgcn_s_setprio(1);
      #pragma unroll
      for (int pt = 0; pt < 2; ++pt) {
        f32x4 z4 = {0.f, 0.f, 0.f, 0.f};
        f32x4 ws = __builtin_amdgcn_mfma_f32_16x16x32_bf16(ga[pt][0], cb0, z4, 0, 0, 0);
        ws = __builtin_amdgcn_mfma_f32_16x16x32_bf16(ga[pt][1], cb1, ws, 0, 0, 0);
        f32x4 hs = __builtin_amdgcn_mfma_f32_16x16x32_bf16(xa[pt][0], bb0, z4, 0, 0, 0);
        hs = __builtin_amdgcn_mfma_f32_16x16x32_bf16(xa[pt][1], bb1, hs, 0, 0, 0);
        corrp[pt] = corrp[pt] + hC[pt][nt] * ws;
        WB[pt][nt] = WB[pt][nt] + ws * capfx;
        hC[pt][nt] = hC[pt][nt] * cs + hs;
      }
      __builtin_amdgcn_s_setprio(0);
    }
    capfx *= cs;
  }

  // ---- epilogue ----
  #pragma unroll
  for (int pt = 0; pt < 2; ++pt)
    #pragma unroll
    for (int nt = 0; nt < 4; ++nt) {
      size_t slot = (size_t)u * 2048 + (size_t)((pt * 4 + nt) * 64 + l) * 4;
      ushort4 hp, wp;
      hp.x = f2bf(hC[pt][nt][0]); hp.y = f2bf(hC[pt][nt][1]);
      hp.z = f2bf(hC[pt][nt][2]); hp.w = f2bf(hC[pt][nt][3]);
      wp.x = f2bf(WB[pt][nt][0]); wp.y = f2bf(WB[pt][nt][1]);
      wp.z = f2bf(WB[pt][nt][2]); wp.w = f2bf(WB[pt][nt][3]);
      *reinterpret_cast<ushort4*>(hpart + slot) = hp;
      *reinterpret_cast<ushort4*>(wacc + slot) = wp;
    }
  float corrv[2][4];
  #pragma unroll
  for (int pt = 0; pt < 2; ++pt)
    #pragma unroll
    for (int r = 0; r < 4; ++r) {
      float c = corrp[pt][r];
      c += __shfl_xor(c, 1); c += __shfl_xor(c, 2);
      c += __shfl_xor(c, 4); c += __shfl_xor(c, 8);
      corrv[pt][r] = c;
    }
  const float Dh = Dp[hh];
  float* ysm = qsm;
  #pragma unroll
  for (int pt = 0; pt < 2; ++pt) {
    float yv = ylac[pt] + Dh * dxac[pt];
    yv += __shfl_xor(yv, 16);
    yv += __shfl_xor(yv, 32);
    if (l < 16) ysm[pt * 16 + l] = yv;
  }
  if (tl == 0) {
    #pragma unroll
    for (int pt = 0; pt < 2; ++pt)
      #pragma unroll
      for (int r = 0; r < 4; ++r)
        ysm[pt * 16 + lg * 4 + r] += corrv[pt][r];
  }
  if (l < 32) ylocal[(size_t)u * 32 + l] = ysm[l];
  if (l == 0) aprod[u] = capfx;
}

// ---------- sequential combine across chunks (bf16 hpart/wacc) ----------
__global__ __launch_bounds__(256) void scan_combine_kernel(
    const U16* __restrict__ hpart, const U16* __restrict__ wacc,
    const float* __restrict__ ylocal, const float* __restrict__ aprod,
    float* __restrict__ yysum) {
  const int bh = blockIdx.x;
  const int b = bh >> 5, hh = bh & 31;
  const int w = threadIdx.x >> 6, l = threadIdx.x & 63;
  const int tl = l & 15, lg = l >> 4;
  __shared__ float csm[8][16];
  __shared__ float ylsm[32];
  const int pair0 = w * 2;
  f32x4 hr[2] = {};
  float cv[2][4] = {};
  for (int ci = 0; ci < NCH; ++ci) {
    int bx = (b * NCH + ci) * 32 + hh;
    size_t base = (size_t)bx * 2048 + (size_t)l * 4;
    float ap = aprod[bx];
    #pragma unroll
    for (int k = 0; k < 2; ++k) {
      size_t o = base + (size_t)(pair0 + k) * 256;
      ushort4 wraw = *reinterpret_cast<const ushort4*>(wacc + o);
      ushort4 praw = *reinterpret_cast<const ushort4*>(hpart + o);
      f32x4 wv = {bf2f(wraw.x), bf2f(wraw.y), bf2f(wraw.z), bf2f(wraw.w)};
      f32x4 pv = {bf2f(praw.x), bf2f(praw.y), bf2f(praw.z), bf2f(praw.w)};
      f32x4 a4 = hr[k] * wv;
      #pragma unroll
      for (int r = 0; r < 4; ++r) cv[k][r] += a4[r];
      hr[k] = hr[k] * ap + pv;
    }
  }
  #pragma unroll
  for (int k = 0; k < 2; ++k)
    #pragma unroll
    for (int r = 0; r < 4; ++r) {
      float c = cv[k][r];
      c += __shfl_xor(c, 1); c += __shfl_xor(c, 2);
      c += __shfl_xor(c, 4); c += __shfl_xor(c, 8);
      if (tl == 0) csm[pair0 + k][lg * 4 + r] = c;
    }
  if (threadIdx.x < 32) {
    float yl = 0.f;
    for (int ci = 0; ci < NCH; ++ci)
      yl += ylocal[(size_t)((b * NCH + ci) * 32 + hh) * 32 + threadIdx.x];
    ylsm[threadIdx.x] = yl;
  }
  __syncthreads();
  if (threadIdx.x < 32) {
    int p = threadIdx.x;
    int pt = p >> 4, pl = p & 15;
    float corr = csm[pt * 4 + 0][pl] + csm[pt * 4 + 1][pl] +
                 csm[pt * 4 + 2][pl] + csm[pt * 4 + 3][pl];
    yysum[(size_t)b * 1024 + hh * 32 + p] = ylsm[p] + corr;
  }
}

// ---------- folded epilogue ----------
__global__ __launch_bounds__(128) void final1_kernel(const float* __restrict__ tokpart,
                                                     const float* __restrict__ yysum,
                                                     const float* __restrict__ Wb,
                                                     const float* __restrict__ bb,
                                                     float* __restrict__ m2) {
  int b = blockIdx.x, j = blockIdx.y * 128 + threadIdx.x;
  float tm = 0.f;
  #pragma unroll
  for (int z = 0; z < 16; ++z) tm += tokpart[(z * 8 + b) * 512 + j];
  float s = 0.f;
  for (int d = 0; d < 1024; ++d) s += yysum[b * 1024 + d] * Wb[(size_t)d * 512 + j];
  m2[b * 512 + j] = (tm + s) * (1.f / (float)Lsz) + bb[j];
}

__global__ __launch_bounds__(256) void final2_kernel(const float* __restrict__ m2,
                                                     const float* __restrict__ Wo,
                                                     const float* __restrict__ bo,
                                                     float* __restrict__ out) {
  int b = blockIdx.x, o = blockIdx.y * 256 + threadIdx.x;
  float s = 0.f;
  for (int j = 0; j < 512; ++j) s += m2[b * 512 + j] * Wo[(size_t)j * 1024 + o];
  out[b * 1024 + o] = s + bo[o];
}

extern "C" void kernel_launch(void* const* d_in, const int* in_sizes, int n_in,
                              void* d_out, int out_size, void* d_ws, size_t ws_size,
                              hipStream_t stream) {
  const float* image = (const float*)d_in[0];
  const float* text = (const float*)d_in[1];
  const float* W_in = (const float*)d_in[2];
  const float* b_in = (const float*)d_in[3];
  const float* W_txt = (const float*)d_in[4];
  const float* b_txt = (const float*)d_in[5];
  const float* norm_w = (const float*)d_in[6];
  const float* norm_b = (const float*)d_in[7];
  const float* W_zx = (const float*)d_in[8];
  const float* b_zx = (const float*)d_in[9];
  const float* conv_w = (const float*)d_in[10];
  const float* conv_b = (const float*)d_in[11];
  const float* dt_bias = (const float*)d_in[12];
  const float* A_log = (const float*)d_in[13];
  const float* Dp = (const float*)d_in[14];
  const float* W_blk = (const float*)d_in[15];
  const float* b_blk = (const float*)d_in[16];
  const float* W_out = (const float*)d_in[17];
  const float* b_out = (const float*)d_in[18];
  float* out = (float*)d_out;

  char* ws = (char*)d_ws;
  size_t off = 0;
  auto take = [&](size_t bytes) {
    char* p = ws + off;
    off = (off + bytes + 255) & ~(size_t)255;
    return p;
  };
  U16* zxT = (U16*)take((size_t)Bsz * D_PROJ_PAD * 4096 * 2);
  U16* wt_in = (U16*)take((size_t)DIMV * HID * 2);
  U16* wt_zx = (U16*)take((size_t)D_PROJ_PAD * DIMV * 2);
  U16* tok_bf = (U16*)take((size_t)MROWS * DIMV * 2);
  U16* x_bf = (U16*)take((size_t)MROWS * DIMV * 2);
  U16* xh_t = (U16*)take((size_t)MROWS * D_INNER * 2);
  U16* bm_bf = (U16*)take((size_t)MROWS * 64 * 2);
  U16* cm_bf = (U16*)take((size_t)MROWS * 64 * 2);
  U16* bm_t = (U16*)take((size_t)MROWS * 64 * 2);
  U16* cm_t = (U16*)take((size_t)MROWS * 64 * 2);
  float* decay4 = (float*)take((size_t)256 * 4096 * 16);
  float* txtf = (float*)take(8 * 512 * 4);
  float* tokpart = (float*)take(16 * 8 * 512 * 4);
  float* yysum = (float*)take(8 * 1024 * 4);
  float* m2 = (float*)take(8 * 512 * 4);
  float* ylocal = (float*)take((size_t)4096 * 32 * 4);
  float* aprod = (float*)take((size_t)4096 * 4);
  U16* hpart = tok_bf;
  U16* wacc = x_bf;

  txt_kernel<<<8, 512, 0, stream>>>(text, W_txt, b_txt, txtf);
  transpose_cvt_kernel<<<dim3(DIMV / 32, HID / 32), dim3(32, 8), 0, stream>>>(W_in, wt_in, HID, DIMV, DIMV);
  transpose_cvt_kernel<<<dim3(D_PROJ_PAD / 32, DIMV / 32), dim3(32, 8), 0, stream>>>(W_zx, wt_zx, DIMV, D_PROJ, D_PROJ_PAD);

  gemm_kernel<1, 1, 0><<<1024, 256, 0, stream>>>(
      (const void*)image, wt_in, tok_bf, b_in, txtf, MROWS, HID, DIMV, 4);
  tokpart_kernel<<<dim3(8, 2, 16), 256, 0, stream>>>(tok_bf, tokpart);
  ln_kernel<<<MROWS, 128, 0, stream>>>(tok_bf, x_bf, norm_w, norm_b);

  gemm_kernel<0, 0, 1><<<4608, 256, 0, stream>>>(
      (const void*)x_bf, wt_zx, zxT, b_zx, nullptr, MROWS, DIMV, D_PROJ, 18);

  decay_kernel<<<512, 256, 0, stream>>>(zxT, dt_bias, A_log, decay4);
  conv_t_kernel<<<dim3(16, 18, 8), 256, 0, stream>>>(zxT, conv_w, conv_b,
                                                     xh_t, bm_t, cm_t, bm_bf, cm_bf);

  scan_chunk_kernel<<<1024, 256, 0, stream>>>(xh_t, zxT, bm_bf, cm_bf, bm_t, cm_t,
                                              decay4, Dp, hpart, wacc, ylocal, aprod);
  scan_combine_kernel<<<256, 256, 0, stream>>>(hpart, wacc, ylocal, aprod, yysum);

  final1_kernel<<<dim3(8, 4), 128, 0, stream>>>(tokpart, yysum, W_blk, b_blk, m2);
  final2_kernel<<<dim3(8, 4), 256, 0, stream>>>(m2, W_out, b_out, out);
}

// Round 14
// 533.963 us; speedup vs baseline: 1.0472x; 1.0064x over previous
//
#include <hip/hip_runtime.h>

typedef unsigned short U16;
typedef __attribute__((ext_vector_type(4))) float f32x4;
typedef __attribute__((ext_vector_type(8))) short short8;
typedef __attribute__((ext_vector_type(8))) __bf16 bf16x8;

#define Bsz 8
#define Lsz 4096
#define HID 1024
#define DIMV 512
#define D_INNER 1024
#define NHEADS 32
#define HEADDIM 32
#define D_STATE 64
#define CONV_DIM 1152
#define D_PROJ 2208
#define D_PROJ_PAD 2304
#define MROWS 32768
#define CL2 256        // scan chunk per unit
#define NSUB 4         // sub-chunks of 64
#define NCH 16         // Lsz / CL2

__device__ __forceinline__ float bf2f(U16 u) {
  return __builtin_bit_cast(float, (unsigned)(((unsigned)u) << 16));
}
__device__ __forceinline__ U16 f2bf(float f) {
  unsigned u = __builtin_bit_cast(unsigned, f);
  return (U16)((u + 0x7FFFu + ((u >> 16) & 1u)) >> 16);
}
__device__ __forceinline__ void gload_lds16(const void* g, void* l) {
  __builtin_amdgcn_global_load_lds((const __attribute__((address_space(1))) unsigned int*)g,
                                   (__attribute__((address_space(3))) unsigned int*)l, 16, 0, 0);
}
__device__ __forceinline__ float fast_silu(float v) {
  return v * __builtin_amdgcn_rcpf(1.f + __expf(-v));
}

// ---------- tiny txt GEMM ----------
__global__ __launch_bounds__(512) void txt_kernel(const float* __restrict__ text,
                                                  const float* __restrict__ Wt,
                                                  const float* __restrict__ bt,
                                                  float* __restrict__ txt) {
  int b = blockIdx.x, j = threadIdx.x;
  float s = bt[j];
  const float* tp = text + (size_t)b * 77 * 768;
  for (int k = 0; k < 768; ++k) s += tp[k] * Wt[(size_t)k * 512 + j];
  txt[b * 512 + j] = s;
}

// ---------- transpose + convert weights ----------
__global__ __launch_bounds__(256) void transpose_cvt_kernel(const float* __restrict__ in,
                                                            U16* __restrict__ out,
                                                            int K, int N, int Npad) {
  __shared__ U16 tile[32][33];
  int n0 = blockIdx.x * 32, k0 = blockIdx.y * 32;
  int tx = threadIdx.x, ty = threadIdx.y;
  #pragma unroll
  for (int i = 0; i < 4; ++i) {
    int k = k0 + ty + i * 8, n = n0 + tx;
    float v = (n < N) ? in[(size_t)k * N + n] : 0.f;
    tile[ty + i * 8][tx] = f2bf(v);
  }
  __syncthreads();
  #pragma unroll
  for (int i = 0; i < 4; ++i) {
    int n = n0 + ty + i * 8;
    out[(size_t)n * K + k0 + tx] = tile[tx][ty + i * 8];
  }
}

// ---------- bf16 MFMA GEMM ----------
// EPI=1 (GEMM1): adds txt bias and emits per-(m-tile) column partial sums.
// TRANS=1 (GEMM2): writes C transposed as zx_t[b][c][l], bias+silu(z) fused.
template <int EPI, int AF32, int TRANS>
__global__ __launch_bounds__(256) void gemm_kernel(const void* __restrict__ Ap,
                                                   const U16* __restrict__ Bt,
                                                   U16* __restrict__ C,
                                                   const float* __restrict__ bias,
                                                   const float* __restrict__ txtv,
                                                   float* __restrict__ colp,
                                                   int M, int K, int Nreal, int NT) {
  __shared__ alignas(16) U16 smem[128 * 128];
  U16* As = smem;
  U16* Bs = smem + 128 * 64;
  const int tid = threadIdx.x;
  const int wid = tid >> 6, lane = tid & 63;
  const int lhi = lane >> 4, llo = lane & 15;
  const int xcd = blockIdx.x & 7, slot = blockIdx.x >> 3;
  const int m0 = (xcd + 8 * (slot / NT)) * 128;
  const int n0 = (slot % NT) * 128;
  const int wr = wid >> 1, wc = wid & 1;
  f32x4 acc[4][4] = {};

  for (int k0 = 0; k0 < K; k0 += 64) {
    __syncthreads();
    if constexpr (AF32) {
      const float* Af = (const float*)Ap;
      #pragma unroll
      for (int is = 0; is < 4; ++is) {
        int q = is * 256 + tid;
        int r = q >> 3, cl = q & 7;
        int cg = cl ^ (r & 7);
        const float* src = Af + (size_t)(m0 + r) * K + k0 + cg * 8;
        f32x4 v0 = *reinterpret_cast<const f32x4*>(src);
        f32x4 v1 = *reinterpret_cast<const f32x4*>(src + 4);
        short8 o;
        #pragma unroll
        for (int j = 0; j < 4; ++j) {
          o[j] = (short)f2bf(v0[j]);
          o[j + 4] = (short)f2bf(v1[j]);
        }
        *reinterpret_cast<short8*>(&As[q * 8]) = o;
      }
    } else {
      const U16* A = (const U16*)Ap;
      #pragma unroll
      for (int is = 0; is < 4; ++is) {
        int qbase = is * 256 + wid * 64;
        int q = qbase + lane;
        int r = q >> 3;
        int cc = (q & 7) ^ (r & 7);
        gload_lds16(A + (size_t)(m0 + r) * K + k0 + cc * 8, &As[qbase * 8]);
      }
    }
    #pragma unroll
    for (int is = 0; is < 4; ++is) {
      int qbase = is * 256 + wid * 64;
      int q = qbase + lane;
      int r = q >> 3;
      int cc = (q & 7) ^ (r & 7);
      gload_lds16(Bt + (size_t)(n0 + r) * K + k0 + cc * 8, &Bs[qbase * 8]);
    }
    __syncthreads();
    #pragma unroll
    for (int kk = 0; kk < 64; kk += 32) {
      bf16x8 av[4], bv[4];
      #pragma unroll
      for (int i = 0; i < 4; ++i) {
        int ra = wr * 64 + i * 16 + llo;
        short8 a = *reinterpret_cast<const short8*>(
            &As[ra * 64 + ((((kk >> 3) + lhi) ^ (ra & 7)) << 3)]);
        av[i] = __builtin_bit_cast(bf16x8, a);
        int rb = wc * 64 + i * 16 + llo;
        short8 b = *reinterpret_cast<const short8*>(
            &Bs[rb * 64 + ((((kk >> 3) + lhi) ^ (rb & 7)) << 3)]);
        bv[i] = __builtin_bit_cast(bf16x8, b);
      }
      #pragma unroll
      for (int i = 0; i < 4; ++i)
        #pragma unroll
        for (int j = 0; j < 4; ++j)
          acc[i][j] = __builtin_amdgcn_mfma_f32_16x16x32_bf16(av[i], bv[j], acc[i][j], 0, 0, 0);
    }
  }
  const int b = m0 >> 12;
  if constexpr (TRANS) {
    __syncthreads();
    U16* T = smem;
    #pragma unroll
    for (int i = 0; i < 4; ++i) {
      #pragma unroll
      for (int j = 0; j < 4; ++j) {
        int c_loc = wc * 64 + j * 16 + llo;
        int cg = n0 + c_loc;
        float badd = (cg < D_PROJ) ? bias[cg] : 0.f;
        int q = wr * 16 + i * 4 + lhi;
        int qs = q ^ ((c_loc & 15) << 1);
        U16 pk[4];
        #pragma unroll
        for (int r = 0; r < 4; ++r) {
          float v = acc[i][j][r] + badd;
          if (cg < 1024) v = fast_silu(v);
          pk[r] = f2bf(v);
        }
        uint2 p2;
        p2.x = (unsigned)pk[0] | ((unsigned)pk[1] << 16);
        p2.y = (unsigned)pk[2] | ((unsigned)pk[3] << 16);
        *reinterpret_cast<uint2*>(&T[c_loc * 128 + qs * 4]) = p2;
      }
    }
    __syncthreads();
    const int l0 = m0 & 4095;
    #pragma unroll
    for (int cs = 0; cs < 8; ++cs) {
      int c = cs * 16 + (tid >> 4);
      int gch = n0 + c;
      int kp = (tid & 15) * 2;
      int q0 = kp ^ ((c & 15) << 1);
      int q1 = (kp + 1) ^ ((c & 15) << 1);
      uint2 a = *reinterpret_cast<const uint2*>(&T[c * 128 + q0 * 4]);
      uint2 bq = *reinterpret_cast<const uint2*>(&T[c * 128 + q1 * 4]);
      if (gch < D_PROJ) {
        uint4 oo;
        oo.x = a.x; oo.y = a.y; oo.z = bq.x; oo.w = bq.y;
        *reinterpret_cast<uint4*>(C + ((size_t)b * D_PROJ_PAD + gch) * 4096 + l0 + kp * 4) = oo;
      }
    }
  } else {
    float cp[4] = {0.f, 0.f, 0.f, 0.f};
    #pragma unroll
    for (int i = 0; i < 4; ++i) {
      int rbase = m0 + wr * 64 + i * 16 + lhi * 4;
      #pragma unroll
      for (int j = 0; j < 4; ++j) {
        int cg = n0 + wc * 64 + j * 16 + llo;
        if (cg < Nreal) {
          float badd = bias[cg] + (EPI ? txtv[b * 512 + cg] : 0.f);
          #pragma unroll
          for (int r = 0; r < 4; ++r) {
            float v = acc[i][j][r] + badd;
            C[(size_t)(rbase + r) * Nreal + cg] = f2bf(v);
            if constexpr (EPI) cp[j] += v;
          }
        }
      }
    }
    if constexpr (EPI) {
      // column partial sums for this 128x128 tile (exact f32 of written values)
      #pragma unroll
      for (int j = 0; j < 4; ++j) {
        cp[j] += __shfl_xor(cp[j], 16);
        cp[j] += __shfl_xor(cp[j], 32);
      }
      __syncthreads();  // all waves done with As/Bs
      float* colsm = reinterpret_cast<float*>(smem);
      if (lane < 16) {
        #pragma unroll
        for (int j = 0; j < 4; ++j)
          colsm[wr * 128 + wc * 64 + j * 16 + lane] = cp[j];
      }
      __syncthreads();
      if (tid < 128)
        colp[(size_t)(m0 >> 7) * 512 + n0 + tid] = colsm[tid] + colsm[128 + tid];
    }
  }
}

// ---------- LayerNorm ----------
__global__ __launch_bounds__(128) void ln_kernel(const U16* __restrict__ tok,
                                                 U16* __restrict__ xo,
                                                 const float* __restrict__ w,
                                                 const float* __restrict__ bb) {
  int row = blockIdx.x, tid = threadIdx.x;
  const U16* rp = tok + (size_t)row * 512 + tid * 4;
  uint2 raw = *reinterpret_cast<const uint2*>(rp);
  float f0 = bf2f((U16)(raw.x & 0xffff)), f1 = bf2f((U16)(raw.x >> 16));
  float f2 = bf2f((U16)(raw.y & 0xffff)), f3 = bf2f((U16)(raw.y >> 16));
  float s = f0 + f1 + f2 + f3;
  float q = f0 * f0 + f1 * f1 + f2 * f2 + f3 * f3;
  for (int m = 1; m < 64; m <<= 1) { s += __shfl_xor(s, m); q += __shfl_xor(q, m); }
  __shared__ float ss[2], qq[2];
  if ((tid & 63) == 0) { ss[tid >> 6] = s; qq[tid >> 6] = q; }
  __syncthreads();
  s = ss[0] + ss[1]; q = qq[0] + qq[1];
  float mu = s * (1.f / 512.f);
  float var = q * (1.f / 512.f) - mu * mu;
  float rs = rsqrtf(var + 1e-5f);
  int j0 = tid * 4;
  unsigned c0 = f2bf((f0 - mu) * rs * w[j0] + bb[j0]);
  unsigned c1 = f2bf((f1 - mu) * rs * w[j0 + 1] + bb[j0 + 1]);
  unsigned c2 = f2bf((f2 - mu) * rs * w[j0 + 2] + bb[j0 + 2]);
  unsigned c3 = f2bf((f3 - mu) * rs * w[j0 + 3] + bb[j0 + 3]);
  uint2 o; o.x = c0 | (c1 << 16); o.y = c2 | (c3 << 16);
  *reinterpret_cast<uint2*>(xo + (size_t)row * 512 + j0) = o;
}

// ---------- decay precompute from zx_t ----------
__global__ __launch_bounds__(256) void decay_kernel(const U16* __restrict__ zxT,
                                                    const float* __restrict__ dt_bias,
                                                    const float* __restrict__ A_log,
                                                    float* __restrict__ decay4) {
  const int sc = blockIdx.x;
  const int w = threadIdx.x >> 6, l = threadIdx.x & 63;
  const int r0 = sc * 64;
  const int b = r0 >> 12, l0 = r0 & 4095;
  #pragma unroll
  for (int i = 0; i < 8; ++i) {
    int hh = w * 8 + i;
    float raw = bf2f(zxT[((size_t)b * D_PROJ_PAD + 2176 + hh) * 4096 + l0 + l]) + dt_bias[hh];
    float dt = (raw > 20.f) ? raw : log1pf(__expf(raw));
    float A = -__expf(A_log[hh]);
    float ldA2 = dt * A * 1.44269504088896f;
    float ldt2 = __log2f(dt);
    float la = ldA2;
    #pragma unroll
    for (int d = 1; d < 64; d <<= 1) {
      float o = __shfl_up(la, d);
      if (l >= d) la += o;
    }
    float laend = __shfl(la, 63);
    f32x4 v = {ldt2 - la, la, exp2f(la), exp2f(laend + ldt2 - la)};
    *reinterpret_cast<f32x4*>(decay4 + ((size_t)(b * 32 + hh) * 4096 + l0 + l) * 4) = v;
  }
}

// ---------- conv(K=4)+silu on transposed layout ----------
__global__ __launch_bounds__(256) void conv_t_kernel(
    const U16* __restrict__ zxT, const float* __restrict__ cw,
    const float* __restrict__ cb, U16* __restrict__ xh_t,
    U16* __restrict__ bm_t, U16* __restrict__ cm_t,
    U16* __restrict__ Bmo, U16* __restrict__ Cmo) {
  __shared__ U16 Tc[64 * 264];
  const int lc = blockIdx.x, cg = blockIdx.y, b = blockIdx.z;
  const int tid = threadIdx.x;
  const int cl = tid & 63, ls = tid >> 6;
  const int cc2 = cg * 64 + cl;
  const int l0 = lc * 256 + ls * 64;
  const U16* row = zxT + ((size_t)b * D_PROJ_PAD + 1024 + cc2) * 4096;

  U16 arr[72];
  {
    const U16* src = row + l0 - 8;
    #pragma unroll
    for (int k = 0; k < 9; ++k) {
      uint4 rv;
      if (l0 == 0 && k == 0) {
        rv.x = rv.y = rv.z = rv.w = 0u;
      } else {
        rv = *reinterpret_cast<const uint4*>(src + k * 8);
      }
      arr[k * 8 + 0] = (U16)(rv.x & 0xffff); arr[k * 8 + 1] = (U16)(rv.x >> 16);
      arr[k * 8 + 2] = (U16)(rv.y & 0xffff); arr[k * 8 + 3] = (U16)(rv.y >> 16);
      arr[k * 8 + 4] = (U16)(rv.z & 0xffff); arr[k * 8 + 5] = (U16)(rv.z >> 16);
      arr[k * 8 + 6] = (U16)(rv.w & 0xffff); arr[k * 8 + 7] = (U16)(rv.w >> 16);
    }
  }
  const float4 w4 = *reinterpret_cast<const float4*>(cw + cc2 * 4);
  const float cbv = cb[cc2];
  U16 o[64];
  #pragma unroll
  for (int j = 0; j < 64; ++j) {
    float acc = cbv + bf2f(arr[j + 5]) * w4.x + bf2f(arr[j + 6]) * w4.y +
                bf2f(arr[j + 7]) * w4.z + bf2f(arr[j + 8]) * w4.w;
    o[j] = f2bf(fast_silu(acc));
  }
  {
    U16* dst;
    if (cc2 < 1024)      dst = xh_t + ((size_t)b * 1024 + cc2) * 4096 + l0;
    else if (cc2 < 1088) dst = bm_t + ((size_t)(b * 64 + (cc2 - 1024))) * 4096 + l0;
    else                 dst = cm_t + ((size_t)(b * 64 + (cc2 - 1088))) * 4096 + l0;
    #pragma unroll
    for (int k = 0; k < 8; ++k) {
      uint4 ov;
      ov.x = (unsigned)o[k * 8 + 0] | ((unsigned)o[k * 8 + 1] << 16);
      ov.y = (unsigned)o[k * 8 + 2] | ((unsigned)o[k * 8 + 3] << 16);
      ov.z = (unsigned)o[k * 8 + 4] | ((unsigned)o[k * 8 + 5] << 16);
      ov.w = (unsigned)o[k * 8 + 6] | ((unsigned)o[k * 8 + 7] << 16);
      *reinterpret_cast<uint4*>(dst + k * 8) = ov;
    }
  }
  if (cg >= 16) {
    #pragma unroll
    for (int k = 0; k < 8; ++k) {
      uint4 ov;
      ov.x = (unsigned)o[k * 8 + 0] | ((unsigned)o[k * 8 + 1] << 16);
      ov.y = (unsigned)o[k * 8 + 2] | ((unsigned)o[k * 8 + 3] << 16);
      ov.z = (unsigned)o[k * 8 + 4] | ((unsigned)o[k * 8 + 5] << 16);
      ov.w = (unsigned)o[k * 8 + 6] | ((unsigned)o[k * 8 + 7] << 16);
      *reinterpret_cast<uint4*>(&Tc[cl * 264 + ls * 64 + k * 8]) = ov;
    }
    __syncthreads();
    U16* outp = (cg == 16) ? Bmo : Cmo;
    const int lt = tid;
    U16 rowv[64];
    #pragma unroll
    for (int n = 0; n < 64; ++n) rowv[n] = Tc[n * 264 + lt];
    U16* dst = outp + ((size_t)b * 4096 + lc * 256 + lt) * 64;
    #pragma unroll
    for (int k = 0; k < 8; ++k) {
      uint4 ov;
      ov.x = (unsigned)rowv[k * 8 + 0] | ((unsigned)rowv[k * 8 + 1] << 16);
      ov.y = (unsigned)rowv[k * 8 + 2] | ((unsigned)rowv[k * 8 + 3] << 16);
      ov.z = (unsigned)rowv[k * 8 + 4] | ((unsigned)rowv[k * 8 + 5] << 16);
      ov.w = (unsigned)rowv[k * 8 + 6] | ((unsigned)rowv[k * 8 + 7] << 16);
      *reinterpret_cast<uint4*>(dst + k * 8) = ov;
    }
  }
}

// ---------- SSD chunked scan via MFMA (round-13 body + gzp in early batch) ----------
__global__ __launch_bounds__(256, 2) void scan_chunk_kernel(
    const U16* __restrict__ xh_t, const U16* __restrict__ zxT,
    const U16* __restrict__ Bm, const U16* __restrict__ Cm,
    const U16* __restrict__ bm_t, const U16* __restrict__ cm_t,
    const float* __restrict__ decay4, const float* __restrict__ Dp,
    U16* __restrict__ hpart, U16* __restrict__ wacc,
    float* __restrict__ ylocal, float* __restrict__ aprod) {
  const int w = threadIdx.x >> 6, l = threadIdx.x & 63;
  const int bid = (blockIdx.x & 7) * 128 + (blockIdx.x >> 3);
  const int u = bid * 4 + w;
  const int hh = u & 31, ci = (u >> 5) & (NCH - 1), b = u >> 9;
  const int tl = l & 15, lg = l >> 4;

  __shared__ alignas(16) U16 MsmAll[4 * 64 * 72];
  __shared__ alignas(16) float decAll[4 * 256];
  U16* Msm = &MsmAll[w * 64 * 72];
  float* qsm = &decAll[w * 256];
  float* la2sm = qsm + 64;
  float* casm = qsm + 128;
  float* cfsm = qsm + 192;

  #pragma unroll
  for (int i = 0; i < 9; ++i)
    *reinterpret_cast<f32x4*>(reinterpret_cast<char*>(Msm) + (size_t)l * 144 + i * 16) =
        f32x4{0.f, 0.f, 0.f, 0.f};

  f32x4 hC[2][4] = {};
  f32x4 WB[2][4] = {};
  f32x4 corrp[2] = {};
  float ylac[2] = {0.f, 0.f}, dxac[2] = {0.f, 0.f};
  float capfx = 1.f;
  const size_t xrow = ((size_t)b * 1024 + hh * 32) * 4096;
  const size_t grow = ((size_t)b * D_PROJ_PAD + hh * 32) * 4096;
  const float* dbase = decay4 + ((size_t)(b * 32 + hh) * 4096) * 4;

  for (int sc = 0; sc < NSUB; ++sc) {
    const int lglob = ci * CL2 + sc * 64;
    const int r0g = b * 4096 + lglob;

    f32x4 dv = *reinterpret_cast<const f32x4*>(dbase + (size_t)(lglob + l) * 4);
    qsm[l] = dv[0];
    la2sm[l] = dv[1];
    casm[l] = dv[2];
    cfsm[l] = dv[3];
    const float cs = __shfl(dv[2], 63);

    // ---- EARLY ISSUE: staging raws + gz (latency drains under matmul1) ----
    short8 graw[2][2], xraw[2][2];
    uint2 gzp[4][2];
    #pragma unroll
    for (int pt = 0; pt < 2; ++pt)
      #pragma unroll
      for (int kt = 0; kt < 2; ++kt) {
        size_t po = (size_t)(pt * 16 + tl) * 4096 + lglob + kt * 32 + lg * 8;
        graw[pt][kt] = *reinterpret_cast<const short8*>(zxT + grow + po);
        xraw[pt][kt] = *reinterpret_cast<const short8*>(xh_t + xrow + po);
      }
    #pragma unroll
    for (int tt = 0; tt < 4; ++tt)
      #pragma unroll
      for (int pt = 0; pt < 2; ++pt)
        gzp[tt][pt] = *reinterpret_cast<const uint2*>(
            zxT + grow + (size_t)(pt * 16 + tl) * 4096 + lglob + tt * 16 + lg * 4);

    // ---- matmul1 half A: si in {0,1} (7 tiles) ----
    {
      f32x4 g[7] = {};
      #pragma unroll
      for (int k = 0; k < 2; ++k) {
        const size_t co = (size_t)k * 32 + lg * 8;
        bf16x8 af0 = *reinterpret_cast<const bf16x8*>(Bm + (size_t)(r0g + tl) * 64 + co);
        bf16x8 af1 = *reinterpret_cast<const bf16x8*>(Bm + (size_t)(r0g + 16 + tl) * 64 + co);
        bf16x8 cf0 = *reinterpret_cast<const bf16x8*>(Cm + (size_t)(r0g + tl) * 64 + co);
        bf16x8 cf1 = *reinterpret_cast<const bf16x8*>(Cm + (size_t)(r0g + 16 + tl) * 64 + co);
        bf16x8 cf2 = *reinterpret_cast<const bf16x8*>(Cm + (size_t)(r0g + 32 + tl) * 64 + co);
        bf16x8 cf3 = *reinterpret_cast<const bf16x8*>(Cm + (size_t)(r0g + 48 + tl) * 64 + co);
        __builtin_amdgcn_s_setprio(1);
        g[0] = __builtin_amdgcn_mfma_f32_16x16x32_bf16(af0, cf0, g[0], 0, 0, 0);
        g[1] = __builtin_amdgcn_mfma_f32_16x16x32_bf16(af0, cf1, g[1], 0, 0, 0);
        g[2] = __builtin_amdgcn_mfma_f32_16x16x32_bf16(af0, cf2, g[2], 0, 0, 0);
        g[3] = __builtin_amdgcn_mfma_f32_16x16x32_bf16(af0, cf3, g[3], 0, 0, 0);
        g[4] = __builtin_amdgcn_mfma_f32_16x16x32_bf16(af1, cf1, g[4], 0, 0, 0);
        g[5] = __builtin_amdgcn_mfma_f32_16x16x32_bf16(af1, cf2, g[5], 0, 0, 0);
        g[6] = __builtin_amdgcn_mfma_f32_16x16x32_bf16(af1, cf3, g[6], 0, 0, 0);
        __builtin_amdgcn_s_setprio(0);
      }
      f32x4 q0 = *reinterpret_cast<const f32x4*>(&qsm[lg * 4]);
      f32x4 q1 = *reinterpret_cast<const f32x4*>(&qsm[16 + lg * 4]);
      #pragma unroll
      for (int idx = 0; idx < 7; ++idx) {
        const int si = (idx < 4) ? 0 : 1;
        const int ti = (idx < 4) ? idx : (idx - 3);
        f32x4 q4 = si ? q1 : q0;
        float lat = la2sm[ti * 16 + tl];
        float v[4];
        #pragma unroll
        for (int r = 0; r < 4; ++r) {
          float val = g[idx][r] * exp2f(lat + q4[r]);
          if (si == ti) val = (lg * 4 + r <= tl) ? val : 0.f;
          v[r] = val;
        }
        uint2 pk;
        pk.x = (unsigned)f2bf(v[0]) | ((unsigned)f2bf(v[1]) << 16);
        pk.y = (unsigned)f2bf(v[2]) | ((unsigned)f2bf(v[3]) << 16);
        *reinterpret_cast<uint2*>(reinterpret_cast<char*>(Msm) +
                                  (size_t)(ti * 16 + tl) * 144 + (size_t)(si * 16 + lg * 4) * 2) = pk;
      }
    }
    // ---- matmul1 half B: si in {2,3} (3 tiles) ----
    {
      f32x4 g[3] = {};
      #pragma unroll
      for (int k = 0; k < 2; ++k) {
        const size_t co = (size_t)k * 32 + lg * 8;
        bf16x8 af2 = *reinterpret_cast<const bf16x8*>(Bm + (size_t)(r0g + 32 + tl) * 64 + co);
        bf16x8 af3 = *reinterpret_cast<const bf16x8*>(Bm + (size_t)(r0g + 48 + tl) * 64 + co);
        bf16x8 cf2 = *reinterpret_cast<const bf16x8*>(Cm + (size_t)(r0g + 32 + tl) * 64 + co);
        bf16x8 cf3 = *reinterpret_cast<const bf16x8*>(Cm + (size_t)(r0g + 48 + tl) * 64 + co);
        __builtin_amdgcn_s_setprio(1);
        g[0] = __builtin_amdgcn_mfma_f32_16x16x32_bf16(af2, cf2, g[0], 0, 0, 0);
        g[1] = __builtin_amdgcn_mfma_f32_16x16x32_bf16(af2, cf3, g[1], 0, 0, 0);
        g[2] = __builtin_amdgcn_mfma_f32_16x16x32_bf16(af3, cf3, g[2], 0, 0, 0);
        __builtin_amdgcn_s_setprio(0);
      }
      f32x4 q2 = *reinterpret_cast<const f32x4*>(&qsm[32 + lg * 4]);
      f32x4 q3 = *reinterpret_cast<const f32x4*>(&qsm[48 + lg * 4]);
      const int sis[3] = {2, 2, 3};
      const int tis[3] = {2, 3, 3};
      #pragma unroll
      for (int idx = 0; idx < 3; ++idx) {
        const int si = sis[idx], ti = tis[idx];
        f32x4 q4 = (si == 2) ? q2 : q3;
        float lat = la2sm[ti * 16 + tl];
        float v[4];
        #pragma unroll
        for (int r = 0; r < 4; ++r) {
          float val = g[idx][r] * exp2f(lat + q4[r]);
          if (si == ti) val = (lg * 4 + r <= tl) ? val : 0.f;
          v[r] = val;
        }
        uint2 pk;
        pk.x = (unsigned)f2bf(v[0]) | ((unsigned)f2bf(v[1]) << 16);
        pk.y = (unsigned)f2bf(v[2]) | ((unsigned)f2bf(v[3]) << 16);
        *reinterpret_cast<uint2*>(reinterpret_cast<char*>(Msm) +
                                  (size_t)(ti * 16 + tl) * 144 + (size_t)(si * 16 + lg * 4) * 2) = pk;
      }
    }

    // ---- scale staging (raws already landed); dxac here ----
    bf16x8 ga[2][2], xa[2][2];
    #pragma unroll
    for (int pt = 0; pt < 2; ++pt)
      #pragma unroll
      for (int kt = 0; kt < 2; ++kt) {
        const float* cap = &casm[kt * 32 + lg * 8];
        const float* cfp = &cfsm[kt * 32 + lg * 8];
        short8 gs, xs8;
        #pragma unroll
        for (int j = 0; j < 8; ++j) {
          float gf = bf2f((U16)graw[pt][kt][j]);
          float xf = bf2f((U16)xraw[pt][kt][j]);
          dxac[pt] = fmaf(gf, xf, dxac[pt]);
          gs[j] = (short)f2bf(gf * cap[j]);
          xs8[j] = (short)f2bf(xf * cfp[j]);
        }
        ga[pt][kt] = __builtin_bit_cast(bf16x8, gs);
        xa[pt][kt] = __builtin_bit_cast(bf16x8, xs8);
      }

    // ---- matmul2: Y = M X (X from xraw); ylac ----
    #pragma unroll
    for (int tt = 0; tt < 4; ++tt) {
      f32x4 y[2] = {f32x4{0.f, 0.f, 0.f, 0.f}, f32x4{0.f, 0.f, 0.f, 0.f}};
      __builtin_amdgcn_s_setprio(1);
      #pragma unroll
      for (int ks = 0; ks < 2; ++ks) {
        bf16x8 mf = *reinterpret_cast<const bf16x8*>(
            reinterpret_cast<char*>(Msm) + (size_t)(tt * 16 + tl) * 144 + (ks * 32 + lg * 8) * 2);
        #pragma unroll
        for (int pt = 0; pt < 2; ++pt)
          y[pt] = __builtin_amdgcn_mfma_f32_16x16x32_bf16(
              mf, __builtin_bit_cast(bf16x8, xraw[pt][ks]), y[pt], 0, 0, 0);
      }
      __builtin_amdgcn_s_setprio(0);
      #pragma unroll
      for (int pt = 0; pt < 2; ++pt) {
        uint2 gz2 = gzp[tt][pt];
        float gzv[4] = {bf2f((U16)(gz2.x & 0xffff)), bf2f((U16)(gz2.x >> 16)),
                        bf2f((U16)(gz2.y & 0xffff)), bf2f((U16)(gz2.y >> 16))};
        #pragma unroll
        for (int r = 0; r < 4; ++r)
          ylac[pt] = fmaf(gzv[r], y[pt][r], ylac[pt]);
      }
    }

    // ---- matmul3 streamed per nt (batched fragment loads per nt) ----
    #pragma unroll
    for (int nt = 0; nt < 4; ++nt) {
      size_t cro = (size_t)(b * 64 + nt * 16 + tl) * 4096 + lglob;
      bf16x8 cb0 = *reinterpret_cast<const bf16x8*>(cm_t + cro + lg * 8);
      bf16x8 cb1 = *reinterpret_cast<const bf16x8*>(cm_t + cro + 32 + lg * 8);
      bf16x8 bb0 = *reinterpret_cast<const bf16x8*>(bm_t + cro + lg * 8);
      bf16x8 bb1 = *reinterpret_cast<const bf16x8*>(bm_t + cro + 32 + lg * 8);
      __builtin_amdgcn_s_setprio(1);
      #pragma unroll
      for (int pt = 0; pt < 2; ++pt) {
        f32x4 z4 = {0.f, 0.f, 0.f, 0.f};
        f32x4 ws = __builtin_amdgcn_mfma_f32_16x16x32_bf16(ga[pt][0], cb0, z4, 0, 0, 0);
        ws = __builtin_amdgcn_mfma_f32_16x16x32_bf16(ga[pt][1], cb1, ws, 0, 0, 0);
        f32x4 hs = __builtin_amdgcn_mfma_f32_16x16x32_bf16(xa[pt][0], bb0, z4, 0, 0, 0);
        hs = __builtin_amdgcn_mfma_f32_16x16x32_bf16(xa[pt][1], bb1, hs, 0, 0, 0);
        corrp[pt] = corrp[pt] + hC[pt][nt] * ws;
        WB[pt][nt] = WB[pt][nt] + ws * capfx;
        hC[pt][nt] = hC[pt][nt] * cs + hs;
      }
      __builtin_amdgcn_s_setprio(0);
    }
    capfx *= cs;
  }

  // ---- epilogue ----
  #pragma unroll
  for (int pt = 0; pt < 2; ++pt)
    #pragma unroll
    for (int nt = 0; nt < 4; ++nt) {
      size_t slot = (size_t)u * 2048 + (size_t)((pt * 4 + nt) * 64 + l) * 4;
      ushort4 hp, wp;
      hp.x = f2bf(hC[pt][nt][0]); hp.y = f2bf(hC[pt][nt][1]);
      hp.z = f2bf(hC[pt][nt][2]); hp.w = f2bf(hC[pt][nt][3]);
      wp.x = f2bf(WB[pt][nt][0]); wp.y = f2bf(WB[pt][nt][1]);
      wp.z = f2bf(WB[pt][nt][2]); wp.w = f2bf(WB[pt][nt][3]);
      *reinterpret_cast<ushort4*>(hpart + slot) = hp;
      *reinterpret_cast<ushort4*>(wacc + slot) = wp;
    }
  float corrv[2][4];
  #pragma unroll
  for (int pt = 0; pt < 2; ++pt)
    #pragma unroll
    for (int r = 0; r < 4; ++r) {
      float c = corrp[pt][r];
      c += __shfl_xor(c, 1); c += __shfl_xor(c, 2);
      c += __shfl_xor(c, 4); c += __shfl_xor(c, 8);
      corrv[pt][r] = c;
    }
  const float Dh = Dp[hh];
  float* ysm = qsm;
  #pragma unroll
  for (int pt = 0; pt < 2; ++pt) {
    float yv = ylac[pt] + Dh * dxac[pt];
    yv += __shfl_xor(yv, 16);
    yv += __shfl_xor(yv, 32);
    if (l < 16) ysm[pt * 16 + l] = yv;
  }
  if (tl == 0) {
    #pragma unroll
    for (int pt = 0; pt < 2; ++pt)
      #pragma unroll
      for (int r = 0; r < 4; ++r)
        ysm[pt * 16 + lg * 4 + r] += corrv[pt][r];
  }
  if (l < 32) ylocal[(size_t)u * 32 + l] = ysm[l];
  if (l == 0) aprod[u] = capfx;
}

// ---------- sequential combine across chunks (bf16 hpart/wacc) ----------
__global__ __launch_bounds__(256) void scan_combine_kernel(
    const U16* __restrict__ hpart, const U16* __restrict__ wacc,
    const float* __restrict__ ylocal, const float* __restrict__ aprod,
    float* __restrict__ yysum) {
  const int bh = blockIdx.x;
  const int b = bh >> 5, hh = bh & 31;
  const int w = threadIdx.x >> 6, l = threadIdx.x & 63;
  const int tl = l & 15, lg = l >> 4;
  __shared__ float csm[8][16];
  __shared__ float ylsm[32];
  const int pair0 = w * 2;
  f32x4 hr[2] = {};
  float cv[2][4] = {};
  for (int ci = 0; ci < NCH; ++ci) {
    int bx = (b * NCH + ci) * 32 + hh;
    size_t base = (size_t)bx * 2048 + (size_t)l * 4;
    float ap = aprod[bx];
    #pragma unroll
    for (int k = 0; k < 2; ++k) {
      size_t o = base + (size_t)(pair0 + k) * 256;
      ushort4 wraw = *reinterpret_cast<const ushort4*>(wacc + o);
      ushort4 praw = *reinterpret_cast<const ushort4*>(hpart + o);
      f32x4 wv = {bf2f(wraw.x), bf2f(wraw.y), bf2f(wraw.z), bf2f(wraw.w)};
      f32x4 pv = {bf2f(praw.x), bf2f(praw.y), bf2f(praw.z), bf2f(praw.w)};
      f32x4 a4 = hr[k] * wv;
      #pragma unroll
      for (int r = 0; r < 4; ++r) cv[k][r] += a4[r];
      hr[k] = hr[k] * ap + pv;
    }
  }
  #pragma unroll
  for (int k = 0; k < 2; ++k)
    #pragma unroll
    for (int r = 0; r < 4; ++r) {
      float c = cv[k][r];
      c += __shfl_xor(c, 1); c += __shfl_xor(c, 2);
      c += __shfl_xor(c, 4); c += __shfl_xor(c, 8);
      if (tl == 0) csm[pair0 + k][lg * 4 + r] = c;
    }
  if (threadIdx.x < 32) {
    float yl = 0.f;
    for (int ci = 0; ci < NCH; ++ci)
      yl += ylocal[(size_t)((b * NCH + ci) * 32 + hh) * 32 + threadIdx.x];
    ylsm[threadIdx.x] = yl;
  }
  __syncthreads();
  if (threadIdx.x < 32) {
    int p = threadIdx.x;
    int pt = p >> 4, pl = p & 15;
    float corr = csm[pt * 4 + 0][pl] + csm[pt * 4 + 1][pl] +
                 csm[pt * 4 + 2][pl] + csm[pt * 4 + 3][pl];
    yysum[(size_t)b * 1024 + hh * 32 + p] = ylsm[p] + corr;
  }
}

// ---------- folded epilogue (tokmean from GEMM1 col partials) ----------
__global__ __launch_bounds__(128) void final1_kernel(const float* __restrict__ colp,
                                                     const float* __restrict__ yysum,
                                                     const float* __restrict__ Wb,
                                                     const float* __restrict__ bb,
                                                     float* __restrict__ m2) {
  int b = blockIdx.x, j = blockIdx.y * 128 + threadIdx.x;
  float tm = 0.f;
  #pragma unroll
  for (int t = 0; t < 32; ++t) tm += colp[(size_t)(b * 32 + t) * 512 + j];
  float s = 0.f;
  for (int d = 0; d < 1024; ++d) s += yysum[b * 1024 + d] * Wb[(size_t)d * 512 + j];
  m2[b * 512 + j] = (tm + s) * (1.f / (float)Lsz) + bb[j];
}

__global__ __launch_bounds__(256) void final2_kernel(const float* __restrict__ m2,
                                                     const float* __restrict__ Wo,
                                                     const float* __restrict__ bo,
                                                     float* __restrict__ out) {
  int b = blockIdx.x, o = blockIdx.y * 256 + threadIdx.x;
  float s = 0.f;
  for (int j = 0; j < 512; ++j) s += m2[b * 512 + j] * Wo[(size_t)j * 1024 + o];
  out[b * 1024 + o] = s + bo[o];
}

extern "C" void kernel_launch(void* const* d_in, const int* in_sizes, int n_in,
                              void* d_out, int out_size, void* d_ws, size_t ws_size,
                              hipStream_t stream) {
  const float* image = (const float*)d_in[0];
  const float* text = (const float*)d_in[1];
  const float* W_in = (const float*)d_in[2];
  const float* b_in = (const float*)d_in[3];
  const float* W_txt = (const float*)d_in[4];
  const float* b_txt = (const float*)d_in[5];
  const float* norm_w = (const float*)d_in[6];
  const float* norm_b = (const float*)d_in[7];
  const float* W_zx = (const float*)d_in[8];
  const float* b_zx = (const float*)d_in[9];
  const float* conv_w = (const float*)d_in[10];
  const float* conv_b = (const float*)d_in[11];
  const float* dt_bias = (const float*)d_in[12];
  const float* A_log = (const float*)d_in[13];
  const float* Dp = (const float*)d_in[14];
  const float* W_blk = (const float*)d_in[15];
  const float* b_blk = (const float*)d_in[16];
  const float* W_out = (const float*)d_in[17];
  const float* b_out = (const float*)d_in[18];
  float* out = (float*)d_out;

  char* ws = (char*)d_ws;
  size_t off = 0;
  auto take = [&](size_t bytes) {
    char* p = ws + off;
    off = (off + bytes + 255) & ~(size_t)255;
    return p;
  };
  U16* zxT = (U16*)take((size_t)Bsz * D_PROJ_PAD * 4096 * 2);
  U16* wt_in = (U16*)take((size_t)DIMV * HID * 2);
  U16* wt_zx = (U16*)take((size_t)D_PROJ_PAD * DIMV * 2);
  U16* tok_bf = (U16*)take((size_t)MROWS * DIMV * 2);
  U16* x_bf = (U16*)take((size_t)MROWS * DIMV * 2);
  U16* xh_t = (U16*)take((size_t)MROWS * D_INNER * 2);
  U16* bm_bf = (U16*)take((size_t)MROWS * 64 * 2);
  U16* cm_bf = (U16*)take((size_t)MROWS * 64 * 2);
  U16* bm_t = (U16*)take((size_t)MROWS * 64 * 2);
  U16* cm_t = (U16*)take((size_t)MROWS * 64 * 2);
  float* decay4 = (float*)take((size_t)256 * 4096 * 16);
  float* txtf = (float*)take(8 * 512 * 4);
  float* colp = (float*)take((size_t)256 * 512 * 4);
  float* yysum = (float*)take(8 * 1024 * 4);
  float* m2 = (float*)take(8 * 512 * 4);
  float* ylocal = (float*)take((size_t)4096 * 32 * 4);
  float* aprod = (float*)take((size_t)4096 * 4);
  U16* hpart = tok_bf;
  U16* wacc = x_bf;

  txt_kernel<<<8, 512, 0, stream>>>(text, W_txt, b_txt, txtf);
  transpose_cvt_kernel<<<dim3(DIMV / 32, HID / 32), dim3(32, 8), 0, stream>>>(W_in, wt_in, HID, DIMV, DIMV);
  transpose_cvt_kernel<<<dim3(D_PROJ_PAD / 32, DIMV / 32), dim3(32, 8), 0, stream>>>(W_zx, wt_zx, DIMV, D_PROJ, D_PROJ_PAD);

  gemm_kernel<1, 1, 0><<<1024, 256, 0, stream>>>(
      (const void*)image, wt_in, tok_bf, b_in, txtf, colp, MROWS, HID, DIMV, 4);
  ln_kernel<<<MROWS, 128, 0, stream>>>(tok_bf, x_bf, norm_w, norm_b);

  gemm_kernel<0, 0, 1><<<4608, 256, 0, stream>>>(
      (const void*)x_bf, wt_zx, zxT, b_zx, nullptr, nullptr, MROWS, DIMV, D_PROJ, 18);

  decay_kernel<<<512, 256, 0, stream>>>(zxT, dt_bias, A_log, decay4);
  conv_t_kernel<<<dim3(16, 18, 8), 256, 0, stream>>>(zxT, conv_w, conv_b,
                                                     xh_t, bm_t, cm_t, bm_bf, cm_bf);

  scan_chunk_kernel<<<1024, 256, 0, stream>>>(xh_t, zxT, bm_bf, cm_bf, bm_t, cm_t,
                                              decay4, Dp, hpart, wacc, ylocal, aprod);
  scan_combine_kernel<<<256, 256, 0, stream>>>(hpart, wacc, ylocal, aprod, yysum);

  final1_kernel<<<dim3(8, 4), 128, 0, stream>>>(colp, yysum, W_blk, b_blk, m2);
  final2_kernel<<<dim3(8, 4), 256, 0, stream>>>(m2, W_out, b_out, out);
}

// Round 15
// 522.434 us; speedup vs baseline: 1.0703x; 1.0221x over previous
//
#include <hip/hip_runtime.h>

typedef unsigned short U16;
typedef __attribute__((ext_vector_type(4))) float f32x4;
typedef __attribute__((ext_vector_type(8))) short short8;
typedef __attribute__((ext_vector_type(8))) __bf16 bf16x8;

#define Bsz 8
#define Lsz 4096
#define HID 1024
#define DIMV 512
#define D_INNER 1024
#define NHEADS 32
#define HEADDIM 32
#define D_STATE 64
#define CONV_DIM 1152
#define D_PROJ 2208
#define D_PROJ_PAD 2304
#define MROWS 32768
#define CL2 256        // scan chunk per unit
#define NSUB 4         // sub-chunks of 64
#define NCH 16         // Lsz / CL2

__device__ __forceinline__ float bf2f(U16 u) {
  return __builtin_bit_cast(float, (unsigned)(((unsigned)u) << 16));
}
__device__ __forceinline__ U16 f2bf(float f) {
  unsigned u = __builtin_bit_cast(unsigned, f);
  return (U16)((u + 0x7FFFu + ((u >> 16) & 1u)) >> 16);
}
__device__ __forceinline__ void gload_lds16(const void* g, void* l) {
  __builtin_amdgcn_global_load_lds((const __attribute__((address_space(1))) unsigned int*)g,
                                   (__attribute__((address_space(3))) unsigned int*)l, 16, 0, 0);
}
__device__ __forceinline__ float fast_silu(float v) {
  return v * __builtin_amdgcn_rcpf(1.f + __expf(-v));
}

// ---------- tiny txt GEMM ----------
__global__ __launch_bounds__(512) void txt_kernel(const float* __restrict__ text,
                                                  const float* __restrict__ Wt,
                                                  const float* __restrict__ bt,
                                                  float* __restrict__ txt) {
  int b = blockIdx.x, j = threadIdx.x;
  float s = bt[j];
  const float* tp = text + (size_t)b * 77 * 768;
  for (int k = 0; k < 768; ++k) s += tp[k] * Wt[(size_t)k * 512 + j];
  txt[b * 512 + j] = s;
}

// ---------- transpose + convert weights ----------
__global__ __launch_bounds__(256) void transpose_cvt_kernel(const float* __restrict__ in,
                                                            U16* __restrict__ out,
                                                            int K, int N, int Npad) {
  __shared__ U16 tile[32][33];
  int n0 = blockIdx.x * 32, k0 = blockIdx.y * 32;
  int tx = threadIdx.x, ty = threadIdx.y;
  #pragma unroll
  for (int i = 0; i < 4; ++i) {
    int k = k0 + ty + i * 8, n = n0 + tx;
    float v = (n < N) ? in[(size_t)k * N + n] : 0.f;
    tile[ty + i * 8][tx] = f2bf(v);
  }
  __syncthreads();
  #pragma unroll
  for (int i = 0; i < 4; ++i) {
    int n = n0 + ty + i * 8;
    out[(size_t)n * K + k0 + tx] = tile[tx][ty + i * 8];
  }
}

// ---------- bf16 MFMA GEMM ----------
// EPI=1 (GEMM1): adds txt bias and emits per-(m-tile) column partial sums.
// TRANS=1 (GEMM2): writes C transposed as zx_t[b][c][l], bias+silu(z) fused.
template <int EPI, int AF32, int TRANS>
__global__ __launch_bounds__(256) void gemm_kernel(const void* __restrict__ Ap,
                                                   const U16* __restrict__ Bt,
                                                   U16* __restrict__ C,
                                                   const float* __restrict__ bias,
                                                   const float* __restrict__ txtv,
                                                   float* __restrict__ colp,
                                                   int M, int K, int Nreal, int NT) {
  __shared__ alignas(16) U16 smem[128 * 128];
  U16* As = smem;
  U16* Bs = smem + 128 * 64;
  const int tid = threadIdx.x;
  const int wid = tid >> 6, lane = tid & 63;
  const int lhi = lane >> 4, llo = lane & 15;
  const int xcd = blockIdx.x & 7, slot = blockIdx.x >> 3;
  const int m0 = (xcd + 8 * (slot / NT)) * 128;
  const int n0 = (slot % NT) * 128;
  const int wr = wid >> 1, wc = wid & 1;
  f32x4 acc[4][4] = {};

  for (int k0 = 0; k0 < K; k0 += 64) {
    __syncthreads();
    if constexpr (AF32) {
      const float* Af = (const float*)Ap;
      #pragma unroll
      for (int is = 0; is < 4; ++is) {
        int q = is * 256 + tid;
        int r = q >> 3, cl = q & 7;
        int cg = cl ^ (r & 7);
        const float* src = Af + (size_t)(m0 + r) * K + k0 + cg * 8;
        f32x4 v0 = *reinterpret_cast<const f32x4*>(src);
        f32x4 v1 = *reinterpret_cast<const f32x4*>(src + 4);
        short8 o;
        #pragma unroll
        for (int j = 0; j < 4; ++j) {
          o[j] = (short)f2bf(v0[j]);
          o[j + 4] = (short)f2bf(v1[j]);
        }
        *reinterpret_cast<short8*>(&As[q * 8]) = o;
      }
    } else {
      const U16* A = (const U16*)Ap;
      #pragma unroll
      for (int is = 0; is < 4; ++is) {
        int qbase = is * 256 + wid * 64;
        int q = qbase + lane;
        int r = q >> 3;
        int cc = (q & 7) ^ (r & 7);
        gload_lds16(A + (size_t)(m0 + r) * K + k0 + cc * 8, &As[qbase * 8]);
      }
    }
    #pragma unroll
    for (int is = 0; is < 4; ++is) {
      int qbase = is * 256 + wid * 64;
      int q = qbase + lane;
      int r = q >> 3;
      int cc = (q & 7) ^ (r & 7);
      gload_lds16(Bt + (size_t)(n0 + r) * K + k0 + cc * 8, &Bs[qbase * 8]);
    }
    __syncthreads();
    #pragma unroll
    for (int kk = 0; kk < 64; kk += 32) {
      bf16x8 av[4], bv[4];
      #pragma unroll
      for (int i = 0; i < 4; ++i) {
        int ra = wr * 64 + i * 16 + llo;
        short8 a = *reinterpret_cast<const short8*>(
            &As[ra * 64 + ((((kk >> 3) + lhi) ^ (ra & 7)) << 3)]);
        av[i] = __builtin_bit_cast(bf16x8, a);
        int rb = wc * 64 + i * 16 + llo;
        short8 b = *reinterpret_cast<const short8*>(
            &Bs[rb * 64 + ((((kk >> 3) + lhi) ^ (rb & 7)) << 3)]);
        bv[i] = __builtin_bit_cast(bf16x8, b);
      }
      #pragma unroll
      for (int i = 0; i < 4; ++i)
        #pragma unroll
        for (int j = 0; j < 4; ++j)
          acc[i][j] = __builtin_amdgcn_mfma_f32_16x16x32_bf16(av[i], bv[j], acc[i][j], 0, 0, 0);
    }
  }
  const int b = m0 >> 12;
  if constexpr (TRANS) {
    __syncthreads();
    U16* T = smem;
    #pragma unroll
    for (int i = 0; i < 4; ++i) {
      #pragma unroll
      for (int j = 0; j < 4; ++j) {
        int c_loc = wc * 64 + j * 16 + llo;
        int cg = n0 + c_loc;
        float badd = (cg < D_PROJ) ? bias[cg] : 0.f;
        int q = wr * 16 + i * 4 + lhi;
        int qs = q ^ ((c_loc & 15) << 1);
        U16 pk[4];
        #pragma unroll
        for (int r = 0; r < 4; ++r) {
          float v = acc[i][j][r] + badd;
          if (cg < 1024) v = fast_silu(v);
          pk[r] = f2bf(v);
        }
        uint2 p2;
        p2.x = (unsigned)pk[0] | ((unsigned)pk[1] << 16);
        p2.y = (unsigned)pk[2] | ((unsigned)pk[3] << 16);
        *reinterpret_cast<uint2*>(&T[c_loc * 128 + qs * 4]) = p2;
      }
    }
    __syncthreads();
    const int l0 = m0 & 4095;
    #pragma unroll
    for (int cs = 0; cs < 8; ++cs) {
      int c = cs * 16 + (tid >> 4);
      int gch = n0 + c;
      int kp = (tid & 15) * 2;
      int q0 = kp ^ ((c & 15) << 1);
      int q1 = (kp + 1) ^ ((c & 15) << 1);
      uint2 a = *reinterpret_cast<const uint2*>(&T[c * 128 + q0 * 4]);
      uint2 bq = *reinterpret_cast<const uint2*>(&T[c * 128 + q1 * 4]);
      if (gch < D_PROJ) {
        uint4 oo;
        oo.x = a.x; oo.y = a.y; oo.z = bq.x; oo.w = bq.y;
        *reinterpret_cast<uint4*>(C + ((size_t)b * D_PROJ_PAD + gch) * 4096 + l0 + kp * 4) = oo;
      }
    }
  } else {
    float cp[4] = {0.f, 0.f, 0.f, 0.f};
    #pragma unroll
    for (int i = 0; i < 4; ++i) {
      int rbase = m0 + wr * 64 + i * 16 + lhi * 4;
      #pragma unroll
      for (int j = 0; j < 4; ++j) {
        int cg = n0 + wc * 64 + j * 16 + llo;
        if (cg < Nreal) {
          float badd = bias[cg] + (EPI ? txtv[b * 512 + cg] : 0.f);
          #pragma unroll
          for (int r = 0; r < 4; ++r) {
            float v = acc[i][j][r] + badd;
            C[(size_t)(rbase + r) * Nreal + cg] = f2bf(v);
            if constexpr (EPI) cp[j] += v;
          }
        }
      }
    }
    if constexpr (EPI) {
      #pragma unroll
      for (int j = 0; j < 4; ++j) {
        cp[j] += __shfl_xor(cp[j], 16);
        cp[j] += __shfl_xor(cp[j], 32);
      }
      __syncthreads();
      float* colsm = reinterpret_cast<float*>(smem);
      if (lane < 16) {
        #pragma unroll
        for (int j = 0; j < 4; ++j)
          colsm[wr * 128 + wc * 64 + j * 16 + lane] = cp[j];
      }
      __syncthreads();
      if (tid < 128)
        colp[(size_t)(m0 >> 7) * 512 + n0 + tid] = colsm[tid] + colsm[128 + tid];
    }
  }
}

// ---------- LayerNorm ----------
__global__ __launch_bounds__(128) void ln_kernel(const U16* __restrict__ tok,
                                                 U16* __restrict__ xo,
                                                 const float* __restrict__ w,
                                                 const float* __restrict__ bb) {
  int row = blockIdx.x, tid = threadIdx.x;
  const U16* rp = tok + (size_t)row * 512 + tid * 4;
  uint2 raw = *reinterpret_cast<const uint2*>(rp);
  float f0 = bf2f((U16)(raw.x & 0xffff)), f1 = bf2f((U16)(raw.x >> 16));
  float f2 = bf2f((U16)(raw.y & 0xffff)), f3 = bf2f((U16)(raw.y >> 16));
  float s = f0 + f1 + f2 + f3;
  float q = f0 * f0 + f1 * f1 + f2 * f2 + f3 * f3;
  for (int m = 1; m < 64; m <<= 1) { s += __shfl_xor(s, m); q += __shfl_xor(q, m); }
  __shared__ float ss[2], qq[2];
  if ((tid & 63) == 0) { ss[tid >> 6] = s; qq[tid >> 6] = q; }
  __syncthreads();
  s = ss[0] + ss[1]; q = qq[0] + qq[1];
  float mu = s * (1.f / 512.f);
  float var = q * (1.f / 512.f) - mu * mu;
  float rs = rsqrtf(var + 1e-5f);
  int j0 = tid * 4;
  unsigned c0 = f2bf((f0 - mu) * rs * w[j0] + bb[j0]);
  unsigned c1 = f2bf((f1 - mu) * rs * w[j0 + 1] + bb[j0 + 1]);
  unsigned c2 = f2bf((f2 - mu) * rs * w[j0 + 2] + bb[j0 + 2]);
  unsigned c3 = f2bf((f3 - mu) * rs * w[j0 + 3] + bb[j0 + 3]);
  uint2 o; o.x = c0 | (c1 << 16); o.y = c2 | (c3 << 16);
  *reinterpret_cast<uint2*>(xo + (size_t)row * 512 + j0) = o;
}

// ---------- decay precompute from zx_t ----------
__global__ __launch_bounds__(256) void decay_kernel(const U16* __restrict__ zxT,
                                                    const float* __restrict__ dt_bias,
                                                    const float* __restrict__ A_log,
                                                    float* __restrict__ decay4) {
  const int sc = blockIdx.x;
  const int w = threadIdx.x >> 6, l = threadIdx.x & 63;
  const int r0 = sc * 64;
  const int b = r0 >> 12, l0 = r0 & 4095;
  #pragma unroll
  for (int i = 0; i < 8; ++i) {
    int hh = w * 8 + i;
    float raw = bf2f(zxT[((size_t)b * D_PROJ_PAD + 2176 + hh) * 4096 + l0 + l]) + dt_bias[hh];
    float dt = (raw > 20.f) ? raw : log1pf(__expf(raw));
    float A = -__expf(A_log[hh]);
    float ldA2 = dt * A * 1.44269504088896f;
    float ldt2 = __log2f(dt);
    float la = ldA2;
    #pragma unroll
    for (int d = 1; d < 64; d <<= 1) {
      float o = __shfl_up(la, d);
      if (l >= d) la += o;
    }
    float laend = __shfl(la, 63);
    f32x4 v = {ldt2 - la, la, exp2f(la), exp2f(laend + ldt2 - la)};
    *reinterpret_cast<f32x4*>(decay4 + ((size_t)(b * 32 + hh) * 4096 + l0 + l) * 4) = v;
  }
}

// ---------- conv(K=4)+silu on transposed layout ----------
__global__ __launch_bounds__(256) void conv_t_kernel(
    const U16* __restrict__ zxT, const float* __restrict__ cw,
    const float* __restrict__ cb, U16* __restrict__ xh_t,
    U16* __restrict__ bm_t, U16* __restrict__ cm_t,
    U16* __restrict__ Bmo, U16* __restrict__ Cmo) {
  __shared__ U16 Tc[64 * 264];
  const int lc = blockIdx.x, cg = blockIdx.y, b = blockIdx.z;
  const int tid = threadIdx.x;
  const int cl = tid & 63, ls = tid >> 6;
  const int cc2 = cg * 64 + cl;
  const int l0 = lc * 256 + ls * 64;
  const U16* row = zxT + ((size_t)b * D_PROJ_PAD + 1024 + cc2) * 4096;

  U16 arr[72];
  {
    const U16* src = row + l0 - 8;
    #pragma unroll
    for (int k = 0; k < 9; ++k) {
      uint4 rv;
      if (l0 == 0 && k == 0) {
        rv.x = rv.y = rv.z = rv.w = 0u;
      } else {
        rv = *reinterpret_cast<const uint4*>(src + k * 8);
      }
      arr[k * 8 + 0] = (U16)(rv.x & 0xffff); arr[k * 8 + 1] = (U16)(rv.x >> 16);
      arr[k * 8 + 2] = (U16)(rv.y & 0xffff); arr[k * 8 + 3] = (U16)(rv.y >> 16);
      arr[k * 8 + 4] = (U16)(rv.z & 0xffff); arr[k * 8 + 5] = (U16)(rv.z >> 16);
      arr[k * 8 + 6] = (U16)(rv.w & 0xffff); arr[k * 8 + 7] = (U16)(rv.w >> 16);
    }
  }
  const float4 w4 = *reinterpret_cast<const float4*>(cw + cc2 * 4);
  const float cbv = cb[cc2];
  U16 o[64];
  #pragma unroll
  for (int j = 0; j < 64; ++j) {
    float acc = cbv + bf2f(arr[j + 5]) * w4.x + bf2f(arr[j + 6]) * w4.y +
                bf2f(arr[j + 7]) * w4.z + bf2f(arr[j + 8]) * w4.w;
    o[j] = f2bf(fast_silu(acc));
  }
  {
    U16* dst;
    if (cc2 < 1024)      dst = xh_t + ((size_t)b * 1024 + cc2) * 4096 + l0;
    else if (cc2 < 1088) dst = bm_t + ((size_t)(b * 64 + (cc2 - 1024))) * 4096 + l0;
    else                 dst = cm_t + ((size_t)(b * 64 + (cc2 - 1088))) * 4096 + l0;
    #pragma unroll
    for (int k = 0; k < 8; ++k) {
      uint4 ov;
      ov.x = (unsigned)o[k * 8 + 0] | ((unsigned)o[k * 8 + 1] << 16);
      ov.y = (unsigned)o[k * 8 + 2] | ((unsigned)o[k * 8 + 3] << 16);
      ov.z = (unsigned)o[k * 8 + 4] | ((unsigned)o[k * 8 + 5] << 16);
      ov.w = (unsigned)o[k * 8 + 6] | ((unsigned)o[k * 8 + 7] << 16);
      *reinterpret_cast<uint4*>(dst + k * 8) = ov;
    }
  }
  if (cg >= 16) {
    #pragma unroll
    for (int k = 0; k < 8; ++k) {
      uint4 ov;
      ov.x = (unsigned)o[k * 8 + 0] | ((unsigned)o[k * 8 + 1] << 16);
      ov.y = (unsigned)o[k * 8 + 2] | ((unsigned)o[k * 8 + 3] << 16);
      ov.z = (unsigned)o[k * 8 + 4] | ((unsigned)o[k * 8 + 5] << 16);
      ov.w = (unsigned)o[k * 8 + 6] | ((unsigned)o[k * 8 + 7] << 16);
      *reinterpret_cast<uint4*>(&Tc[cl * 264 + ls * 64 + k * 8]) = ov;
    }
    __syncthreads();
    U16* outp = (cg == 16) ? Bmo : Cmo;
    const int lt = tid;
    U16 rowv[64];
    #pragma unroll
    for (int n = 0; n < 64; ++n) rowv[n] = Tc[n * 264 + lt];
    U16* dst = outp + ((size_t)b * 4096 + lc * 256 + lt) * 64;
    #pragma unroll
    for (int k = 0; k < 8; ++k) {
      uint4 ov;
      ov.x = (unsigned)rowv[k * 8 + 0] | ((unsigned)rowv[k * 8 + 1] << 16);
      ov.y = (unsigned)rowv[k * 8 + 2] | ((unsigned)rowv[k * 8 + 3] << 16);
      ov.z = (unsigned)rowv[k * 8 + 4] | ((unsigned)rowv[k * 8 + 5] << 16);
      ov.w = (unsigned)rowv[k * 8 + 6] | ((unsigned)rowv[k * 8 + 7] << 16);
      *reinterpret_cast<uint4*>(dst + k * 8) = ov;
    }
  }
}

// ---------- SSD chunked scan via MFMA (round-13 no-spill body: early staging
// raws only; gzp inside matmul2; matmul3 per-nt streamed) ----------
__global__ __launch_bounds__(256, 2) void scan_chunk_kernel(
    const U16* __restrict__ xh_t, const U16* __restrict__ zxT,
    const U16* __restrict__ Bm, const U16* __restrict__ Cm,
    const U16* __restrict__ bm_t, const U16* __restrict__ cm_t,
    const float* __restrict__ decay4, const float* __restrict__ Dp,
    U16* __restrict__ hpart, U16* __restrict__ wacc,
    float* __restrict__ ylocal, float* __restrict__ aprod) {
  const int w = threadIdx.x >> 6, l = threadIdx.x & 63;
  const int bid = (blockIdx.x & 7) * 128 + (blockIdx.x >> 3);
  const int u = bid * 4 + w;
  const int hh = u & 31, ci = (u >> 5) & (NCH - 1), b = u >> 9;
  const int tl = l & 15, lg = l >> 4;

  __shared__ alignas(16) U16 MsmAll[4 * 64 * 72];
  __shared__ alignas(16) float decAll[4 * 256];
  U16* Msm = &MsmAll[w * 64 * 72];
  float* qsm = &decAll[w * 256];
  float* la2sm = qsm + 64;
  float* casm = qsm + 128;
  float* cfsm = qsm + 192;

  #pragma unroll
  for (int i = 0; i < 9; ++i)
    *reinterpret_cast<f32x4*>(reinterpret_cast<char*>(Msm) + (size_t)l * 144 + i * 16) =
        f32x4{0.f, 0.f, 0.f, 0.f};

  f32x4 hC[2][4] = {};
  f32x4 WB[2][4] = {};
  f32x4 corrp[2] = {};
  float ylac[2] = {0.f, 0.f}, dxac[2] = {0.f, 0.f};
  float capfx = 1.f;
  const size_t xrow = ((size_t)b * 1024 + hh * 32) * 4096;
  const size_t grow = ((size_t)b * D_PROJ_PAD + hh * 32) * 4096;
  const float* dbase = decay4 + ((size_t)(b * 32 + hh) * 4096) * 4;

  for (int sc = 0; sc < NSUB; ++sc) {
    const int lglob = ci * CL2 + sc * 64;
    const int r0g = b * 4096 + lglob;

    f32x4 dv = *reinterpret_cast<const f32x4*>(dbase + (size_t)(lglob + l) * 4);
    qsm[l] = dv[0];
    la2sm[l] = dv[1];
    casm[l] = dv[2];
    cfsm[l] = dv[3];
    const float cs = __shfl(dv[2], 63);

    // ---- EARLY ISSUE: staging raw loads (latency drains under matmul1) ----
    short8 graw[2][2], xraw[2][2];
    #pragma unroll
    for (int pt = 0; pt < 2; ++pt)
      #pragma unroll
      for (int kt = 0; kt < 2; ++kt) {
        size_t po = (size_t)(pt * 16 + tl) * 4096 + lglob + kt * 32 + lg * 8;
        graw[pt][kt] = *reinterpret_cast<const short8*>(zxT + grow + po);
        xraw[pt][kt] = *reinterpret_cast<const short8*>(xh_t + xrow + po);
      }

    // ---- matmul1 half A: si in {0,1} (7 tiles) ----
    {
      f32x4 g[7] = {};
      #pragma unroll
      for (int k = 0; k < 2; ++k) {
        const size_t co = (size_t)k * 32 + lg * 8;
        bf16x8 af0 = *reinterpret_cast<const bf16x8*>(Bm + (size_t)(r0g + tl) * 64 + co);
        bf16x8 af1 = *reinterpret_cast<const bf16x8*>(Bm + (size_t)(r0g + 16 + tl) * 64 + co);
        bf16x8 cf0 = *reinterpret_cast<const bf16x8*>(Cm + (size_t)(r0g + tl) * 64 + co);
        bf16x8 cf1 = *reinterpret_cast<const bf16x8*>(Cm + (size_t)(r0g + 16 + tl) * 64 + co);
        bf16x8 cf2 = *reinterpret_cast<const bf16x8*>(Cm + (size_t)(r0g + 32 + tl) * 64 + co);
        bf16x8 cf3 = *reinterpret_cast<const bf16x8*>(Cm + (size_t)(r0g + 48 + tl) * 64 + co);
        __builtin_amdgcn_s_setprio(1);
        g[0] = __builtin_amdgcn_mfma_f32_16x16x32_bf16(af0, cf0, g[0], 0, 0, 0);
        g[1] = __builtin_amdgcn_mfma_f32_16x16x32_bf16(af0, cf1, g[1], 0, 0, 0);
        g[2] = __builtin_amdgcn_mfma_f32_16x16x32_bf16(af0, cf2, g[2], 0, 0, 0);
        g[3] = __builtin_amdgcn_mfma_f32_16x16x32_bf16(af0, cf3, g[3], 0, 0, 0);
        g[4] = __builtin_amdgcn_mfma_f32_16x16x32_bf16(af1, cf1, g[4], 0, 0, 0);
        g[5] = __builtin_amdgcn_mfma_f32_16x16x32_bf16(af1, cf2, g[5], 0, 0, 0);
        g[6] = __builtin_amdgcn_mfma_f32_16x16x32_bf16(af1, cf3, g[6], 0, 0, 0);
        __builtin_amdgcn_s_setprio(0);
      }
      f32x4 q0 = *reinterpret_cast<const f32x4*>(&qsm[lg * 4]);
      f32x4 q1 = *reinterpret_cast<const f32x4*>(&qsm[16 + lg * 4]);
      #pragma unroll
      for (int idx = 0; idx < 7; ++idx) {
        const int si = (idx < 4) ? 0 : 1;
        const int ti = (idx < 4) ? idx : (idx - 3);
        f32x4 q4 = si ? q1 : q0;
        float lat = la2sm[ti * 16 + tl];
        float v[4];
        #pragma unroll
        for (int r = 0; r < 4; ++r) {
          float val = g[idx][r] * exp2f(lat + q4[r]);
          if (si == ti) val = (lg * 4 + r <= tl) ? val : 0.f;
          v[r] = val;
        }
        uint2 pk;
        pk.x = (unsigned)f2bf(v[0]) | ((unsigned)f2bf(v[1]) << 16);
        pk.y = (unsigned)f2bf(v[2]) | ((unsigned)f2bf(v[3]) << 16);
        *reinterpret_cast<uint2*>(reinterpret_cast<char*>(Msm) +
                                  (size_t)(ti * 16 + tl) * 144 + (size_t)(si * 16 + lg * 4) * 2) = pk;
      }
    }
    // ---- matmul1 half B: si in {2,3} (3 tiles) ----
    {
      f32x4 g[3] = {};
      #pragma unroll
      for (int k = 0; k < 2; ++k) {
        const size_t co = (size_t)k * 32 + lg * 8;
        bf16x8 af2 = *reinterpret_cast<const bf16x8*>(Bm + (size_t)(r0g + 32 + tl) * 64 + co);
        bf16x8 af3 = *reinterpret_cast<const bf16x8*>(Bm + (size_t)(r0g + 48 + tl) * 64 + co);
        bf16x8 cf2 = *reinterpret_cast<const bf16x8*>(Cm + (size_t)(r0g + 32 + tl) * 64 + co);
        bf16x8 cf3 = *reinterpret_cast<const bf16x8*>(Cm + (size_t)(r0g + 48 + tl) * 64 + co);
        __builtin_amdgcn_s_setprio(1);
        g[0] = __builtin_amdgcn_mfma_f32_16x16x32_bf16(af2, cf2, g[0], 0, 0, 0);
        g[1] = __builtin_amdgcn_mfma_f32_16x16x32_bf16(af2, cf3, g[1], 0, 0, 0);
        g[2] = __builtin_amdgcn_mfma_f32_16x16x32_bf16(af3, cf3, g[2], 0, 0, 0);
        __builtin_amdgcn_s_setprio(0);
      }
      f32x4 q2 = *reinterpret_cast<const f32x4*>(&qsm[32 + lg * 4]);
      f32x4 q3 = *reinterpret_cast<const f32x4*>(&qsm[48 + lg * 4]);
      const int sis[3] = {2, 2, 3};
      const int tis[3] = {2, 3, 3};
      #pragma unroll
      for (int idx = 0; idx < 3; ++idx) {
        const int si = sis[idx], ti = tis[idx];
        f32x4 q4 = (si == 2) ? q2 : q3;
        float lat = la2sm[ti * 16 + tl];
        float v[4];
        #pragma unroll
        for (int r = 0; r < 4; ++r) {
          float val = g[idx][r] * exp2f(lat + q4[r]);
          if (si == ti) val = (lg * 4 + r <= tl) ? val : 0.f;
          v[r] = val;
        }
        uint2 pk;
        pk.x = (unsigned)f2bf(v[0]) | ((unsigned)f2bf(v[1]) << 16);
        pk.y = (unsigned)f2bf(v[2]) | ((unsigned)f2bf(v[3]) << 16);
        *reinterpret_cast<uint2*>(reinterpret_cast<char*>(Msm) +
                                  (size_t)(ti * 16 + tl) * 144 + (size_t)(si * 16 + lg * 4) * 2) = pk;
      }
    }

    // ---- scale staging (raws already landed); dxac here ----
    bf16x8 ga[2][2], xa[2][2];
    #pragma unroll
    for (int pt = 0; pt < 2; ++pt)
      #pragma unroll
      for (int kt = 0; kt < 2; ++kt) {
        const float* cap = &casm[kt * 32 + lg * 8];
        const float* cfp = &cfsm[kt * 32 + lg * 8];
        short8 gs, xs8;
        #pragma unroll
        for (int j = 0; j < 8; ++j) {
          float gf = bf2f((U16)graw[pt][kt][j]);
          float xf = bf2f((U16)xraw[pt][kt][j]);
          dxac[pt] = fmaf(gf, xf, dxac[pt]);
          gs[j] = (short)f2bf(gf * cap[j]);
          xs8[j] = (short)f2bf(xf * cfp[j]);
        }
        ga[pt][kt] = __builtin_bit_cast(bf16x8, gs);
        xa[pt][kt] = __builtin_bit_cast(bf16x8, xs8);
      }

    // ---- matmul2: Y = M X (X from xraw); gz preloaded batch; ylac ----
    {
      uint2 gzp[4][2];
      #pragma unroll
      for (int tt = 0; tt < 4; ++tt)
        #pragma unroll
        for (int pt = 0; pt < 2; ++pt)
          gzp[tt][pt] = *reinterpret_cast<const uint2*>(
              zxT + grow + (size_t)(pt * 16 + tl) * 4096 + lglob + tt * 16 + lg * 4);
      #pragma unroll
      for (int tt = 0; tt < 4; ++tt) {
        f32x4 y[2] = {f32x4{0.f, 0.f, 0.f, 0.f}, f32x4{0.f, 0.f, 0.f, 0.f}};
        __builtin_amdgcn_s_setprio(1);
        #pragma unroll
        for (int ks = 0; ks < 2; ++ks) {
          bf16x8 mf = *reinterpret_cast<const bf16x8*>(
              reinterpret_cast<char*>(Msm) + (size_t)(tt * 16 + tl) * 144 + (ks * 32 + lg * 8) * 2);
          #pragma unroll
          for (int pt = 0; pt < 2; ++pt)
            y[pt] = __builtin_amdgcn_mfma_f32_16x16x32_bf16(
                mf, __builtin_bit_cast(bf16x8, xraw[pt][ks]), y[pt], 0, 0, 0);
        }
        __builtin_amdgcn_s_setprio(0);
        #pragma unroll
        for (int pt = 0; pt < 2; ++pt) {
          uint2 gz2 = gzp[tt][pt];
          float gzv[4] = {bf2f((U16)(gz2.x & 0xffff)), bf2f((U16)(gz2.x >> 16)),
                          bf2f((U16)(gz2.y & 0xffff)), bf2f((U16)(gz2.y >> 16))};
          #pragma unroll
          for (int r = 0; r < 4; ++r)
            ylac[pt] = fmaf(gzv[r], y[pt][r], ylac[pt]);
        }
      }
    }

    // ---- matmul3 streamed per nt (batched fragment loads per nt) ----
    #pragma unroll
    for (int nt = 0; nt < 4; ++nt) {
      size_t cro = (size_t)(b * 64 + nt * 16 + tl) * 4096 + lglob;
      bf16x8 cb0 = *reinterpret_cast<const bf16x8*>(cm_t + cro + lg * 8);
      bf16x8 cb1 = *reinterpret_cast<const bf16x8*>(cm_t + cro + 32 + lg * 8);
      bf16x8 bb0 = *reinterpret_cast<const bf16x8*>(bm_t + cro + lg * 8);
      bf16x8 bb1 = *reinterpret_cast<const bf16x8*>(bm_t + cro + 32 + lg * 8);
      __builtin_amdgcn_s_setprio(1);
      #pragma unroll
      for (int pt = 0; pt < 2; ++pt) {
        f32x4 z4 = {0.f, 0.f, 0.f, 0.f};
        f32x4 ws = __builtin_amdgcn_mfma_f32_16x16x32_bf16(ga[pt][0], cb0, z4, 0, 0, 0);
        ws = __builtin_amdgcn_mfma_f32_16x16x32_bf16(ga[pt][1], cb1, ws, 0, 0, 0);
        f32x4 hs = __builtin_amdgcn_mfma_f32_16x16x32_bf16(xa[pt][0], bb0, z4, 0, 0, 0);
        hs = __builtin_amdgcn_mfma_f32_16x16x32_bf16(xa[pt][1], bb1, hs, 0, 0, 0);
        corrp[pt] = corrp[pt] + hC[pt][nt] * ws;
        WB[pt][nt] = WB[pt][nt] + ws * capfx;
        hC[pt][nt] = hC[pt][nt] * cs + hs;
      }
      __builtin_amdgcn_s_setprio(0);
    }
    capfx *= cs;
  }

  // ---- epilogue ----
  #pragma unroll
  for (int pt = 0; pt < 2; ++pt)
    #pragma unroll
    for (int nt = 0; nt < 4; ++nt) {
      size_t slot = (size_t)u * 2048 + (size_t)((pt * 4 + nt) * 64 + l) * 4;
      ushort4 hp, wp;
      hp.x = f2bf(hC[pt][nt][0]); hp.y = f2bf(hC[pt][nt][1]);
      hp.z = f2bf(hC[pt][nt][2]); hp.w = f2bf(hC[pt][nt][3]);
      wp.x = f2bf(WB[pt][nt][0]); wp.y = f2bf(WB[pt][nt][1]);
      wp.z = f2bf(WB[pt][nt][2]); wp.w = f2bf(WB[pt][nt][3]);
      *reinterpret_cast<ushort4*>(hpart + slot) = hp;
      *reinterpret_cast<ushort4*>(wacc + slot) = wp;
    }
  float corrv[2][4];
  #pragma unroll
  for (int pt = 0; pt < 2; ++pt)
    #pragma unroll
    for (int r = 0; r < 4; ++r) {
      float c = corrp[pt][r];
      c += __shfl_xor(c, 1); c += __shfl_xor(c, 2);
      c += __shfl_xor(c, 4); c += __shfl_xor(c, 8);
      corrv[pt][r] = c;
    }
  const float Dh = Dp[hh];
  float* ysm = qsm;
  #pragma unroll
  for (int pt = 0; pt < 2; ++pt) {
    float yv = ylac[pt] + Dh * dxac[pt];
    yv += __shfl_xor(yv, 16);
    yv += __shfl_xor(yv, 32);
    if (l < 16) ysm[pt * 16 + l] = yv;
  }
  if (tl == 0) {
    #pragma unroll
    for (int pt = 0; pt < 2; ++pt)
      #pragma unroll
      for (int r = 0; r < 4; ++r)
        ysm[pt * 16 + lg * 4 + r] += corrv[pt][r];
  }
  if (l < 32) ylocal[(size_t)u * 32 + l] = ysm[l];
  if (l == 0) aprod[u] = capfx;
}

// ---------- sequential combine across chunks (bf16 hpart/wacc) ----------
__global__ __launch_bounds__(256) void scan_combine_kernel(
    const U16* __restrict__ hpart, const U16* __restrict__ wacc,
    const float* __restrict__ ylocal, const float* __restrict__ aprod,
    float* __restrict__ yysum) {
  const int bh = blockIdx.x;
  const int b = bh >> 5, hh = bh & 31;
  const int w = threadIdx.x >> 6, l = threadIdx.x & 63;
  const int tl = l & 15, lg = l >> 4;
  __shared__ float csm[8][16];
  __shared__ float ylsm[32];
  const int pair0 = w * 2;
  f32x4 hr[2] = {};
  float cv[2][4] = {};
  for (int ci = 0; ci < NCH; ++ci) {
    int bx = (b * NCH + ci) * 32 + hh;
    size_t base = (size_t)bx * 2048 + (size_t)l * 4;
    float ap = aprod[bx];
    #pragma unroll
    for (int k = 0; k < 2; ++k) {
      size_t o = base + (size_t)(pair0 + k) * 256;
      ushort4 wraw = *reinterpret_cast<const ushort4*>(wacc + o);
      ushort4 praw = *reinterpret_cast<const ushort4*>(hpart + o);
      f32x4 wv = {bf2f(wraw.x), bf2f(wraw.y), bf2f(wraw.z), bf2f(wraw.w)};
      f32x4 pv = {bf2f(praw.x), bf2f(praw.y), bf2f(praw.z), bf2f(praw.w)};
      f32x4 a4 = hr[k] * wv;
      #pragma unroll
      for (int r = 0; r < 4; ++r) cv[k][r] += a4[r];
      hr[k] = hr[k] * ap + pv;
    }
  }
  #pragma unroll
  for (int k = 0; k < 2; ++k)
    #pragma unroll
    for (int r = 0; r < 4; ++r) {
      float c = cv[k][r];
      c += __shfl_xor(c, 1); c += __shfl_xor(c, 2);
      c += __shfl_xor(c, 4); c += __shfl_xor(c, 8);
      if (tl == 0) csm[pair0 + k][lg * 4 + r] = c;
    }
  if (threadIdx.x < 32) {
    float yl = 0.f;
    for (int ci = 0; ci < NCH; ++ci)
      yl += ylocal[(size_t)((b * NCH + ci) * 32 + hh) * 32 + threadIdx.x];
    ylsm[threadIdx.x] = yl;
  }
  __syncthreads();
  if (threadIdx.x < 32) {
    int p = threadIdx.x;
    int pt = p >> 4, pl = p & 15;
    float corr = csm[pt * 4 + 0][pl] + csm[pt * 4 + 1][pl] +
                 csm[pt * 4 + 2][pl] + csm[pt * 4 + 3][pl];
    yysum[(size_t)b * 1024 + hh * 32 + p] = ylsm[p] + corr;
  }
}

// ---------- folded epilogue (tokmean from GEMM1 col partials) ----------
__global__ __launch_bounds__(128) void final1_kernel(const float* __restrict__ colp,
                                                     const float* __restrict__ yysum,
                                                     const float* __restrict__ Wb,
                                                     const float* __restrict__ bb,
                                                     float* __restrict__ m2) {
  int b = blockIdx.x, j = blockIdx.y * 128 + threadIdx.x;
  float tm = 0.f;
  #pragma unroll
  for (int t = 0; t < 32; ++t) tm += colp[(size_t)(b * 32 + t) * 512 + j];
  float s = 0.f;
  for (int d = 0; d < 1024; ++d) s += yysum[b * 1024 + d] * Wb[(size_t)d * 512 + j];
  m2[b * 512 + j] = (tm + s) * (1.f / (float)Lsz) + bb[j];
}

__global__ __launch_bounds__(256) void final2_kernel(const float* __restrict__ m2,
                                                     const float* __restrict__ Wo,
                                                     const float* __restrict__ bo,
                                                     float* __restrict__ out) {
  int b = blockIdx.x, o = blockIdx.y * 256 + threadIdx.x;
  float s = 0.f;
  for (int j = 0; j < 512; ++j) s += m2[b * 512 + j] * Wo[(size_t)j * 1024 + o];
  out[b * 1024 + o] = s + bo[o];
}

extern "C" void kernel_launch(void* const* d_in, const int* in_sizes, int n_in,
                              void* d_out, int out_size, void* d_ws, size_t ws_size,
                              hipStream_t stream) {
  const float* image = (const float*)d_in[0];
  const float* text = (const float*)d_in[1];
  const float* W_in = (const float*)d_in[2];
  const float* b_in = (const float*)d_in[3];
  const float* W_txt = (const float*)d_in[4];
  const float* b_txt = (const float*)d_in[5];
  const float* norm_w = (const float*)d_in[6];
  const float* norm_b = (const float*)d_in[7];
  const float* W_zx = (const float*)d_in[8];
  const float* b_zx = (const float*)d_in[9];
  const float* conv_w = (const float*)d_in[10];
  const float* conv_b = (const float*)d_in[11];
  const float* dt_bias = (const float*)d_in[12];
  const float* A_log = (const float*)d_in[13];
  const float* Dp = (const float*)d_in[14];
  const float* W_blk = (const float*)d_in[15];
  const float* b_blk = (const float*)d_in[16];
  const float* W_out = (const float*)d_in[17];
  const float* b_out = (const float*)d_in[18];
  float* out = (float*)d_out;

  char* ws = (char*)d_ws;
  size_t off = 0;
  auto take = [&](size_t bytes) {
    char* p = ws + off;
    off = (off + bytes + 255) & ~(size_t)255;
    return p;
  };
  U16* zxT = (U16*)take((size_t)Bsz * D_PROJ_PAD * 4096 * 2);
  U16* wt_in = (U16*)take((size_t)DIMV * HID * 2);
  U16* wt_zx = (U16*)take((size_t)D_PROJ_PAD * DIMV * 2);
  U16* tok_bf = (U16*)take((size_t)MROWS * DIMV * 2);
  U16* x_bf = (U16*)take((size_t)MROWS * DIMV * 2);
  U16* xh_t = (U16*)take((size_t)MROWS * D_INNER * 2);
  U16* bm_bf = (U16*)take((size_t)MROWS * 64 * 2);
  U16* cm_bf = (U16*)take((size_t)MROWS * 64 * 2);
  U16* bm_t = (U16*)take((size_t)MROWS * 64 * 2);
  U16* cm_t = (U16*)take((size_t)MROWS * 64 * 2);
  float* decay4 = (float*)take((size_t)256 * 4096 * 16);
  float* txtf = (float*)take(8 * 512 * 4);
  float* colp = (float*)take((size_t)256 * 512 * 4);
  float* yysum = (float*)take(8 * 1024 * 4);
  float* m2 = (float*)take(8 * 512 * 4);
  float* ylocal = (float*)take((size_t)4096 * 32 * 4);
  float* aprod = (float*)take((size_t)4096 * 4);
  U16* hpart = tok_bf;
  U16* wacc = x_bf;

  txt_kernel<<<8, 512, 0, stream>>>(text, W_txt, b_txt, txtf);
  transpose_cvt_kernel<<<dim3(DIMV / 32, HID / 32), dim3(32, 8), 0, stream>>>(W_in, wt_in, HID, DIMV, DIMV);
  transpose_cvt_kernel<<<dim3(D_PROJ_PAD / 32, DIMV / 32), dim3(32, 8), 0, stream>>>(W_zx, wt_zx, DIMV, D_PROJ, D_PROJ_PAD);

  gemm_kernel<1, 1, 0><<<1024, 256, 0, stream>>>(
      (const void*)image, wt_in, tok_bf, b_in, txtf, colp, MROWS, HID, DIMV, 4);
  ln_kernel<<<MROWS, 128, 0, stream>>>(tok_bf, x_bf, norm_w, norm_b);

  gemm_kernel<0, 0, 1><<<4608, 256, 0, stream>>>(
      (const void*)x_bf, wt_zx, zxT, b_zx, nullptr, nullptr, MROWS, DIMV, D_PROJ, 18);

  decay_kernel<<<512, 256, 0, stream>>>(zxT, dt_bias, A_log, decay4);
  conv_t_kernel<<<dim3(16, 18, 8), 256, 0, stream>>>(zxT, conv_w, conv_b,
                                                     xh_t, bm_t, cm_t, bm_bf, cm_bf);

  scan_chunk_kernel<<<1024, 256, 0, stream>>>(xh_t, zxT, bm_bf, cm_bf, bm_t, cm_t,
                                              decay4, Dp, hpart, wacc, ylocal, aprod);
  scan_combine_kernel<<<256, 256, 0, stream>>>(hpart, wacc, ylocal, aprod, yysum);

  final1_kernel<<<dim3(8, 4), 128, 0, stream>>>(colp, yysum, W_blk, b_blk, m2);
  final2_kernel<<<dim3(8, 4), 256, 0, stream>>>(m2, W_out, b_out, out);
}

// Round 16
// 520.320 us; speedup vs baseline: 1.0746x; 1.0041x over previous
//
#include <hip/hip_runtime.h>

typedef unsigned short U16;
typedef __attribute__((ext_vector_type(4))) float f32x4;
typedef __attribute__((ext_vector_type(8))) short short8;
typedef __attribute__((ext_vector_type(8))) __bf16 bf16x8;

#define Bsz 8
#define Lsz 4096
#define HID 1024
#define DIMV 512
#define D_INNER 1024
#define NHEADS 32
#define HEADDIM 32
#define D_STATE 64
#define CONV_DIM 1152
#define D_PROJ 2208
#define D_PROJ_PAD 2304
#define MROWS 32768
#define CL2 256        // scan chunk per unit
#define NSUB 4         // sub-chunks of 64
#define NCH 16         // Lsz / CL2

__device__ __forceinline__ float bf2f(U16 u) {
  return __builtin_bit_cast(float, (unsigned)(((unsigned)u) << 16));
}
__device__ __forceinline__ U16 f2bf(float f) {
  unsigned u = __builtin_bit_cast(unsigned, f);
  return (U16)((u + 0x7FFFu + ((u >> 16) & 1u)) >> 16);
}
__device__ __forceinline__ void gload_lds16(const void* g, void* l) {
  __builtin_amdgcn_global_load_lds((const __attribute__((address_space(1))) unsigned int*)g,
                                   (__attribute__((address_space(3))) unsigned int*)l, 16, 0, 0);
}
__device__ __forceinline__ float fast_silu(float v) {
  return v * __builtin_amdgcn_rcpf(1.f + __expf(-v));
}

// ---------- tiny txt GEMM ----------
__global__ __launch_bounds__(512) void txt_kernel(const float* __restrict__ text,
                                                  const float* __restrict__ Wt,
                                                  const float* __restrict__ bt,
                                                  float* __restrict__ txt) {
  int b = blockIdx.x, j = threadIdx.x;
  float s = bt[j];
  const float* tp = text + (size_t)b * 77 * 768;
  for (int k = 0; k < 768; ++k) s += tp[k] * Wt[(size_t)k * 512 + j];
  txt[b * 512 + j] = s;
}

// ---------- transpose + convert weights ----------
__global__ __launch_bounds__(256) void transpose_cvt_kernel(const float* __restrict__ in,
                                                            U16* __restrict__ out,
                                                            int K, int N, int Npad) {
  __shared__ U16 tile[32][33];
  int n0 = blockIdx.x * 32, k0 = blockIdx.y * 32;
  int tx = threadIdx.x, ty = threadIdx.y;
  #pragma unroll
  for (int i = 0; i < 4; ++i) {
    int k = k0 + ty + i * 8, n = n0 + tx;
    float v = (n < N) ? in[(size_t)k * N + n] : 0.f;
    tile[ty + i * 8][tx] = f2bf(v);
  }
  __syncthreads();
  #pragma unroll
  for (int i = 0; i < 4; ++i) {
    int n = n0 + ty + i * 8;
    out[(size_t)n * K + k0 + tx] = tile[tx][ty + i * 8];
  }
}

// ---------- bf16 MFMA GEMM ----------
// EPI=1 (GEMM1): adds txt bias and emits per-(m-tile) column partial sums.
// TRANS=1 (GEMM2): writes C transposed as zx_t[b][c][l], bias+silu(z) fused.
template <int EPI, int AF32, int TRANS>
__global__ __launch_bounds__(256) void gemm_kernel(const void* __restrict__ Ap,
                                                   const U16* __restrict__ Bt,
                                                   U16* __restrict__ C,
                                                   const float* __restrict__ bias,
                                                   const float* __restrict__ txtv,
                                                   float* __restrict__ colp,
                                                   int M, int K, int Nreal, int NT) {
  __shared__ alignas(16) U16 smem[128 * 128];
  U16* As = smem;
  U16* Bs = smem + 128 * 64;
  const int tid = threadIdx.x;
  const int wid = tid >> 6, lane = tid & 63;
  const int lhi = lane >> 4, llo = lane & 15;
  const int xcd = blockIdx.x & 7, slot = blockIdx.x >> 3;
  const int m0 = (xcd + 8 * (slot / NT)) * 128;
  const int n0 = (slot % NT) * 128;
  const int wr = wid >> 1, wc = wid & 1;
  f32x4 acc[4][4] = {};

  for (int k0 = 0; k0 < K; k0 += 64) {
    __syncthreads();
    if constexpr (AF32) {
      const float* Af = (const float*)Ap;
      #pragma unroll
      for (int is = 0; is < 4; ++is) {
        int q = is * 256 + tid;
        int r = q >> 3, cl = q & 7;
        int cg = cl ^ (r & 7);
        const float* src = Af + (size_t)(m0 + r) * K + k0 + cg * 8;
        f32x4 v0 = *reinterpret_cast<const f32x4*>(src);
        f32x4 v1 = *reinterpret_cast<const f32x4*>(src + 4);
        short8 o;
        #pragma unroll
        for (int j = 0; j < 4; ++j) {
          o[j] = (short)f2bf(v0[j]);
          o[j + 4] = (short)f2bf(v1[j]);
        }
        *reinterpret_cast<short8*>(&As[q * 8]) = o;
      }
    } else {
      const U16* A = (const U16*)Ap;
      #pragma unroll
      for (int is = 0; is < 4; ++is) {
        int qbase = is * 256 + wid * 64;
        int q = qbase + lane;
        int r = q >> 3;
        int cc = (q & 7) ^ (r & 7);
        gload_lds16(A + (size_t)(m0 + r) * K + k0 + cc * 8, &As[qbase * 8]);
      }
    }
    #pragma unroll
    for (int is = 0; is < 4; ++is) {
      int qbase = is * 256 + wid * 64;
      int q = qbase + lane;
      int r = q >> 3;
      int cc = (q & 7) ^ (r & 7);
      gload_lds16(Bt + (size_t)(n0 + r) * K + k0 + cc * 8, &Bs[qbase * 8]);
    }
    __syncthreads();
    #pragma unroll
    for (int kk = 0; kk < 64; kk += 32) {
      bf16x8 av[4], bv[4];
      #pragma unroll
      for (int i = 0; i < 4; ++i) {
        int ra = wr * 64 + i * 16 + llo;
        short8 a = *reinterpret_cast<const short8*>(
            &As[ra * 64 + ((((kk >> 3) + lhi) ^ (ra & 7)) << 3)]);
        av[i] = __builtin_bit_cast(bf16x8, a);
        int rb = wc * 64 + i * 16 + llo;
        short8 b = *reinterpret_cast<const short8*>(
            &Bs[rb * 64 + ((((kk >> 3) + lhi) ^ (rb & 7)) << 3)]);
        bv[i] = __builtin_bit_cast(bf16x8, b);
      }
      #pragma unroll
      for (int i = 0; i < 4; ++i)
        #pragma unroll
        for (int j = 0; j < 4; ++j)
          acc[i][j] = __builtin_amdgcn_mfma_f32_16x16x32_bf16(av[i], bv[j], acc[i][j], 0, 0, 0);
    }
  }
  const int b = m0 >> 12;
  if constexpr (TRANS) {
    __syncthreads();
    U16* T = smem;
    #pragma unroll
    for (int i = 0; i < 4; ++i) {
      #pragma unroll
      for (int j = 0; j < 4; ++j) {
        int c_loc = wc * 64 + j * 16 + llo;
        int cg = n0 + c_loc;
        float badd = (cg < D_PROJ) ? bias[cg] : 0.f;
        int q = wr * 16 + i * 4 + lhi;
        int qs = q ^ ((c_loc & 15) << 1);
        U16 pk[4];
        #pragma unroll
        for (int r = 0; r < 4; ++r) {
          float v = acc[i][j][r] + badd;
          if (cg < 1024) v = fast_silu(v);
          pk[r] = f2bf(v);
        }
        uint2 p2;
        p2.x = (unsigned)pk[0] | ((unsigned)pk[1] << 16);
        p2.y = (unsigned)pk[2] | ((unsigned)pk[3] << 16);
        *reinterpret_cast<uint2*>(&T[c_loc * 128 + qs * 4]) = p2;
      }
    }
    __syncthreads();
    const int l0 = m0 & 4095;
    #pragma unroll
    for (int cs = 0; cs < 8; ++cs) {
      int c = cs * 16 + (tid >> 4);
      int gch = n0 + c;
      int kp = (tid & 15) * 2;
      int q0 = kp ^ ((c & 15) << 1);
      int q1 = (kp + 1) ^ ((c & 15) << 1);
      uint2 a = *reinterpret_cast<const uint2*>(&T[c * 128 + q0 * 4]);
      uint2 bq = *reinterpret_cast<const uint2*>(&T[c * 128 + q1 * 4]);
      if (gch < D_PROJ) {
        uint4 oo;
        oo.x = a.x; oo.y = a.y; oo.z = bq.x; oo.w = bq.y;
        *reinterpret_cast<uint4*>(C + ((size_t)b * D_PROJ_PAD + gch) * 4096 + l0 + kp * 4) = oo;
      }
    }
  } else {
    float cp[4] = {0.f, 0.f, 0.f, 0.f};
    #pragma unroll
    for (int i = 0; i < 4; ++i) {
      int rbase = m0 + wr * 64 + i * 16 + lhi * 4;
      #pragma unroll
      for (int j = 0; j < 4; ++j) {
        int cg = n0 + wc * 64 + j * 16 + llo;
        if (cg < Nreal) {
          float badd = bias[cg] + (EPI ? txtv[b * 512 + cg] : 0.f);
          #pragma unroll
          for (int r = 0; r < 4; ++r) {
            float v = acc[i][j][r] + badd;
            C[(size_t)(rbase + r) * Nreal + cg] = f2bf(v);
            if constexpr (EPI) cp[j] += v;
          }
        }
      }
    }
    if constexpr (EPI) {
      #pragma unroll
      for (int j = 0; j < 4; ++j) {
        cp[j] += __shfl_xor(cp[j], 16);
        cp[j] += __shfl_xor(cp[j], 32);
      }
      __syncthreads();
      float* colsm = reinterpret_cast<float*>(smem);
      if (lane < 16) {
        #pragma unroll
        for (int j = 0; j < 4; ++j)
          colsm[wr * 128 + wc * 64 + j * 16 + lane] = cp[j];
      }
      __syncthreads();
      if (tid < 128)
        colp[(size_t)(m0 >> 7) * 512 + n0 + tid] = colsm[tid] + colsm[128 + tid];
    }
  }
}

// ---------- LayerNorm ----------
__global__ __launch_bounds__(128) void ln_kernel(const U16* __restrict__ tok,
                                                 U16* __restrict__ xo,
                                                 const float* __restrict__ w,
                                                 const float* __restrict__ bb) {
  int row = blockIdx.x, tid = threadIdx.x;
  const U16* rp = tok + (size_t)row * 512 + tid * 4;
  uint2 raw = *reinterpret_cast<const uint2*>(rp);
  float f0 = bf2f((U16)(raw.x & 0xffff)), f1 = bf2f((U16)(raw.x >> 16));
  float f2 = bf2f((U16)(raw.y & 0xffff)), f3 = bf2f((U16)(raw.y >> 16));
  float s = f0 + f1 + f2 + f3;
  float q = f0 * f0 + f1 * f1 + f2 * f2 + f3 * f3;
  for (int m = 1; m < 64; m <<= 1) { s += __shfl_xor(s, m); q += __shfl_xor(q, m); }
  __shared__ float ss[2], qq[2];
  if ((tid & 63) == 0) { ss[tid >> 6] = s; qq[tid >> 6] = q; }
  __syncthreads();
  s = ss[0] + ss[1]; q = qq[0] + qq[1];
  float mu = s * (1.f / 512.f);
  float var = q * (1.f / 512.f) - mu * mu;
  float rs = rsqrtf(var + 1e-5f);
  int j0 = tid * 4;
  unsigned c0 = f2bf((f0 - mu) * rs * w[j0] + bb[j0]);
  unsigned c1 = f2bf((f1 - mu) * rs * w[j0 + 1] + bb[j0 + 1]);
  unsigned c2 = f2bf((f2 - mu) * rs * w[j0 + 2] + bb[j0 + 2]);
  unsigned c3 = f2bf((f3 - mu) * rs * w[j0 + 3] + bb[j0 + 3]);
  uint2 o; o.x = c0 | (c1 << 16); o.y = c2 | (c3 << 16);
  *reinterpret_cast<uint2*>(xo + (size_t)row * 512 + j0) = o;
}

// ---------- decay precompute from zx_t ----------
__global__ __launch_bounds__(256) void decay_kernel(const U16* __restrict__ zxT,
                                                    const float* __restrict__ dt_bias,
                                                    const float* __restrict__ A_log,
                                                    float* __restrict__ decay4) {
  const int sc = blockIdx.x;
  const int w = threadIdx.x >> 6, l = threadIdx.x & 63;
  const int r0 = sc * 64;
  const int b = r0 >> 12, l0 = r0 & 4095;
  #pragma unroll
  for (int i = 0; i < 8; ++i) {
    int hh = w * 8 + i;
    float raw = bf2f(zxT[((size_t)b * D_PROJ_PAD + 2176 + hh) * 4096 + l0 + l]) + dt_bias[hh];
    float dt = (raw > 20.f) ? raw : log1pf(__expf(raw));
    float A = -__expf(A_log[hh]);
    float ldA2 = dt * A * 1.44269504088896f;
    float ldt2 = __log2f(dt);
    float la = ldA2;
    #pragma unroll
    for (int d = 1; d < 64; d <<= 1) {
      float o = __shfl_up(la, d);
      if (l >= d) la += o;
    }
    float laend = __shfl(la, 63);
    f32x4 v = {ldt2 - la, la, exp2f(la), exp2f(laend + ldt2 - la)};
    *reinterpret_cast<f32x4*>(decay4 + ((size_t)(b * 32 + hh) * 4096 + l0 + l) * 4) = v;
  }
}

// ---------- conv(K=4)+silu on transposed layout ----------
__global__ __launch_bounds__(256) void conv_t_kernel(
    const U16* __restrict__ zxT, const float* __restrict__ cw,
    const float* __restrict__ cb, U16* __restrict__ xh_t,
    U16* __restrict__ bm_t, U16* __restrict__ cm_t,
    U16* __restrict__ Bmo, U16* __restrict__ Cmo) {
  __shared__ U16 Tc[64 * 264];
  const int lc = blockIdx.x, cg = blockIdx.y, b = blockIdx.z;
  const int tid = threadIdx.x;
  const int cl = tid & 63, ls = tid >> 6;
  const int cc2 = cg * 64 + cl;
  const int l0 = lc * 256 + ls * 64;
  const U16* row = zxT + ((size_t)b * D_PROJ_PAD + 1024 + cc2) * 4096;

  U16 arr[72];
  {
    const U16* src = row + l0 - 8;
    #pragma unroll
    for (int k = 0; k < 9; ++k) {
      uint4 rv;
      if (l0 == 0 && k == 0) {
        rv.x = rv.y = rv.z = rv.w = 0u;
      } else {
        rv = *reinterpret_cast<const uint4*>(src + k * 8);
      }
      arr[k * 8 + 0] = (U16)(rv.x & 0xffff); arr[k * 8 + 1] = (U16)(rv.x >> 16);
      arr[k * 8 + 2] = (U16)(rv.y & 0xffff); arr[k * 8 + 3] = (U16)(rv.y >> 16);
      arr[k * 8 + 4] = (U16)(rv.z & 0xffff); arr[k * 8 + 5] = (U16)(rv.z >> 16);
      arr[k * 8 + 6] = (U16)(rv.w & 0xffff); arr[k * 8 + 7] = (U16)(rv.w >> 16);
    }
  }
  const float4 w4 = *reinterpret_cast<const float4*>(cw + cc2 * 4);
  const float cbv = cb[cc2];
  U16 o[64];
  #pragma unroll
  for (int j = 0; j < 64; ++j) {
    float acc = cbv + bf2f(arr[j + 5]) * w4.x + bf2f(arr[j + 6]) * w4.y +
                bf2f(arr[j + 7]) * w4.z + bf2f(arr[j + 8]) * w4.w;
    o[j] = f2bf(fast_silu(acc));
  }
  {
    U16* dst;
    if (cc2 < 1024)      dst = xh_t + ((size_t)b * 1024 + cc2) * 4096 + l0;
    else if (cc2 < 1088) dst = bm_t + ((size_t)(b * 64 + (cc2 - 1024))) * 4096 + l0;
    else                 dst = cm_t + ((size_t)(b * 64 + (cc2 - 1088))) * 4096 + l0;
    #pragma unroll
    for (int k = 0; k < 8; ++k) {
      uint4 ov;
      ov.x = (unsigned)o[k * 8 + 0] | ((unsigned)o[k * 8 + 1] << 16);
      ov.y = (unsigned)o[k * 8 + 2] | ((unsigned)o[k * 8 + 3] << 16);
      ov.z = (unsigned)o[k * 8 + 4] | ((unsigned)o[k * 8 + 5] << 16);
      ov.w = (unsigned)o[k * 8 + 6] | ((unsigned)o[k * 8 + 7] << 16);
      *reinterpret_cast<uint4*>(dst + k * 8) = ov;
    }
  }
  if (cg >= 16) {
    #pragma unroll
    for (int k = 0; k < 8; ++k) {
      uint4 ov;
      ov.x = (unsigned)o[k * 8 + 0] | ((unsigned)o[k * 8 + 1] << 16);
      ov.y = (unsigned)o[k * 8 + 2] | ((unsigned)o[k * 8 + 3] << 16);
      ov.z = (unsigned)o[k * 8 + 4] | ((unsigned)o[k * 8 + 5] << 16);
      ov.w = (unsigned)o[k * 8 + 6] | ((unsigned)o[k * 8 + 7] << 16);
      *reinterpret_cast<uint4*>(&Tc[cl * 264 + ls * 64 + k * 8]) = ov;
    }
    __syncthreads();
    U16* outp = (cg == 16) ? Bmo : Cmo;
    const int lt = tid;
    U16 rowv[64];
    #pragma unroll
    for (int n = 0; n < 64; ++n) rowv[n] = Tc[n * 264 + lt];
    U16* dst = outp + ((size_t)b * 4096 + lc * 256 + lt) * 64;
    #pragma unroll
    for (int k = 0; k < 8; ++k) {
      uint4 ov;
      ov.x = (unsigned)rowv[k * 8 + 0] | ((unsigned)rowv[k * 8 + 1] << 16);
      ov.y = (unsigned)rowv[k * 8 + 2] | ((unsigned)rowv[k * 8 + 3] << 16);
      ov.z = (unsigned)rowv[k * 8 + 4] | ((unsigned)rowv[k * 8 + 5] << 16);
      ov.w = (unsigned)rowv[k * 8 + 6] | ((unsigned)rowv[k * 8 + 7] << 16);
      *reinterpret_cast<uint4*>(dst + k * 8) = ov;
    }
  }
}

// ---------- SSD chunked scan via MFMA (round-15 body; M-buffer pad removed,
// XOR 16B-chunk swizzle instead -> LDS 40960->36864 B, 4 blocks/CU) ----------
__global__ __launch_bounds__(256, 2) void scan_chunk_kernel(
    const U16* __restrict__ xh_t, const U16* __restrict__ zxT,
    const U16* __restrict__ Bm, const U16* __restrict__ Cm,
    const U16* __restrict__ bm_t, const U16* __restrict__ cm_t,
    const float* __restrict__ decay4, const float* __restrict__ Dp,
    U16* __restrict__ hpart, U16* __restrict__ wacc,
    float* __restrict__ ylocal, float* __restrict__ aprod) {
  const int w = threadIdx.x >> 6, l = threadIdx.x & 63;
  const int bid = (blockIdx.x & 7) * 128 + (blockIdx.x >> 3);
  const int u = bid * 4 + w;
  const int hh = u & 31, ci = (u >> 5) & (NCH - 1), b = u >> 9;
  const int tl = l & 15, lg = l >> 4;

  __shared__ alignas(16) U16 MsmAll[4 * 64 * 64];   // 32768 B (swizzled, no pad)
  __shared__ alignas(16) float decAll[4 * 256];     //  4096 B
  U16* Msm = &MsmAll[w * 64 * 64];
  float* qsm = &decAll[w * 256];
  float* la2sm = qsm + 64;
  float* casm = qsm + 128;
  float* cfsm = qsm + 192;

  #pragma unroll
  for (int i = 0; i < 8; ++i)
    *reinterpret_cast<f32x4*>(reinterpret_cast<char*>(Msm) + (size_t)l * 128 + i * 16) =
        f32x4{0.f, 0.f, 0.f, 0.f};

  f32x4 hC[2][4] = {};
  f32x4 WB[2][4] = {};
  f32x4 corrp[2] = {};
  float ylac[2] = {0.f, 0.f}, dxac[2] = {0.f, 0.f};
  float capfx = 1.f;
  const size_t xrow = ((size_t)b * 1024 + hh * 32) * 4096;
  const size_t grow = ((size_t)b * D_PROJ_PAD + hh * 32) * 4096;
  const float* dbase = decay4 + ((size_t)(b * 32 + hh) * 4096) * 4;

  for (int sc = 0; sc < NSUB; ++sc) {
    const int lglob = ci * CL2 + sc * 64;
    const int r0g = b * 4096 + lglob;

    f32x4 dv = *reinterpret_cast<const f32x4*>(dbase + (size_t)(lglob + l) * 4);
    qsm[l] = dv[0];
    la2sm[l] = dv[1];
    casm[l] = dv[2];
    cfsm[l] = dv[3];
    const float cs = __shfl(dv[2], 63);

    // ---- EARLY ISSUE: staging raw loads (latency drains under matmul1) ----
    short8 graw[2][2], xraw[2][2];
    #pragma unroll
    for (int pt = 0; pt < 2; ++pt)
      #pragma unroll
      for (int kt = 0; kt < 2; ++kt) {
        size_t po = (size_t)(pt * 16 + tl) * 4096 + lglob + kt * 32 + lg * 8;
        graw[pt][kt] = *reinterpret_cast<const short8*>(zxT + grow + po);
        xraw[pt][kt] = *reinterpret_cast<const short8*>(xh_t + xrow + po);
      }

    // ---- matmul1 half A: si in {0,1} (7 tiles) ----
    {
      f32x4 g[7] = {};
      #pragma unroll
      for (int k = 0; k < 2; ++k) {
        const size_t co = (size_t)k * 32 + lg * 8;
        bf16x8 af0 = *reinterpret_cast<const bf16x8*>(Bm + (size_t)(r0g + tl) * 64 + co);
        bf16x8 af1 = *reinterpret_cast<const bf16x8*>(Bm + (size_t)(r0g + 16 + tl) * 64 + co);
        bf16x8 cf0 = *reinterpret_cast<const bf16x8*>(Cm + (size_t)(r0g + tl) * 64 + co);
        bf16x8 cf1 = *reinterpret_cast<const bf16x8*>(Cm + (size_t)(r0g + 16 + tl) * 64 + co);
        bf16x8 cf2 = *reinterpret_cast<const bf16x8*>(Cm + (size_t)(r0g + 32 + tl) * 64 + co);
        bf16x8 cf3 = *reinterpret_cast<const bf16x8*>(Cm + (size_t)(r0g + 48 + tl) * 64 + co);
        __builtin_amdgcn_s_setprio(1);
        g[0] = __builtin_amdgcn_mfma_f32_16x16x32_bf16(af0, cf0, g[0], 0, 0, 0);
        g[1] = __builtin_amdgcn_mfma_f32_16x16x32_bf16(af0, cf1, g[1], 0, 0, 0);
        g[2] = __builtin_amdgcn_mfma_f32_16x16x32_bf16(af0, cf2, g[2], 0, 0, 0);
        g[3] = __builtin_amdgcn_mfma_f32_16x16x32_bf16(af0, cf3, g[3], 0, 0, 0);
        g[4] = __builtin_amdgcn_mfma_f32_16x16x32_bf16(af1, cf1, g[4], 0, 0, 0);
        g[5] = __builtin_amdgcn_mfma_f32_16x16x32_bf16(af1, cf2, g[5], 0, 0, 0);
        g[6] = __builtin_amdgcn_mfma_f32_16x16x32_bf16(af1, cf3, g[6], 0, 0, 0);
        __builtin_amdgcn_s_setprio(0);
      }
      f32x4 q0 = *reinterpret_cast<const f32x4*>(&qsm[lg * 4]);
      f32x4 q1 = *reinterpret_cast<const f32x4*>(&qsm[16 + lg * 4]);
      #pragma unroll
      for (int idx = 0; idx < 7; ++idx) {
        const int si = (idx < 4) ? 0 : 1;
        const int ti = (idx < 4) ? idx : (idx - 3);
        f32x4 q4 = si ? q1 : q0;
        float lat = la2sm[ti * 16 + tl];
        float v[4];
        #pragma unroll
        for (int r = 0; r < 4; ++r) {
          float val = g[idx][r] * exp2f(lat + q4[r]);
          if (si == ti) val = (lg * 4 + r <= tl) ? val : 0.f;
          v[r] = val;
        }
        uint2 pk;
        pk.x = (unsigned)f2bf(v[0]) | ((unsigned)f2bf(v[1]) << 16);
        pk.y = (unsigned)f2bf(v[2]) | ((unsigned)f2bf(v[3]) << 16);
        // swizzled write: row stride 128B, 16B-chunk index ^= (row&7)
        int chs = ((si * 2 + (lg >> 1)) ^ (tl & 7));
        *reinterpret_cast<uint2*>(reinterpret_cast<char*>(Msm) +
                                  (size_t)(ti * 16 + tl) * 128 + (chs << 4) + ((lg & 1) << 3)) = pk;
      }
    }
    // ---- matmul1 half B: si in {2,3} (3 tiles) ----
    {
      f32x4 g[3] = {};
      #pragma unroll
      for (int k = 0; k < 2; ++k) {
        const size_t co = (size_t)k * 32 + lg * 8;
        bf16x8 af2 = *reinterpret_cast<const bf16x8*>(Bm + (size_t)(r0g + 32 + tl) * 64 + co);
        bf16x8 af3 = *reinterpret_cast<const bf16x8*>(Bm + (size_t)(r0g + 48 + tl) * 64 + co);
        bf16x8 cf2 = *reinterpret_cast<const bf16x8*>(Cm + (size_t)(r0g + 32 + tl) * 64 + co);
        bf16x8 cf3 = *reinterpret_cast<const bf16x8*>(Cm + (size_t)(r0g + 48 + tl) * 64 + co);
        __builtin_amdgcn_s_setprio(1);
        g[0] = __builtin_amdgcn_mfma_f32_16x16x32_bf16(af2, cf2, g[0], 0, 0, 0);
        g[1] = __builtin_amdgcn_mfma_f32_16x16x32_bf16(af2, cf3, g[1], 0, 0, 0);
        g[2] = __builtin_amdgcn_mfma_f32_16x16x32_bf16(af3, cf3, g[2], 0, 0, 0);
        __builtin_amdgcn_s_setprio(0);
      }
      f32x4 q2 = *reinterpret_cast<const f32x4*>(&qsm[32 + lg * 4]);
      f32x4 q3 = *reinterpret_cast<const f32x4*>(&qsm[48 + lg * 4]);
      const int sis[3] = {2, 2, 3};
      const int tis[3] = {2, 3, 3};
      #pragma unroll
      for (int idx = 0; idx < 3; ++idx) {
        const int si = sis[idx], ti = tis[idx];
        f32x4 q4 = (si == 2) ? q2 : q3;
        float lat = la2sm[ti * 16 + tl];
        float v[4];
        #pragma unroll
        for (int r = 0; r < 4; ++r) {
          float val = g[idx][r] * exp2f(lat + q4[r]);
          if (si == ti) val = (lg * 4 + r <= tl) ? val : 0.f;
          v[r] = val;
        }
        uint2 pk;
        pk.x = (unsigned)f2bf(v[0]) | ((unsigned)f2bf(v[1]) << 16);
        pk.y = (unsigned)f2bf(v[2]) | ((unsigned)f2bf(v[3]) << 16);
        int chs = ((si * 2 + (lg >> 1)) ^ (tl & 7));
        *reinterpret_cast<uint2*>(reinterpret_cast<char*>(Msm) +
                                  (size_t)(ti * 16 + tl) * 128 + (chs << 4) + ((lg & 1) << 3)) = pk;
      }
    }

    // ---- scale staging (raws already landed); dxac here ----
    bf16x8 ga[2][2], xa[2][2];
    #pragma unroll
    for (int pt = 0; pt < 2; ++pt)
      #pragma unroll
      for (int kt = 0; kt < 2; ++kt) {
        const float* cap = &casm[kt * 32 + lg * 8];
        const float* cfp = &cfsm[kt * 32 + lg * 8];
        short8 gs, xs8;
        #pragma unroll
        for (int j = 0; j < 8; ++j) {
          float gf = bf2f((U16)graw[pt][kt][j]);
          float xf = bf2f((U16)xraw[pt][kt][j]);
          dxac[pt] = fmaf(gf, xf, dxac[pt]);
          gs[j] = (short)f2bf(gf * cap[j]);
          xs8[j] = (short)f2bf(xf * cfp[j]);
        }
        ga[pt][kt] = __builtin_bit_cast(bf16x8, gs);
        xa[pt][kt] = __builtin_bit_cast(bf16x8, xs8);
      }

    // ---- matmul2: Y = M X (X from xraw); gz preloaded batch; ylac ----
    {
      uint2 gzp[4][2];
      #pragma unroll
      for (int tt = 0; tt < 4; ++tt)
        #pragma unroll
        for (int pt = 0; pt < 2; ++pt)
          gzp[tt][pt] = *reinterpret_cast<const uint2*>(
              zxT + grow + (size_t)(pt * 16 + tl) * 4096 + lglob + tt * 16 + lg * 4);
      #pragma unroll
      for (int tt = 0; tt < 4; ++tt) {
        f32x4 y[2] = {f32x4{0.f, 0.f, 0.f, 0.f}, f32x4{0.f, 0.f, 0.f, 0.f}};
        __builtin_amdgcn_s_setprio(1);
        #pragma unroll
        for (int ks = 0; ks < 2; ++ks) {
          // swizzled read: 16B chunk (ks*4+lg) ^ (row&7)
          int chr = ((ks * 4 + lg) ^ (tl & 7));
          bf16x8 mf = *reinterpret_cast<const bf16x8*>(
              reinterpret_cast<char*>(Msm) + (size_t)(tt * 16 + tl) * 128 + (chr << 4));
          #pragma unroll
          for (int pt = 0; pt < 2; ++pt)
            y[pt] = __builtin_amdgcn_mfma_f32_16x16x32_bf16(
                mf, __builtin_bit_cast(bf16x8, xraw[pt][ks]), y[pt], 0, 0, 0);
        }
        __builtin_amdgcn_s_setprio(0);
        #pragma unroll
        for (int pt = 0; pt < 2; ++pt) {
          uint2 gz2 = gzp[tt][pt];
          float gzv[4] = {bf2f((U16)(gz2.x & 0xffff)), bf2f((U16)(gz2.x >> 16)),
                          bf2f((U16)(gz2.y & 0xffff)), bf2f((U16)(gz2.y >> 16))};
          #pragma unroll
          for (int r = 0; r < 4; ++r)
            ylac[pt] = fmaf(gzv[r], y[pt][r], ylac[pt]);
        }
      }
    }

    // ---- matmul3 streamed per nt (batched fragment loads per nt) ----
    #pragma unroll
    for (int nt = 0; nt < 4; ++nt) {
      size_t cro = (size_t)(b * 64 + nt * 16 + tl) * 4096 + lglob;
      bf16x8 cb0 = *reinterpret_cast<const bf16x8*>(cm_t + cro + lg * 8);
      bf16x8 cb1 = *reinterpret_cast<const bf16x8*>(cm_t + cro + 32 + lg * 8);
      bf16x8 bb0 = *reinterpret_cast<const bf16x8*>(bm_t + cro + lg * 8);
      bf16x8 bb1 = *reinterpret_cast<const bf16x8*>(bm_t + cro + 32 + lg * 8);
      __builtin_amdgcn_s_setprio(1);
      #pragma unroll
      for (int pt = 0; pt < 2; ++pt) {
        f32x4 z4 = {0.f, 0.f, 0.f, 0.f};
        f32x4 ws = __builtin_amdgcn_mfma_f32_16x16x32_bf16(ga[pt][0], cb0, z4, 0, 0, 0);
        ws = __builtin_amdgcn_mfma_f32_16x16x32_bf16(ga[pt][1], cb1, ws, 0, 0, 0);
        f32x4 hs = __builtin_amdgcn_mfma_f32_16x16x32_bf16(xa[pt][0], bb0, z4, 0, 0, 0);
        hs = __builtin_amdgcn_mfma_f32_16x16x32_bf16(xa[pt][1], bb1, hs, 0, 0, 0);
        corrp[pt] = corrp[pt] + hC[pt][nt] * ws;
        WB[pt][nt] = WB[pt][nt] + ws * capfx;
        hC[pt][nt] = hC[pt][nt] * cs + hs;
      }
      __builtin_amdgcn_s_setprio(0);
    }
    capfx *= cs;
  }

  // ---- epilogue ----
  #pragma unroll
  for (int pt = 0; pt < 2; ++pt)
    #pragma unroll
    for (int nt = 0; nt < 4; ++nt) {
      size_t slot = (size_t)u * 2048 + (size_t)((pt * 4 + nt) * 64 + l) * 4;
      ushort4 hp, wp;
      hp.x = f2bf(hC[pt][nt][0]); hp.y = f2bf(hC[pt][nt][1]);
      hp.z = f2bf(hC[pt][nt][2]); hp.w = f2bf(hC[pt][nt][3]);
      wp.x = f2bf(WB[pt][nt][0]); wp.y = f2bf(WB[pt][nt][1]);
      wp.z = f2bf(WB[pt][nt][2]); wp.w = f2bf(WB[pt][nt][3]);
      *reinterpret_cast<ushort4*>(hpart + slot) = hp;
      *reinterpret_cast<ushort4*>(wacc + slot) = wp;
    }
  float corrv[2][4];
  #pragma unroll
  for (int pt = 0; pt < 2; ++pt)
    #pragma unroll
    for (int r = 0; r < 4; ++r) {
      float c = corrp[pt][r];
      c += __shfl_xor(c, 1); c += __shfl_xor(c, 2);
      c += __shfl_xor(c, 4); c += __shfl_xor(c, 8);
      corrv[pt][r] = c;
    }
  const float Dh = Dp[hh];
  float* ysm = qsm;
  #pragma unroll
  for (int pt = 0; pt < 2; ++pt) {
    float yv = ylac[pt] + Dh * dxac[pt];
    yv += __shfl_xor(yv, 16);
    yv += __shfl_xor(yv, 32);
    if (l < 16) ysm[pt * 16 + l] = yv;
  }
  if (tl == 0) {
    #pragma unroll
    for (int pt = 0; pt < 2; ++pt)
      #pragma unroll
      for (int r = 0; r < 4; ++r)
        ysm[pt * 16 + lg * 4 + r] += corrv[pt][r];
  }
  if (l < 32) ylocal[(size_t)u * 32 + l] = ysm[l];
  if (l == 0) aprod[u] = capfx;
}

// ---------- sequential combine across chunks (bf16 hpart/wacc) ----------
__global__ __launch_bounds__(256) void scan_combine_kernel(
    const U16* __restrict__ hpart, const U16* __restrict__ wacc,
    const float* __restrict__ ylocal, const float* __restrict__ aprod,
    float* __restrict__ yysum) {
  const int bh = blockIdx.x;
  const int b = bh >> 5, hh = bh & 31;
  const int w = threadIdx.x >> 6, l = threadIdx.x & 63;
  const int tl = l & 15, lg = l >> 4;
  __shared__ float csm[8][16];
  __shared__ float ylsm[32];
  const int pair0 = w * 2;
  f32x4 hr[2] = {};
  float cv[2][4] = {};
  for (int ci = 0; ci < NCH; ++ci) {
    int bx = (b * NCH + ci) * 32 + hh;
    size_t base = (size_t)bx * 2048 + (size_t)l * 4;
    float ap = aprod[bx];
    #pragma unroll
    for (int k = 0; k < 2; ++k) {
      size_t o = base + (size_t)(pair0 + k) * 256;
      ushort4 wraw = *reinterpret_cast<const ushort4*>(wacc + o);
      ushort4 praw = *reinterpret_cast<const ushort4*>(hpart + o);
      f32x4 wv = {bf2f(wraw.x), bf2f(wraw.y), bf2f(wraw.z), bf2f(wraw.w)};
      f32x4 pv = {bf2f(praw.x), bf2f(praw.y), bf2f(praw.z), bf2f(praw.w)};
      f32x4 a4 = hr[k] * wv;
      #pragma unroll
      for (int r = 0; r < 4; ++r) cv[k][r] += a4[r];
      hr[k] = hr[k] * ap + pv;
    }
  }
  #pragma unroll
  for (int k = 0; k < 2; ++k)
    #pragma unroll
    for (int r = 0; r < 4; ++r) {
      float c = cv[k][r];
      c += __shfl_xor(c, 1); c += __shfl_xor(c, 2);
      c += __shfl_xor(c, 4); c += __shfl_xor(c, 8);
      if (tl == 0) csm[pair0 + k][lg * 4 + r] = c;
    }
  if (threadIdx.x < 32) {
    float yl = 0.f;
    for (int ci = 0; ci < NCH; ++ci)
      yl += ylocal[(size_t)((b * NCH + ci) * 32 + hh) * 32 + threadIdx.x];
    ylsm[threadIdx.x] = yl;
  }
  __syncthreads();
  if (threadIdx.x < 32) {
    int p = threadIdx.x;
    int pt = p >> 4, pl = p & 15;
    float corr = csm[pt * 4 + 0][pl] + csm[pt * 4 + 1][pl] +
                 csm[pt * 4 + 2][pl] + csm[pt * 4 + 3][pl];
    yysum[(size_t)b * 1024 + hh * 32 + p] = ylsm[p] + corr;
  }
}

// ---------- folded epilogue (tokmean from GEMM1 col partials) ----------
__global__ __launch_bounds__(128) void final1_kernel(const float* __restrict__ colp,
                                                     const float* __restrict__ yysum,
                                                     const float* __restrict__ Wb,
                                                     const float* __restrict__ bb,
                                                     float* __restrict__ m2) {
  int b = blockIdx.x, j = blockIdx.y * 128 + threadIdx.x;
  float tm = 0.f;
  #pragma unroll
  for (int t = 0; t < 32; ++t) tm += colp[(size_t)(b * 32 + t) * 512 + j];
  float s = 0.f;
  for (int d = 0; d < 1024; ++d) s += yysum[b * 1024 + d] * Wb[(size_t)d * 512 + j];
  m2[b * 512 + j] = (tm + s) * (1.f / (float)Lsz) + bb[j];
}

__global__ __launch_bounds__(256) void final2_kernel(const float* __restrict__ m2,
                                                     const float* __restrict__ Wo,
                                                     const float* __restrict__ bo,
                                                     float* __restrict__ out) {
  int b = blockIdx.x, o = blockIdx.y * 256 + threadIdx.x;
  float s = 0.f;
  for (int j = 0; j < 512; ++j) s += m2[b * 512 + j] * Wo[(size_t)j * 1024 + o];
  out[b * 1024 + o] = s + bo[o];
}

extern "C" void kernel_launch(void* const* d_in, const int* in_sizes, int n_in,
                              void* d_out, int out_size, void* d_ws, size_t ws_size,
                              hipStream_t stream) {
  const float* image = (const float*)d_in[0];
  const float* text = (const float*)d_in[1];
  const float* W_in = (const float*)d_in[2];
  const float* b_in = (const float*)d_in[3];
  const float* W_txt = (const float*)d_in[4];
  const float* b_txt = (const float*)d_in[5];
  const float* norm_w = (const float*)d_in[6];
  const float* norm_b = (const float*)d_in[7];
  const float* W_zx = (const float*)d_in[8];
  const float* b_zx = (const float*)d_in[9];
  const float* conv_w = (const float*)d_in[10];
  const float* conv_b = (const float*)d_in[11];
  const float* dt_bias = (const float*)d_in[12];
  const float* A_log = (const float*)d_in[13];
  const float* Dp = (const float*)d_in[14];
  const float* W_blk = (const float*)d_in[15];
  const float* b_blk = (const float*)d_in[16];
  const float* W_out = (const float*)d_in[17];
  const float* b_out = (const float*)d_in[18];
  float* out = (float*)d_out;

  char* ws = (char*)d_ws;
  size_t off = 0;
  auto take = [&](size_t bytes) {
    char* p = ws + off;
    off = (off + bytes + 255) & ~(size_t)255;
    return p;
  };
  U16* zxT = (U16*)take((size_t)Bsz * D_PROJ_PAD * 4096 * 2);
  U16* wt_in = (U16*)take((size_t)DIMV * HID * 2);
  U16* wt_zx = (U16*)take((size_t)D_PROJ_PAD * DIMV * 2);
  U16* tok_bf = (U16*)take((size_t)MROWS * DIMV * 2);
  U16* x_bf = (U16*)take((size_t)MROWS * DIMV * 2);
  U16* xh_t = (U16*)take((size_t)MROWS * D_INNER * 2);
  U16* bm_bf = (U16*)take((size_t)MROWS * 64 * 2);
  U16* cm_bf = (U16*)take((size_t)MROWS * 64 * 2);
  U16* bm_t = (U16*)take((size_t)MROWS * 64 * 2);
  U16* cm_t = (U16*)take((size_t)MROWS * 64 * 2);
  float* decay4 = (float*)take((size_t)256 * 4096 * 16);
  float* txtf = (float*)take(8 * 512 * 4);
  float* colp = (float*)take((size_t)256 * 512 * 4);
  float* yysum = (float*)take(8 * 1024 * 4);
  float* m2 = (float*)take(8 * 512 * 4);
  float* ylocal = (float*)take((size_t)4096 * 32 * 4);
  float* aprod = (float*)take((size_t)4096 * 4);
  U16* hpart = tok_bf;
  U16* wacc = x_bf;

  txt_kernel<<<8, 512, 0, stream>>>(text, W_txt, b_txt, txtf);
  transpose_cvt_kernel<<<dim3(DIMV / 32, HID / 32), dim3(32, 8), 0, stream>>>(W_in, wt_in, HID, DIMV, DIMV);
  transpose_cvt_kernel<<<dim3(D_PROJ_PAD / 32, DIMV / 32), dim3(32, 8), 0, stream>>>(W_zx, wt_zx, DIMV, D_PROJ, D_PROJ_PAD);

  gemm_kernel<1, 1, 0><<<1024, 256, 0, stream>>>(
      (const void*)image, wt_in, tok_bf, b_in, txtf, colp, MROWS, HID, DIMV, 4);
  ln_kernel<<<MROWS, 128, 0, stream>>>(tok_bf, x_bf, norm_w, norm_b);

  gemm_kernel<0, 0, 1><<<4608, 256, 0, stream>>>(
      (const void*)x_bf, wt_zx, zxT, b_zx, nullptr, nullptr, MROWS, DIMV, D_PROJ, 18);

  decay_kernel<<<512, 256, 0, stream>>>(zxT, dt_bias, A_log, decay4);
  conv_t_kernel<<<dim3(16, 18, 8), 256, 0, stream>>>(zxT, conv_w, conv_b,
                                                     xh_t, bm_t, cm_t, bm_bf, cm_bf);

  scan_chunk_kernel<<<1024, 256, 0, stream>>>(xh_t, zxT, bm_bf, cm_bf, bm_t, cm_t,
                                              decay4, Dp, hpart, wacc, ylocal, aprod);
  scan_combine_kernel<<<256, 256, 0, stream>>>(hpart, wacc, ylocal, aprod, yysum);

  final1_kernel<<<dim3(8, 4), 128, 0, stream>>>(colp, yysum, W_blk, b_blk, m2);
  final2_kernel<<<dim3(8, 4), 256, 0, stream>>>(m2, W_out, b_out, out);
}